// Round 9
// baseline (4903.368 us; speedup 1.0000x reference)
//
#include <hip/hip_runtime.h>
#include <math.h>

// ChainedGP v16: v15 (multi-launch, best@3914us) with 128-WIDE PANELS.
// Evidence: v15's factor path ~2900us over ~44 launches; real work ~700us;
// => ~50us per dependent kernel boundary (matches v8 fence, v9/v14 sc1 —
// all sync mechanisms cost ~50-60us/event on MI355X). Only lever left:
// FEWER boundaries. Cholesky at 64-grain = 32 sequential steps; at 128-grain
// = 16. diag128 fits one block's LDS (Cs[128][132]=68KB, tot ~136KB<160KB).
// diag128_0 + 15 panel128 kernels replace diag0 + 31 panels (33->17
// boundaries in the chol chain). Block 0 of each panel owns the THREE
// next-diag 64-tiles (dual-wave TRSM of rows rs,rs+1; 3 SYRKs; in-LDS
// blocked factor128 = factor64+TRSM64+SYRK+factor64). Internal pair
// off-diag L(rs+1,rs)->ltri, so phase2/phase3/red_small unchanged.
#define NN 16384
#define MM 2048
#define DD 8
#define NB 32                     // MM/64
#define LDW 132                   // LDS row stride for 128-wide tiles (528B, 16B-aligned)
#define SZB ((size_t)16777216)    // 2048*2048*4 bytes

constexpr float HLOG2PI = 0.91893853320467274178f;

using short8  = __attribute__((ext_vector_type(8))) short;
using float4v = __attribute__((ext_vector_type(4))) float;

__device__ __forceinline__ float4v f4zero(){ float4v v; v[0]=0.f; v[1]=0.f; v[2]=0.f; v[3]=0.f; return v; }

__device__ __forceinline__ void bfsplit(float v, short& h, short& lo){
  unsigned b = __float_as_uint(v);
  h = (short)(b >> 16);
  float hf = __uint_as_float(b & 0xFFFF0000u);
  lo = (short)(__float_as_uint(v - hf) >> 16);
}
__device__ __forceinline__ float bf2f(short s){
  return __uint_as_float(((unsigned)(unsigned short)s) << 16);
}
__device__ __forceinline__ float4v mfma3(short8 ah, short8 al, short8 bh, short8 bl, float4v c){
  c = __builtin_amdgcn_mfma_f32_16x16x32_bf16(ah, bh, c, 0, 0, 0);
  c = __builtin_amdgcn_mfma_f32_16x16x32_bf16(ah, bl, c, 0, 0, 0);
  c = __builtin_amdgcn_mfma_f32_16x16x32_bf16(al, bh, c, 0, 0, 0);
  return c;
}

__device__ __forceinline__ float block_reduce(float v, float* scratch){
  int lane = threadIdx.x & 63;
  int w    = threadIdx.x >> 6;
  #pragma unroll
  for (int off=32; off; off>>=1) v += __shfl_down(v, off, 64);
  __syncthreads();
  if (lane==0) scratch[w] = v;
  __syncthreads();
  float r = 0.f;
  if (threadIdx.x < 4) r = scratch[threadIdx.x];
  if (w==0){ r += __shfl_down(r, 2, 64); r += __shfl_down(r, 1, 64); }
  return r;
}

// ---- 64x64 tile helpers (LDS row stride 68 floats) ----
__device__ __forceinline__ void stage64(float (*S)[68], const float* __restrict__ g, int ld, int t){
  #pragma unroll
  for (int p=t; p<1024; p+=256)
    *(float4*)&S[p>>4][(p&15)*4] = *(const float4*)&g[(size_t)(p>>4)*ld + (p&15)*4];
}
__device__ __forceinline__ void tile_gemm_step(float acc[4][4], const float (*As)[68], const float (*Bs)[68], int tx, int ty){
  for (int k=0;k<64;++k){
    float ar[4], bc4[4];
    #pragma unroll
    for (int u=0;u<4;++u){ ar[u]=As[ty*4+u][k]; bc4[u]=Bs[k][tx*4+u]; }
    #pragma unroll
    for (int u=0;u<4;++u)
      #pragma unroll
      for (int v=0;v<4;++v) acc[u][v] += ar[u]*bc4[v];
  }
}

// ---- 128-wide helpers (LDS row stride LDW) ----
__device__ __forceinline__ void stage64h(float (*S)[LDW], int co, const float* __restrict__ g, int ld, int t){
  #pragma unroll
  for (int p=t; p<1024; p+=256)
    *(float4*)&S[p>>4][co + (p&15)*4] = *(const float4*)&g[(size_t)(p>>4)*ld + (p&15)*4];
}
__device__ __forceinline__ void syrk132(float acc[4][4], const float (*P)[LDW], const float (*Q)[LDW], int ko, int tx, int ty){
  for (int k=ko;k<ko+64;++k){
    float pr[4], qc[4];
    #pragma unroll
    for (int u=0;u<4;++u){ pr[u]=P[ty*4+u][k]; qc[u]=Q[tx*4+u][k]; }
    #pragma unroll
    for (int u=0;u<4;++u)
      #pragma unroll
      for (int v=0;v<4;++v) acc[u][v] += pr[u]*qc[v];
  }
}
// forward-solve one 128-row of S (LDS [*][LDW]) in-place vs 128 lower-tri Cs/sd.
// Blocked 64|64: full-unroll triangular solves; rolled rank-64 update reads
// the solved low half from LDS (runtime j must NOT index registers — v11 lesson).
__device__ __forceinline__ void trsm_row128(float* Srow, const float (*Cs)[LDW], const float* sd){
  float a[64];
  #pragma unroll
  for (int c4=0;c4<16;++c4) *(float4*)&a[c4*4] = *(const float4*)&Srow[c4*4];
  #pragma unroll
  for (int j=0;j<64;++j){
    float xj = a[j]*sd[j];
    a[j] = xj;
    #pragma unroll
    for (int cc=j+1;cc<64;++cc) a[cc] -= xj*Cs[cc][j];
  }
  #pragma unroll
  for (int c4=0;c4<16;++c4) *(float4*)&Srow[c4*4] = *(float4*)&a[c4*4];
  float b[64];
  #pragma unroll
  for (int c4=0;c4<16;++c4) *(float4*)&b[c4*4] = *(const float4*)&Srow[64+c4*4];
  for (int j=0;j<64;++j){               // rolled: xj from LDS (own row, just stored)
    float xj = Srow[j];
    #pragma unroll
    for (int cc=0;cc<64;++cc) b[cc] -= xj*Cs[64+cc][j];
  }
  #pragma unroll
  for (int j=0;j<64;++j){
    float xj = b[j]*sd[64+j];
    b[j] = xj;
    #pragma unroll
    for (int cc=j+1;cc<64;++cc) b[cc] -= xj*Cs[64+cc][64+j];
  }
  #pragma unroll
  for (int c4=0;c4<16;++c4) *(float4*)&Srow[64+c4*4] = *(float4*)&b[c4*4];
}

// wave-0 register Cholesky of a 64x64 LDS tile at S (row stride LDW);
// writes L -> lkd[d] AND back into S; inv-diag -> sdg (global) + sdl (LDS).
__device__ __forceinline__ void factor64_p(float* S, float* __restrict__ lkd,
    float* __restrict__ sdg_, float* sdl, int d, int t){
  if (t < 64){
    float xr[64];
    #pragma unroll
    for (int c4=0;c4<16;++c4) *(float4*)&xr[c4*4] = *(const float4*)&S[t*LDW + c4*4];
    float myrp = 1.f;
    #pragma unroll
    for (int j=0;j<64;++j){
      float ajj = __shfl(xr[j], j, 64);
      float piv = sqrtf(fmaxf(ajj, 1e-20f));
      float rp  = 1.f/piv;
      float val = xr[j]*rp;
      if (t==j){ xr[j] = piv; myrp = rp; }
      else if (t>j) xr[j] = val;
      else val = 0.f;
      #pragma unroll
      for (int c=j+1;c<64;++c){
        float vc = __shfl(val, c, 64);
        if (c<=t) xr[c] -= val*vc;
      }
    }
    #pragma unroll
    for (int c=0;c<64;++c) if (c>t) xr[c] = 0.f;
    #pragma unroll
    for (int c4=0;c4<16;++c4){
      *(float4*)&lkd[d*4096 + t*64 + c4*4] = *(float4*)&xr[c4*4];
      *(float4*)&S[t*LDW + c4*4] = *(float4*)&xr[c4*4];
    }
    sdg_[d*64 + t] = myrp;
    sdl[t] = myrp;
  }
}

// blocked 128x128 Cholesky of Cs (lower-stored: 11, 21, 22 quadrants filled).
// Writes lkdiag[rs], lkdiag[rs+1], internal L21 -> ltri(rs+1, rs), sdg.
__device__ void factor128(float (*Cs)[LDW], float* sd, float* __restrict__ lkd,
    float* __restrict__ sdg_, float* __restrict__ ltri, int rs, int t){
  factor64_p(&Cs[0][0], lkd, sdg_, sd, rs, t);
  __syncthreads();
  if (t < 64){   // TRSM row (64+t) of C21 vs C11
    float xr[64];
    #pragma unroll
    for (int c4=0;c4<16;++c4) *(float4*)&xr[c4*4] = *(const float4*)&Cs[64+t][c4*4];
    #pragma unroll
    for (int j=0;j<64;++j){
      float xj = xr[j]*sd[j];
      xr[j] = xj;
      #pragma unroll
      for (int cc=j+1;cc<64;++cc) xr[cc] -= xj*Cs[cc][j];
    }
    #pragma unroll
    for (int c4=0;c4<16;++c4) *(float4*)&Cs[64+t][c4*4] = *(float4*)&xr[c4*4];
  }
  __syncthreads();
  {
    const int tx = t & 15, ty = t >> 4;
    for (int p=t;p<1024;p+=256)   // publish internal L21 -> ltri(rs+1, rs)
      *(float4*)&ltri[(size_t)((rs+1)*64+(p>>4))*MM + rs*64 + (p&15)*4] =
          *(float4*)&Cs[64+(p>>4)][(p&15)*4];
    float acc[4][4] = {};         // C22 -= L21 L21^T
    for (int k=0;k<64;++k){
      float pr[4], qc[4];
      #pragma unroll
      for (int u=0;u<4;++u){ pr[u]=Cs[64+ty*4+u][k]; qc[u]=Cs[64+tx*4+u][k]; }
      #pragma unroll
      for (int u=0;u<4;++u)
        #pragma unroll
        for (int v=0;v<4;++v) acc[u][v] += pr[u]*qc[v];
    }
    #pragma unroll
    for (int u=0;u<4;++u)
      #pragma unroll
      for (int v=0;v<4;++v)
        Cs[64+ty*4+u][64+tx*4+v] -= acc[u][v];
  }
  __syncthreads();
  factor64_p(&Cs[64][64], lkd, sdg_, sd, rs+1, t);
}

// ================= factorization kernels (multi-launch) =================

// phase 0: all 528 lower Kuu tiles; grid = 528
__global__ __launch_bounds__(256) void phase0_kernel(
    const float* __restrict__ z, float* __restrict__ kuu){
  __shared__ float As[64][68];
  __shared__ float Bs[64][68];
  const int t = threadIdx.x, tx = t & 15, ty = t >> 4;
  int idx = blockIdx.x;
  int r=0; while ((r+1)*(r+2)/2 <= idx) ++r;
  int c = idx - r*(r+1)/2;
  for (int p=t; p<128; p+=256){ int i=p>>1, h=p&1;
    *(float4*)&As[i][h*4] = *(const float4*)&z[(size_t)(r*64+i)*DD + h*4];
    *(float4*)&Bs[i][h*4] = *(const float4*)&z[(size_t)(c*64+i)*DD + h*4]; }
  __syncthreads();
  #pragma unroll
  for (int u=0;u<4;++u){
    float4 o;
    float* ov = (float*)&o;
    #pragma unroll
    for (int v=0;v<4;++v){
      float d2=0.f;
      #pragma unroll
      for (int d=0;d<8;++d){ float df=As[ty*4+u][d]-Bs[tx*4+v][d]; d2+=df*df; }
      float val = __expf(-2.f*d2);
      if (r*64+ty*4+u == c*64+tx*4+v) val += 1e-6f;
      ov[v] = val;
    }
    *(float4*)&kuu[(size_t)(r*64+ty*4+u)*MM + c*64 + tx*4] = o;
  }
}

// initial 128-diag factor; grid = 1
__global__ __launch_bounds__(256) void diag128_0_kernel(
    const float* __restrict__ kuu, float* __restrict__ lkdiag,
    float* __restrict__ sdg, float* __restrict__ ltri){
  __shared__ float Cs[128][LDW];
  __shared__ float sd[128];
  const int t = threadIdx.x;
  for (int p=t;p<1024;p+=256){
    int r=p>>4, c0=(p&15)*4;
    *(float4*)&Cs[r][c0]       = *(const float4*)&kuu[(size_t)r*MM + c0];
    *(float4*)&Cs[64+r][c0]    = *(const float4*)&kuu[(size_t)(64+r)*MM + c0];
    *(float4*)&Cs[64+r][64+c0] = *(const float4*)&kuu[(size_t)(64+r)*MM + 64 + c0];
  }
  __syncthreads();
  factor128(Cs, sd, lkdiag, sdg, ltri, 0, t);
}

// panel kb (128-wide, kb=0..14): diag cols d0=2kb,d1=2kb+1; trailing rows
// rs=2kb+2..31. Block 0 owns the 3 next-diag tiles + lookahead factor128;
// blocks b>=1 handle tile idx b+2 (TRSM+SYRK+kuu RMW, v15 semantics).
__global__ __launch_bounds__(256) void panel128_kernel(
    float* __restrict__ kuu, float* __restrict__ lkdiag,
    float* __restrict__ sdg, float* __restrict__ ltri, int kb){
  __shared__ float As[64][LDW];
  __shared__ float Bs[64][LDW];
  __shared__ float Cs[128][LDW];
  __shared__ float sd[128];
  const int t = threadIdx.x, tx = t & 15, ty = t >> 4;
  const int d0 = 2*kb, d1 = 2*kb+1, rs = 2*kb+2;
  // stage panel-diag L (128x128 lower) + inv-diag
  for (int p=t;p<1024;p+=256){
    int r=p>>4, c0=(p&15)*4;
    *(float4*)&Cs[r][c0]       = *(const float4*)&lkdiag[d0*4096 + r*64 + c0];
    *(float4*)&Cs[64+r][c0]    = *(const float4*)&ltri[(size_t)(d1*64+r)*MM + d0*64 + c0];
    *(float4*)&Cs[64+r][64+c0] = *(const float4*)&lkdiag[d1*4096 + r*64 + c0];
  }
  if (t < 128) sd[t] = sdg[d0*64 + t];
  const int bid = blockIdx.x;
  const bool isdiag = (bid == 0);
  int bi = rs, bc = rs;
  if (!isdiag){
    int idx = bid + 2;
    int r=0; while ((r+1)*(r+2)/2 <= idx) ++r;
    int c = idx - r*(r+1)/2;
    bi = rs + r; bc = rs + c;
    stage64h(As, 0,  kuu + (size_t)(bi*64)*MM + d0*64, MM, t);
    stage64h(As, 64, kuu + (size_t)(bi*64)*MM + d1*64, MM, t);
    if (bc != bi){
      stage64h(Bs, 0,  kuu + (size_t)(bc*64)*MM + d0*64, MM, t);
      stage64h(Bs, 64, kuu + (size_t)(bc*64)*MM + d1*64, MM, t);
    }
  } else {
    stage64h(As, 0,  kuu + (size_t)(rs*64)*MM + d0*64, MM, t);
    stage64h(As, 64, kuu + (size_t)(rs*64)*MM + d1*64, MM, t);
    stage64h(Bs, 0,  kuu + (size_t)((rs+1)*64)*MM + d0*64, MM, t);
    stage64h(Bs, 64, kuu + (size_t)((rs+1)*64)*MM + d1*64, MM, t);
  }
  __syncthreads();
  {
    int w = t>>6, l = t&63;
    bool doB = isdiag || (bc != bi);
    if (w==0) trsm_row128(&As[l][0], (const float (*)[LDW])Cs, sd);
    else if (w==1 && doB) trsm_row128(&Bs[l][0], (const float (*)[LDW])Cs, sd);
  }
  __syncthreads();
  // publish final L columns of this panel
  if (isdiag){
    for (int p=t;p<1024;p+=256){
      int r=p>>4, c0=(p&15)*4;
      *(float4*)&ltri[(size_t)(rs*64+r)*MM + d0*64 + c0]     = *(float4*)&As[r][c0];
      *(float4*)&ltri[(size_t)(rs*64+r)*MM + d1*64 + c0]     = *(float4*)&As[r][64+c0];
      *(float4*)&ltri[(size_t)((rs+1)*64+r)*MM + d0*64 + c0] = *(float4*)&Bs[r][c0];
      *(float4*)&ltri[(size_t)((rs+1)*64+r)*MM + d1*64 + c0] = *(float4*)&Bs[r][64+c0];
    }
  } else if (bc == rs){
    for (int p=t;p<1024;p+=256){
      int r=p>>4, c0=(p&15)*4;
      *(float4*)&ltri[(size_t)(bi*64+r)*MM + d0*64 + c0] = *(float4*)&As[r][c0];
      *(float4*)&ltri[(size_t)(bi*64+r)*MM + d1*64 + c0] = *(float4*)&As[r][64+c0];
    }
  }
  if (!isdiag){
    float acc[4][4] = {};
    const float (*Q)[LDW] = (bc==bi)? (const float (*)[LDW])As : (const float (*)[LDW])Bs;
    syrk132(acc, (const float (*)[LDW])As, Q, 0,  tx, ty);
    syrk132(acc, (const float (*)[LDW])As, Q, 64, tx, ty);
    #pragma unroll
    for (int u=0;u<4;++u){
      float4* dst = (float4*)&kuu[(size_t)(bi*64+ty*4+u)*MM + bc*64 + tx*4];
      float4 o = *dst;
      o.x-=acc[u][0]; o.y-=acc[u][1]; o.z-=acc[u][2]; o.w-=acc[u][3];
      *dst = o;
    }
  } else {
    float a11[4][4]={}, a21[4][4]={}, a22[4][4]={};
    syrk132(a11, (const float (*)[LDW])As, (const float (*)[LDW])As, 0,  tx, ty);
    syrk132(a11, (const float (*)[LDW])As, (const float (*)[LDW])As, 64, tx, ty);
    syrk132(a21, (const float (*)[LDW])Bs, (const float (*)[LDW])As, 0,  tx, ty);
    syrk132(a21, (const float (*)[LDW])Bs, (const float (*)[LDW])As, 64, tx, ty);
    syrk132(a22, (const float (*)[LDW])Bs, (const float (*)[LDW])Bs, 0,  tx, ty);
    syrk132(a22, (const float (*)[LDW])Bs, (const float (*)[LDW])Bs, 64, tx, ty);
    __syncthreads();   // Cs (panel diag) no longer needed; reuse for S
    #pragma unroll
    for (int u=0;u<4;++u){
      float4 k11 = *(const float4*)&kuu[(size_t)(rs*64+ty*4+u)*MM + rs*64 + tx*4];
      Cs[ty*4+u][tx*4  ] = k11.x - a11[u][0];
      Cs[ty*4+u][tx*4+1] = k11.y - a11[u][1];
      Cs[ty*4+u][tx*4+2] = k11.z - a11[u][2];
      Cs[ty*4+u][tx*4+3] = k11.w - a11[u][3];
      float4 k21 = *(const float4*)&kuu[(size_t)((rs+1)*64+ty*4+u)*MM + rs*64 + tx*4];
      Cs[64+ty*4+u][tx*4  ] = k21.x - a21[u][0];
      Cs[64+ty*4+u][tx*4+1] = k21.y - a21[u][1];
      Cs[64+ty*4+u][tx*4+2] = k21.z - a21[u][2];
      Cs[64+ty*4+u][tx*4+3] = k21.w - a21[u][3];
      float4 k22 = *(const float4*)&kuu[(size_t)((rs+1)*64+ty*4+u)*MM + (rs+1)*64 + tx*4];
      Cs[64+ty*4+u][64+tx*4  ] = k22.x - a22[u][0];
      Cs[64+ty*4+u][64+tx*4+1] = k22.y - a22[u][1];
      Cs[64+ty*4+u][64+tx*4+2] = k22.z - a22[u][2];
      Cs[64+ty*4+u][64+tx*4+3] = k22.w - a22[u][3];
    }
    __syncthreads();
    factor128(Cs, sd, lkdiag, sdg, ltri, rs, t);
  }
}

// phase 2: invert 64x64 diagonal blocks; grid = 32
__global__ __launch_bounds__(256) void phase2_kernel(
    const float* __restrict__ lkdiag, float* __restrict__ linv){
  __shared__ float As[64][68];
  __shared__ float Bs[64][68];
  const int t = threadIdx.x, bid = blockIdx.x;
  stage64(As, lkdiag + bid*4096, 64, t);
  __syncthreads();
  if (t < 64){
    for (int j=0;j<64;++j){
      float s = (j==t)?1.f:0.f;
      for (int k=t;k<j;++k) s -= As[j][k]*Bs[k][t];
      Bs[j][t] = (j>=t)? s/As[j][j] : 0.f;
    }
  }
  __syncthreads();
  for (int p=t;p<1024;p+=256){ int i=p>>4, c4=p&15;
    *(float4*)&linv[(size_t)(bid*64+i)*MM + bid*64 + c4*4] = *(float4*)&Bs[i][c4*4]; }
}

// phase 3 level 0 (fused); grid = 16
__global__ __launch_bounds__(256) void p3l0_kernel(
    const float* __restrict__ ltri, float* __restrict__ linv){
  __shared__ float As[64][68];
  __shared__ float Bs[64][68];
  const int t = threadIdx.x, tx = t & 15, ty = t >> 4;
  int m = blockIdx.x;
  stage64(As, ltri + (size_t)((2*m+1)*64)*MM + (2*m)*64, MM, t);
  stage64(Bs, linv + (size_t)((2*m)*64)*MM   + (2*m)*64, MM, t);
  __syncthreads();
  float acc[4][4]={};
  tile_gemm_step(acc, As, Bs, tx, ty);
  __syncthreads();
  #pragma unroll
  for (int u=0;u<4;++u)
    #pragma unroll
    for (int v=0;v<4;++v) Bs[ty*4+u][tx*4+v] = acc[u][v];
  stage64(As, linv + (size_t)((2*m+1)*64)*MM + (2*m+1)*64, MM, t);
  __syncthreads();
  float o[4][4]={};
  tile_gemm_step(o, As, Bs, tx, ty);
  #pragma unroll
  for (int u=0;u<4;++u)
    *(float4*)&linv[(size_t)((2*m+1)*64+ty*4+u)*MM + (2*m)*64 + tx*4] =
        make_float4(-o[u][0],-o[u][1],-o[u][2],-o[u][3]);
}

// phase 3 level 1 (fused per-m); grid = 8
__global__ __launch_bounds__(256) void p3l1_kernel(
    const float* __restrict__ ltri, float* __restrict__ linv, float* __restrict__ ptmp){
  __shared__ float As[64][68];
  __shared__ float Bs[64][68];
  const int t = threadIdx.x, tx = t & 15, ty = t >> 4;
  int m = blockIdx.x;
  float* pm = ptmp + (size_t)m*128*128;
  for (int ti=0; ti<2; ++ti)
    for (int tj=0; tj<2; ++tj){
      int rb = m*4 + 2 + ti, cb0 = m*4;
      float acc[4][4]={};
      for (int k=tj; k<2; ++k){
        __syncthreads();
        stage64(As, ltri + (size_t)(rb*64)*MM + (cb0+k)*64, MM, t);
        stage64(Bs, linv + (size_t)((cb0+k)*64)*MM + (cb0+tj)*64, MM, t);
        __syncthreads();
        tile_gemm_step(acc, As, Bs, tx, ty);
      }
      #pragma unroll
      for (int u=0;u<4;++u)
        *(float4*)&pm[(size_t)(ti*64+ty*4+u)*128 + tj*64 + tx*4] =
            make_float4(acc[u][0],acc[u][1],acc[u][2],acc[u][3]);
    }
  for (int ti=0; ti<2; ++ti)
    for (int tj=0; tj<2; ++tj){
      int rb = m*4 + 2 + ti;
      float acc[4][4]={};
      for (int k=0; k<=ti; ++k){
        __syncthreads();
        stage64(As, linv + (size_t)(rb*64)*MM + (m*4+2+k)*64, MM, t);
        stage64(Bs, pm + (size_t)(k*64)*128 + tj*64, 128, t);
        __syncthreads();
        tile_gemm_step(acc, As, Bs, tx, ty);
      }
      #pragma unroll
      for (int u=0;u<4;++u)
        *(float4*)&linv[(size_t)(rb*64+ty*4+u)*MM + (m*4+tj)*64 + tx*4] =
            make_float4(-acc[u][0],-acc[u][1],-acc[u][2],-acc[u][3]);
    }
}

// phase 3 levels 2..4 part A (P = A21 @ Linv_lower); grid = mc*nb*nb
__global__ __launch_bounds__(256) void p3lA_kernel(
    const float* __restrict__ ltri, const float* __restrict__ linv,
    float* __restrict__ ptmp, int s){
  __shared__ float As[64][68];
  __shared__ float Bs[64][68];
  const int t = threadIdx.x, tx = t & 15, ty = t >> 4;
  int nb = 1<<s, b = 64<<s;
  float* pmb = ptmp + (s==2 ? 131072 : (s==3 ? 393216 : 917504));
  int idx = blockIdx.x;
  int m = idx/(nb*nb), r2 = idx%(nb*nb);
  int ti = r2/nb, tj = r2%nb;
  int rb = m*2*nb + nb + ti, cb0 = m*2*nb;
  float acc[4][4]={};
  for (int k=tj; k<nb; ++k){
    __syncthreads();
    stage64(As, ltri + (size_t)(rb*64)*MM + (cb0+k)*64, MM, t);
    stage64(Bs, linv + (size_t)((cb0+k)*64)*MM + (cb0+tj)*64, MM, t);
    __syncthreads();
    tile_gemm_step(acc, As, Bs, tx, ty);
  }
  float* pm = pmb + (size_t)m*b*b;
  #pragma unroll
  for (int u=0;u<4;++u)
    *(float4*)&pm[(size_t)(ti*64+ty*4+u)*b + tj*64 + tx*4] =
        make_float4(acc[u][0],acc[u][1],acc[u][2],acc[u][3]);
}

// phase 3 levels 2..4 part B (Linv21 = -Linv_lower @ P); grid = mc*nb*nb
__global__ __launch_bounds__(256) void p3lB_kernel(
    float* __restrict__ linv, const float* __restrict__ ptmp, int s){
  __shared__ float As[64][68];
  __shared__ float Bs[64][68];
  const int t = threadIdx.x, tx = t & 15, ty = t >> 4;
  int nb = 1<<s, b = 64<<s;
  const float* pmb = ptmp + (s==2 ? 131072 : (s==3 ? 393216 : 917504));
  int idx = blockIdx.x;
  int m = idx/(nb*nb), r2 = idx%(nb*nb);
  int ti = r2/nb, tj = r2%nb;
  int rb = m*2*nb + nb + ti;
  const float* pm = pmb + (size_t)m*b*b;
  float acc[4][4]={};
  for (int k=0; k<=ti; ++k){
    __syncthreads();
    stage64(As, linv + (size_t)(rb*64)*MM + (m*2*nb+nb+k)*64, MM, t);
    stage64(Bs, pm + (size_t)(k*64)*b + tj*64, b, t);
    __syncthreads();
    tile_gemm_step(acc, As, Bs, tx, ty);
  }
  #pragma unroll
  for (int u=0;u<4;++u)
    *(float4*)&linv[(size_t)(rb*64+ty*4+u)*MM + (m*2*nb+tj)*64 + tx*4] =
        make_float4(-acc[u][0],-acc[u][1],-acc[u][2],-acc[u][3]);
}

// phase 4a: W = Linv @ tril(qL), both GPs; grid = 2*528
__global__ __launch_bounds__(256) void w_kernel(
    const float* __restrict__ linv, const float* __restrict__ qlf,
    const float* __restrict__ qlg, float* __restrict__ wf, float* __restrict__ wg){
  __shared__ float As[64][68];
  __shared__ float Bs[64][68];
  const int t = threadIdx.x, tx = t & 15, ty = t >> 4;
  int idx = blockIdx.x;
  int gp = idx/528, rem = idx%528;
  int bi=0; while ((bi+1)*(bi+2)/2 <= rem) ++bi;
  int bj = rem - bi*(bi+1)/2;
  const float* ql = gp ? qlg : qlf;
  float* w        = gp ? wg  : wf;
  float acc[4][4]={};
  for (int bk=bj; bk<=bi; ++bk){
    __syncthreads();
    stage64(As, linv + (size_t)(bi*64)*MM + bk*64, MM, t);
    stage64(Bs, ql   + (size_t)(bk*64)*MM + bj*64, MM, t);
    __syncthreads();
    if (bk==bj){
      for (int p=t;p<4096;p+=256){ int i=p>>6, c=p&63; if (i<c) Bs[i][c]=0.f; }
      __syncthreads();
    }
    tile_gemm_step(acc, As, Bs, tx, ty);
  }
  #pragma unroll
  for (int u=0;u<4;++u)
    *(float4*)&w[(size_t)(bi*64+ty*4+u)*MM + bj*64 + tx*4] =
        make_float4(acc[u][0],acc[u][1],acc[u][2],acc[u][3]);
}

// phase 4b: alpha = Linv @ qm, both GPs; grid = 256
__global__ __launch_bounds__(256) void alpha_kernel(
    const float* __restrict__ linv, const float* __restrict__ qmf,
    const float* __restrict__ qmg, float* __restrict__ af, float* __restrict__ ag){
  int t = threadIdx.x;
  int gw = blockIdx.x*4 + (t>>6), l = t&63;
  for (int job=gw; job<4096; job+=1024){
    int gp = job>>11, r = job&2047;
    const float* qm = gp ? qmg : qmf;
    float s=0.f;
    for (int c=l; c<=r; c+=64) s += linv[(size_t)r*MM+c]*qm[c];
    #pragma unroll
    for (int off=32; off; off>>=1) s += __shfl_down(s, off, 64);
    if (l==0) (gp ? ag : af)[r] = s;
  }
}

// ================= small kernels (pre/post) =================

__global__ __launch_bounds__(256) void zfrag_kernel(const float* __restrict__ z,
    short* __restrict__ zfh, short* __restrict__ zfl, float* __restrict__ zn2){
  int zr = blockIdx.x*256 + threadIdx.x;
  float v[DD]; float s = 0.f;
  #pragma unroll
  for (int d=0; d<DD; ++d){ v[d] = z[zr*DD + d]; s += v[d]*v[d]; }
  zn2[zr] = s;
  size_t base = (size_t)(zr >> 4)*512 + (zr & 15)*32;
  #pragma unroll
  for (int k=0; k<32; ++k){
    short h = 0, lo = 0;
    if (k < DD) bfsplit(v[k], h, lo);
    zfh[base + k] = h; zfl[base + k] = lo;
  }
}

__global__ __launch_bounds__(256) void red_small(const float* __restrict__ lkd,
    const float* __restrict__ qlf, const float* __restrict__ qlg,
    const float* __restrict__ af, const float* __restrict__ ag,
    float* __restrict__ scal){
  __shared__ float scratch[4];
  float ldk=0, ldf=0, ldg=0, a2f=0, a2g=0;
  for (int i=threadIdx.x;i<MM;i+=256){
    int kb = i>>6, r = i&63;
    ldk += __logf(lkd[kb*4096 + r*64 + r]);
    ldf += __logf(fabsf(qlf[(size_t)i*MM+i]));
    ldg += __logf(fabsf(qlg[(size_t)i*MM+i]));
    float v = af[i]; a2f += v*v;
    v = ag[i];       a2g += v*v;
  }
  float r;
  r = block_reduce(ldk, scratch); if (threadIdx.x==0) scal[0] = 2.f*r;
  r = block_reduce(ldf, scratch); if (threadIdx.x==0) scal[1] = 2.f*r;
  r = block_reduce(ldg, scratch); if (threadIdx.x==0) scal[2] = 2.f*r;
  r = block_reduce(a2f, scratch); if (threadIdx.x==0) scal[3] = r;
  r = block_reduce(a2g, scratch); if (threadIdx.x==0) scal[4] = r;
}

__global__ __launch_bounds__(256) void redw_kernel(const float* __restrict__ wf,
    const float* __restrict__ wg, float* __restrict__ scal){
  __shared__ float scratch[4];
  size_t start  = (size_t)blockIdx.x*256 + threadIdx.x;
  size_t stride = (size_t)gridDim.x*256;
  float sf=0, sg=0;
  for (size_t p=start;p<(size_t)MM*MM;p+=stride){
    float v=wf[p]; sf += v*v;
    v=wg[p];       sg += v*v;
  }
  float r = block_reduce(sf, scratch);
  if (threadIdx.x==0) atomicAdd(&scal[5], r);
  r = block_reduce(sg, scratch);
  if (threadIdx.x==0) atomicAdd(&scal[6], r);
}

__global__ void kl_kernel(const float* __restrict__ scal, float* __restrict__ out){
  float klf = 0.5f*(scal[5] + scal[3] - (float)MM + scal[0] - scal[1]);
  float klg = 0.5f*(scal[6] + scal[4] - (float)MM + scal[0] - scal[2]);
  out[0] += klf + klg;
}

__global__ __launch_bounds__(256) void split_rowmajor(const float* __restrict__ src,
    short* __restrict__ dh, short* __restrict__ dl){
  int p = blockIdx.x*256 + threadIdx.x;
  int chunk = p >> 9, wi = p & 511;
  int mo = chunk >> 6, ko = chunk & 63;
  int row = mo*16 + (wi >> 5), col = ko*32 + (wi & 31);
  float v = src[(size_t)row*MM + col];
  short h, lo; bfsplit(v, h, lo);
  dh[p] = h; dl[p] = lo;
}

__global__ __launch_bounds__(256) void split_transpose(const float* __restrict__ src,
    short* __restrict__ dh, short* __restrict__ dl){
  __shared__ float tile[32][33];
  int t = threadIdx.x;
  int mb = blockIdx.x, kb = blockIdx.y;
  #pragma unroll
  for (int k=0;k<4;++k){
    int idx = t + k*256;
    int lr = idx >> 5, lc = idx & 31;
    tile[lr][lc] = src[(size_t)(kb*32+lr)*MM + mb*32 + lc];
  }
  __syncthreads();
  #pragma unroll
  for (int e=0;e<4;++e){
    int p = t*4 + e;
    int c = p >> 9, wi = p & 511;
    int i = (wi >> 5) & 15, kk = wi & 31;
    float v = tile[kk][c*16 + i];
    short h, lo; bfsplit(v, h, lo);
    size_t gp = ((size_t)(mb*2 + c)*64 + kb)*512 + wi;
    dh[gp] = h; dl[gp] = lo;
  }
}

__global__ __launch_bounds__(256, 2) void tt_mfma(
    const float* __restrict__ x, const float* __restrict__ zn2,
    const short* __restrict__ zfh, const short* __restrict__ zfl,
    const short* __restrict__ lvh, const short* __restrict__ lvl,
    short* __restrict__ tth, short* __restrict__ ttl){
  __shared__ __align__(16) short lAh[8192], lAl[8192], lBh[8192], lBl[8192];
  int t = threadIdx.x;
  int l = t & 63, w = t >> 6;
  int istrip = blockIdx.x, bj2 = blockIdx.y;
  int li = l & 15, q = l >> 4;
  int lofs = li*32 + q*8;
  int wn4 = (w>>1)*4, wm4 = (w&1)*4;

  short8 xh[2], xl[2];
  float xn2v[8];
  {
    float xn2t[2];
    #pragma unroll
    for (int tn=0; tn<2; ++tn){
      int n = istrip*128 + w*32 + tn*16 + li;
      const float4* xp = (const float4*)(x + (size_t)n*DD);
      float4 p0 = xp[0], p1 = xp[1];
      float v[8] = {p0.x,p0.y,p0.z,p0.w,p1.x,p1.y,p1.z,p1.w};
      float s = 0.f;
      #pragma unroll
      for (int d=0; d<8; ++d) s += v[d]*v[d];
      xn2t[tn] = s;
      short8 hh, ll;
      #pragma unroll
      for (int j=0; j<8; ++j){
        short h=0, lo=0;
        if (q==0) bfsplit(v[j], h, lo);
        hh[j]=h; ll[j]=lo;
      }
      xh[tn]=hh; xl[tn]=ll;
    }
    #pragma unroll
    for (int tn=0; tn<2; ++tn)
      #pragma unroll
      for (int r=0; r<4; ++r)
        xn2v[tn*4+r] = __shfl(xn2t[tn], q*4 + r, 64);
  }

  float4v acc[4][4];
  #pragma unroll
  for (int i=0;i<4;++i)
    #pragma unroll
    for (int j=0;j<4;++j) acc[i][j] = f4zero();

  int nkt = 2*bj2 + 2;
  for (int bk=0; bk<nkt; ++bk){
    __syncthreads();
    {
      short8 zh[4], zl[4];
      float zt2[4];
      #pragma unroll
      for (int tz=0; tz<4; ++tz){
        size_t zo = (size_t)(bk*4 + tz)*512 + lofs;
        zh[tz] = *(const short8*)(zfh + zo);
        zl[tz] = *(const short8*)(zfl + zo);
        zt2[tz] = zn2[bk*64 + tz*16 + li];
      }
      #pragma unroll
      for (int tn=0; tn<2; ++tn){
        #pragma unroll
        for (int tz=0; tz<4; ++tz){
          float4v s4 = mfma3(xh[tn], xl[tn], zh[tz], zl[tz], f4zero());
          #pragma unroll
          for (int r=0; r<4; ++r){
            float e = __expf(4.f*s4[r] - 2.f*(xn2v[tn*4+r] + zt2[tz]));
            short h, lo; bfsplit(e, h, lo);
            int pos = ((w*2+tn)*2 + (tz>>1))*512 + (q*4+r)*32 + (tz&1)*16 + li;
            lAh[pos] = h; lAl[pos] = lo;
          }
        }
      }
    }
    #pragma unroll
    for (int c4 = t; c4 < 1024; c4 += 256){
      int ch = c4 >> 6, wdi = c4 & 63;
      size_t g = ((size_t)(bj2*8 + (ch>>1))*64 + (size_t)(bk*2 + (ch&1)))*64 + wdi;
      ((uint4*)lBh)[c4] = ((const uint4*)lvh)[g];
      ((uint4*)lBl)[c4] = ((const uint4*)lvl)[g];
    }
    __syncthreads();
    #pragma unroll
    for (int s=0; s<2; ++s){
      short8 ah[4], al[4], bh[4], bl[4];
      #pragma unroll
      for (int tn=0; tn<4; ++tn){
        int off = ((wn4+tn)*2 + s)*512 + lofs;
        ah[tn] = *(const short8*)&lAh[off];
        al[tn] = *(const short8*)&lAl[off];
      }
      #pragma unroll
      for (int tm=0; tm<4; ++tm){
        int off = ((wm4+tm)*2 + s)*512 + lofs;
        bh[tm] = *(const short8*)&lBh[off];
        bl[tm] = *(const short8*)&lBl[off];
      }
      #pragma unroll
      for (int tn=0; tn<4; ++tn)
        #pragma unroll
        for (int tm=0; tm<4; ++tm)
          acc[tn][tm] = mfma3(ah[tn], al[tn], bh[tm], bl[tm], acc[tn][tm]);
    }
  }
  #pragma unroll
  for (int tn=0; tn<4; ++tn){
    int no_g = istrip*8 + wn4 + tn;
    #pragma unroll
    for (int tm=0; tm<4; ++tm){
      int mo_g = bj2*4 + (w&1)*2 + (tm>>1);
      size_t cb = ((size_t)no_g*64 + mo_g)*512;
      #pragma unroll
      for (int r=0; r<4; ++r){
        short h, lo; bfsplit(acc[tn][tm][r], h, lo);
        size_t pos = cb + (q*4+r)*32 + (tm&1)*16 + li;
        tth[pos] = h; ttl[pos] = lo;
      }
    }
  }
}

__global__ __launch_bounds__(256) void lin_v2(const short* __restrict__ tth,
    const short* __restrict__ ttl, const float* __restrict__ af, const float* __restrict__ ag,
    float* __restrict__ t2, float* __restrict__ lf, float* __restrict__ lg){
  int t = threadIdx.x;
  int w = t >> 6, l = t & 63;
  int n = blockIdx.x*4 + w;
  int g = l >> 2, j = l & 3;
  float s2=0.f, sf=0.f, sg=0.f;
  #pragma unroll
  for (int it=0; it<4; ++it){
    int ck = g + it*16;
    size_t off = ((size_t)(n>>4)*64 + ck)*512 + (n&15)*32 + j*8;
    short8 h8 = *(const short8*)(tth + off);
    short8 l8 = *(const short8*)(ttl + off);
    int m0 = ck*32 + j*8;
    float4 a0 = *(const float4*)(af + m0), a1 = *(const float4*)(af + m0 + 4);
    float4 g0 = *(const float4*)(ag + m0), g1 = *(const float4*)(ag + m0 + 4);
    float av[8] = {a0.x,a0.y,a0.z,a0.w,a1.x,a1.y,a1.z,a1.w};
    float gv[8] = {g0.x,g0.y,g0.z,g0.w,g1.x,g1.y,g1.z,g1.w};
    #pragma unroll
    for (int e=0; e<8; ++e){
      float tv = bf2f(h8[e]) + bf2f(l8[e]);
      s2 += tv*tv; sf += tv*av[e]; sg += tv*gv[e];
    }
  }
  #pragma unroll
  for (int off=32; off; off>>=1){
    s2 += __shfl_down(s2, off, 64);
    sf += __shfl_down(sf, off, 64);
    sg += __shfl_down(sg, off, 64);
  }
  if (l==0){ t2[n] = s2; lf[n] = sf; lg[n] = sg; }
}

__global__ __launch_bounds__(256, 2) void quad_mfma(
    const short* __restrict__ tth, const short* __restrict__ ttl,
    const short* __restrict__ wfh, const short* __restrict__ wfl,
    const short* __restrict__ wgh, const short* __restrict__ wgl,
    float* __restrict__ vfq, float* __restrict__ vgq){
  __shared__ __align__(16) short lAh[8192], lAl[8192], lBh[8192], lBl[8192];
  int t = threadIdx.x, l = t & 63, w = t >> 6;
  int istrip = blockIdx.x, bj2 = blockIdx.y;
  const short* gbh = blockIdx.z ? wgh : wfh;
  const short* gbl = blockIdx.z ? wgl : wfl;
  float* vq = blockIdx.z ? vgq : vfq;
  int li = l & 15, q = l >> 4;
  int lofs = li*32 + q*8;
  int wn4 = (w>>1)*4, wm4 = (w&1)*4;

  float4v acc[4][4];
  #pragma unroll
  for (int i=0;i<4;++i)
    #pragma unroll
    for (int j=0;j<4;++j) acc[i][j] = f4zero();

  for (int bk=2*bj2; bk<32; ++bk){
    __syncthreads();
    #pragma unroll
    for (int c4 = t; c4 < 1024; c4 += 256){
      int ch = c4 >> 6, wdi = c4 & 63;
      size_t ga = ((size_t)(istrip*8 + (ch>>1))*64 + (size_t)(bk*2 + (ch&1)))*64 + wdi;
      ((uint4*)lAh)[c4] = ((const uint4*)tth)[ga];
      ((uint4*)lAl)[c4] = ((const uint4*)ttl)[ga];
      size_t gb = ((size_t)(bj2*8 + (ch>>1))*64 + (size_t)(bk*2 + (ch&1)))*64 + wdi;
      ((uint4*)lBh)[c4] = ((const uint4*)gbh)[gb];
      ((uint4*)lBl)[c4] = ((const uint4*)gbl)[gb];
    }
    __syncthreads();
    #pragma unroll
    for (int s=0; s<2; ++s){
      short8 ah[4], al[4], bh[4], bl[4];
      #pragma unroll
      for (int tn=0; tn<4; ++tn){
        int off = ((wn4+tn)*2 + s)*512 + lofs;
        ah[tn] = *(const short8*)&lAh[off];
        al[tn] = *(const short8*)&lAl[off];
      }
      #pragma unroll
      for (int tm=0; tm<4; ++tm){
        int off = ((wm4+tm)*2 + s)*512 + lofs;
        bh[tm] = *(const short8*)&lBh[off];
        bl[tm] = *(const short8*)&lBl[off];
      }
      #pragma unroll
      for (int tn=0; tn<4; ++tn)
        #pragma unroll
        for (int tm=0; tm<4; ++tm)
          acc[tn][tm] = mfma3(ah[tn], al[tn], bh[tm], bl[tm], acc[tn][tm]);
    }
  }
  float rs[16];
  #pragma unroll
  for (int tn=0; tn<4; ++tn)
    #pragma unroll
    for (int r=0; r<4; ++r){
      float s = 0.f;
      #pragma unroll
      for (int tm=0; tm<4; ++tm){ float v = acc[tn][tm][r]; s += v*v; }
      rs[tn*4+r] = s;
    }
  #pragma unroll
  for (int off=8; off; off>>=1)
    #pragma unroll
    for (int k=0; k<16; ++k) rs[k] += __shfl_down(rs[k], off, 16);
  if (li == 0){
    #pragma unroll
    for (int tn=0; tn<4; ++tn)
      #pragma unroll
      for (int r=0; r<4; ++r){
        int n = istrip*128 + (w>>1)*64 + tn*16 + q*4 + r;
        atomicAdd(&vq[n], rs[tn*4+r]);
      }
  }
}

__global__ __launch_bounds__(256) void final_kernel(const float* __restrict__ y,
    const float* __restrict__ t2, const float* __restrict__ lf, const float* __restrict__ lg,
    const float* __restrict__ vfq, const float* __restrict__ vgq, float* __restrict__ out){
  __shared__ float scratch[4];
  int i = blockIdx.x*256 + threadIdx.x;
  float mf = lf[i], mg = lg[i];
  float vf = 1.f + vfq[i] - t2[i];
  float vg = 1.f + vgq[i] - t2[i];
  float dy = y[i] - mf;
  float e = -HLOG2PI - 0.5f*mg - 0.5f*(dy*dy + vf)*__expf(-mg + 0.5f*vg);
  float r = block_reduce(e, scratch);
  if (threadIdx.x==0) atomicAdd(out, -r);
}

extern "C" void kernel_launch(void* const* d_in, const int* in_sizes, int n_in,
                              void* d_out, int out_size, void* d_ws, size_t ws_size,
                              hipStream_t stream){
  (void)in_sizes; (void)n_in; (void)out_size; (void)ws_size;
  const float* x   = (const float*)d_in[0];
  const float* y   = (const float*)d_in[1];
  const float* z   = (const float*)d_in[2];
  const float* qmf = (const float*)d_in[3];
  const float* qlf = (const float*)d_in[4];
  const float* qmg = (const float*)d_in[5];
  const float* qlg = (const float*)d_in[6];
  float* out = (float*)d_out;
  char* Bw = (char*)d_ws;

  float* kuu  = (float*)Bw;
  float* linv = (float*)(Bw + SZB);
  float* wf   = (float*)(Bw + 2*SZB);
  float* wg   = (float*)(Bw + 3*SZB);
  short* lvh  = (short*)Bw;
  short* lvl  = (short*)(Bw + SZB/2);
  short* wfh  = (short*)(Bw + SZB);
  short* wfl  = (short*)(Bw + SZB + SZB/2);
  short* wgh  = (short*)(Bw + 2*SZB);
  short* wgl  = (short*)(Bw + 2*SZB + SZB/2);
  short* tth  = (short*)(Bw + 3*SZB);
  short* ttl  = (short*)(Bw + 3*SZB + (size_t)NN*MM*2);
  // dead-tt region [64M,112M): ltri 16MB, ptmp 8MB (per-level disjoint),
  // lkdiag 512KB, sdg 8KB
  float* ltri   = (float*)(Bw + 4*SZB);
  float* ptmp   = (float*)(Bw + 5*SZB);
  float* lkdiag = (float*)(Bw + 5*SZB + (size_t)8388608);
  float* sdg    = (float*)(Bw + 5*SZB + (size_t)8388608 + (size_t)524288);
  float* sm   = (float*)(Bw + 3*SZB + (size_t)NN*MM*4);
  float* af = sm;          float* ag = af + MM;
  float* t2 = ag + MM;     float* lf = t2 + NN;   float* lg = lf + NN;
  float* vfq = lg + NN;    float* vgq = vfq + NN; float* scal = vgq + NN;
  float* zn2 = scal + 64 + 2048;
  short* zfh = (short*)(zn2 + MM);
  short* zfl = zfh + MM*32;

  hipMemsetAsync(out, 0, sizeof(float), stream);
  hipMemsetAsync(vfq, 0, (size_t)(2*NN + 64 + 2048)*sizeof(float), stream); // vfq,vgq,scal
  hipMemsetAsync(wf,  0, 2*SZB, stream);    // W upper triangles must be 0
  hipMemsetAsync(linv,0, SZB,   stream);    // Linv upper must be 0

  zfrag_kernel<<<MM/256, 256, 0, stream>>>(z, zfh, zfl, zn2);

  // ---- factorization: multi-launch, 128-wide panels ----
  phase0_kernel<<<528, 256, 0, stream>>>(z, kuu);
  diag128_0_kernel<<<1, 256, 0, stream>>>(kuu, lkdiag, sdg, ltri);
  for (int kb = 0; kb < 15; ++kb){
    int T = 30 - 2*kb;                       // trailing 64-rows
    int ntiles = T*(T+1)/2;
    panel128_kernel<<<ntiles - 2, 256, 0, stream>>>(kuu, lkdiag, sdg, ltri, kb);
  }
  phase2_kernel<<<NB, 256, 0, stream>>>(lkdiag, linv);
  p3l0_kernel<<<16, 256, 0, stream>>>(ltri, linv);
  p3l1_kernel<<<8, 256, 0, stream>>>(ltri, linv, ptmp);
  for (int s = 2; s < 5; ++s){
    int nb = 1<<s, mc = 16>>s;
    p3lA_kernel<<<mc*nb*nb, 256, 0, stream>>>(ltri, linv, ptmp, s);
    p3lB_kernel<<<mc*nb*nb, 256, 0, stream>>>(linv, ptmp, s);
  }
  w_kernel<<<2*528, 256, 0, stream>>>(linv, qlf, qlg, wf, wg);
  alpha_kernel<<<256, 256, 0, stream>>>(linv, qmf, qmg, af, ag);

  red_small<<<1, 256, 0, stream>>>(lkdiag, qlf, qlg, af, ag, scal);
  redw_kernel<<<512, 256, 0, stream>>>(wf, wg, scal);
  kl_kernel<<<1, 1, 0, stream>>>(scal, out);

  split_rowmajor<<<MM*MM/256, 256, 0, stream>>>(linv, lvh, lvl);
  split_transpose<<<dim3(MM/32, MM/32), 256, 0, stream>>>(wf, wfh, wfl);
  split_transpose<<<dim3(MM/32, MM/32), 256, 0, stream>>>(wg, wgh, wgl);

  tt_mfma<<<dim3(NN/128, MM/128), 256, 0, stream>>>(x, zn2, zfh, zfl, lvh, lvl, tth, ttl);
  lin_v2<<<NN/4, 256, 0, stream>>>(tth, ttl, af, ag, t2, lf, lg);
  quad_mfma<<<dim3(NN/128, MM/128, 2), 256, 0, stream>>>(tth, ttl, wfh, wfl, wgh, wgl, vfq, vgq);
  final_kernel<<<NN/256, 256, 0, stream>>>(y, t2, lf, lg, vfq, vgq, out);
}

// Round 10
// 4359.439 us; speedup vs baseline: 1.1248x; 1.1248x over previous
//
#include <hip/hip_runtime.h>
#include <math.h>

// ChainedGP v17: v15 (multi-launch, best@3914us; v16's 128-wide panels
// regressed +1000us via serial-pole inflation and is reverted) with NINE
// launches removed at zero pole cost and zero numerical change:
//  (1) zfrag + diag0 fused into phase0 (grid 536; block 0 factors Kuu(0,0))
//  (2) panels kb=27..30 (20 tiles) -> ONE single-block tail_kernel (next-diag
//      factor kept in LDS Ds/sd2; tiles sequential with __syncthreads)
//  (3) phase2 + p3l0 + p3l1 -> ONE 8-block p3head (all deps block-local)
//  (4) split_rowmajor + 2x split_transpose -> ONE split_all
// red_small/redw/kl/w/alpha/tt/lin/quad/final byte-identical to v15 =>
// identical reduction orders => absmax unchanged.
#define NN 16384
#define MM 2048
#define DD 8
#define NB 32                     // MM/64
#define SZB ((size_t)16777216)    // 2048*2048*4 bytes

constexpr float HLOG2PI = 0.91893853320467274178f;

using short8  = __attribute__((ext_vector_type(8))) short;
using float4v = __attribute__((ext_vector_type(4))) float;

__device__ __forceinline__ float4v f4zero(){ float4v v; v[0]=0.f; v[1]=0.f; v[2]=0.f; v[3]=0.f; return v; }

__device__ __forceinline__ void bfsplit(float v, short& h, short& lo){
  unsigned b = __float_as_uint(v);
  h = (short)(b >> 16);
  float hf = __uint_as_float(b & 0xFFFF0000u);
  lo = (short)(__float_as_uint(v - hf) >> 16);
}
__device__ __forceinline__ float bf2f(short s){
  return __uint_as_float(((unsigned)(unsigned short)s) << 16);
}
__device__ __forceinline__ float4v mfma3(short8 ah, short8 al, short8 bh, short8 bl, float4v c){
  c = __builtin_amdgcn_mfma_f32_16x16x32_bf16(ah, bh, c, 0, 0, 0);
  c = __builtin_amdgcn_mfma_f32_16x16x32_bf16(ah, bl, c, 0, 0, 0);
  c = __builtin_amdgcn_mfma_f32_16x16x32_bf16(al, bh, c, 0, 0, 0);
  return c;
}

__device__ __forceinline__ float block_reduce(float v, float* scratch){
  int lane = threadIdx.x & 63;
  int w    = threadIdx.x >> 6;
  #pragma unroll
  for (int off=32; off; off>>=1) v += __shfl_down(v, off, 64);
  __syncthreads();
  if (lane==0) scratch[w] = v;
  __syncthreads();
  float r = 0.f;
  if (threadIdx.x < 4) r = scratch[threadIdx.x];
  if (w==0){ r += __shfl_down(r, 2, 64); r += __shfl_down(r, 1, 64); }
  return r;
}

// ---- 64x64 tile helpers (LDS row stride 68 floats) ----
__device__ __forceinline__ void stage64(float (*S)[68], const float* __restrict__ g, int ld, int t){
  #pragma unroll
  for (int p=t; p<1024; p+=256)
    *(float4*)&S[p>>4][(p&15)*4] = *(const float4*)&g[(size_t)(p>>4)*ld + (p&15)*4];
}
__device__ __forceinline__ void tile_gemm_step(float acc[4][4], const float (*As)[68], const float (*Bs)[68], int tx, int ty){
  for (int k=0;k<64;++k){
    float ar[4], bc4[4];
    #pragma unroll
    for (int u=0;u<4;++u){ ar[u]=As[ty*4+u][k]; bc4[u]=Bs[k][tx*4+u]; }
    #pragma unroll
    for (int u=0;u<4;++u)
      #pragma unroll
      for (int v=0;v<4;++v) acc[u][v] += ar[u]*bc4[v];
  }
}
__device__ __forceinline__ void tile_syrk_step(float acc[4][4], const float (*P)[68], const float (*Q)[68], int tx, int ty){
  for (int k=0;k<64;++k){
    float pr[4], qc[4];
    #pragma unroll
    for (int u=0;u<4;++u){ pr[u]=P[ty*4+u][k]; qc[u]=Q[tx*4+u][k]; }
    #pragma unroll
    for (int u=0;u<4;++u)
      #pragma unroll
      for (int v=0;v<4;++v) acc[u][v] += pr[u]*qc[v];
  }
}

// wave-0 register Cholesky of a 64x64 tile staged in S (LDS); no __syncthreads.
__device__ __forceinline__ void factor64_reg(const float (*S)[68],
    float* __restrict__ lkd, float* __restrict__ sdg_, int d, int t){
  if (t < 64){
    float xr[64];
    #pragma unroll
    for (int c4=0;c4<16;++c4) *(float4*)&xr[c4*4] = *(const float4*)&S[t][c4*4];
    float myrp = 1.f;
    #pragma unroll
    for (int j=0;j<64;++j){
      float ajj = __shfl(xr[j], j, 64);
      float piv = sqrtf(fmaxf(ajj, 1e-20f));
      float rp  = 1.f/piv;
      float val = xr[j]*rp;
      if (t==j){ xr[j] = piv; myrp = rp; }
      else if (t>j) xr[j] = val;
      else val = 0.f;
      #pragma unroll
      for (int c=j+1;c<64;++c){
        float vc = __shfl(val, c, 64);
        if (c<=t) xr[c] -= val*vc;
      }
    }
    #pragma unroll
    for (int c=0;c<64;++c) if (c>t) xr[c] = 0.f;
    #pragma unroll
    for (int c4=0;c4<16;++c4)
      *(float4*)&lkd[d*4096 + t*64 + c4*4] = *(float4*)&xr[c4*4];
    sdg_[d*64 + t] = myrp;
  }
}

// tail variant: also writes L into LDS D and inv-diag into LDS sdl
__device__ __forceinline__ void factor64_t(const float (*S)[68], float (*D)[68],
    float* sdl, float* __restrict__ lkd, float* __restrict__ sdg_, int d, int t){
  if (t < 64){
    float xr[64];
    #pragma unroll
    for (int c4=0;c4<16;++c4) *(float4*)&xr[c4*4] = *(const float4*)&S[t][c4*4];
    float myrp = 1.f;
    #pragma unroll
    for (int j=0;j<64;++j){
      float ajj = __shfl(xr[j], j, 64);
      float piv = sqrtf(fmaxf(ajj, 1e-20f));
      float rp  = 1.f/piv;
      float val = xr[j]*rp;
      if (t==j){ xr[j] = piv; myrp = rp; }
      else if (t>j) xr[j] = val;
      else val = 0.f;
      #pragma unroll
      for (int c=j+1;c<64;++c){
        float vc = __shfl(val, c, 64);
        if (c<=t) xr[c] -= val*vc;
      }
    }
    #pragma unroll
    for (int c=0;c<64;++c) if (c>t) xr[c] = 0.f;
    #pragma unroll
    for (int c4=0;c4<16;++c4){
      *(float4*)&lkd[d*4096 + t*64 + c4*4] = *(float4*)&xr[c4*4];
      *(float4*)&D[t][c4*4] = *(float4*)&xr[c4*4];
    }
    sdg_[d*64 + t] = myrp;
    sdl[t] = myrp;
  }
}

// ================= factorization kernels (multi-launch) =================

// phase 0: 528 Kuu tiles + (blocks 528..535) zfrag; block 0 factors diag(0).
__global__ __launch_bounds__(256) void phase0_kernel(
    const float* __restrict__ z, float* __restrict__ kuu,
    short* __restrict__ zfh, short* __restrict__ zfl, float* __restrict__ zn2,
    float* __restrict__ lkdiag, float* __restrict__ sdg){
  __shared__ float As[64][68];
  __shared__ float Bs[64][68];
  const int t = threadIdx.x, tx = t & 15, ty = t >> 4;
  const int bid = blockIdx.x;
  if (bid >= 528){
    int zr = (bid-528)*256 + t;
    float v[DD]; float s = 0.f;
    #pragma unroll
    for (int d=0; d<DD; ++d){ v[d] = z[zr*DD + d]; s += v[d]*v[d]; }
    zn2[zr] = s;
    size_t base = (size_t)(zr >> 4)*512 + (zr & 15)*32;
    #pragma unroll
    for (int k=0; k<32; ++k){
      short h = 0, lo = 0;
      if (k < DD) bfsplit(v[k], h, lo);
      zfh[base + k] = h; zfl[base + k] = lo;
    }
    return;
  }
  int idx = bid;
  int r=0; while ((r+1)*(r+2)/2 <= idx) ++r;
  int c = idx - r*(r+1)/2;
  for (int p=t; p<128; p+=256){ int i=p>>1, h=p&1;
    *(float4*)&As[i][h*4] = *(const float4*)&z[(size_t)(r*64+i)*DD + h*4];
    *(float4*)&Bs[i][h*4] = *(const float4*)&z[(size_t)(c*64+i)*DD + h*4]; }
  __syncthreads();
  float kv[4][4];
  #pragma unroll
  for (int u=0;u<4;++u)
    #pragma unroll
    for (int v=0;v<4;++v){
      float d2=0.f;
      #pragma unroll
      for (int d=0;d<8;++d){ float df=As[ty*4+u][d]-Bs[tx*4+v][d]; d2+=df*df; }
      float val = __expf(-2.f*d2);
      if (r*64+ty*4+u == c*64+tx*4+v) val += 1e-6f;
      kv[u][v] = val;
    }
  #pragma unroll
  for (int u=0;u<4;++u)
    *(float4*)&kuu[(size_t)(r*64+ty*4+u)*MM + c*64 + tx*4] =
        make_float4(kv[u][0],kv[u][1],kv[u][2],kv[u][3]);
  if (idx == 0){
    __syncthreads();
    #pragma unroll
    for (int u=0;u<4;++u)
      #pragma unroll
      for (int v=0;v<4;++v) As[ty*4+u][tx*4+v] = kv[u][v];
    __syncthreads();
    factor64_reg(As, lkdiag, sdg, 0, t);
  }
}

// panel kb (kb=0..26): fused TRSM+SYRK; grid = T(T+1)/2, T = 31-kb.
// tile 0 = (kb+1,kb+1): subtract in LDS + factor -> lkdiag[kb+1] (lookahead).
__global__ __launch_bounds__(256) void panel_kernel(
    float* __restrict__ kuu, float* __restrict__ lkdiag,
    float* __restrict__ sdg, float* __restrict__ ltri, int kb){
  __shared__ float As[64][68];
  __shared__ float Bs[64][68];
  __shared__ float Cs[64][68];
  __shared__ float sd[64];
  const int t = threadIdx.x, tx = t & 15, ty = t >> 4;
  int idx = blockIdx.x;
  int r=0; while ((r+1)*(r+2)/2 <= idx) ++r;
  int c = idx - r*(r+1)/2;
  int bi = kb+1+r, bc = kb+1+c;
  stage64(Cs, lkdiag + kb*4096, 64, t);
  if (t < 64) sd[t] = sdg[kb*64 + t];
  stage64(As, kuu + (size_t)(bi*64)*MM + kb*64, MM, t);
  if (bc != bi) stage64(Bs, kuu + (size_t)(bc*64)*MM + kb*64, MM, t);
  __syncthreads();
  {
    int w = t>>6, l = t&63;
    if (w==0 || (w==1 && bc!=bi)){
      float (*S)[68] = (w==0)? As : Bs;
      float xr[64];
      #pragma unroll
      for (int c4=0;c4<16;++c4) *(float4*)&xr[c4*4] = *(const float4*)&S[l][c4*4];
      #pragma unroll
      for (int j=0;j<64;++j){
        float xj = xr[j]*sd[j];
        xr[j] = xj;
        #pragma unroll
        for (int cc=j+1;cc<64;++cc) xr[cc] -= xj*Cs[cc][j];
      }
      #pragma unroll
      for (int c4=0;c4<16;++c4) *(float4*)&S[l][c4*4] = *(float4*)&xr[c4*4];
    }
  }
  __syncthreads();
  if (bc == kb+1){
    for (int p=t;p<1024;p+=256)
      *(float4*)&ltri[(size_t)(bi*64+(p>>4))*MM + kb*64 + (p&15)*4] =
          *(float4*)&As[p>>4][(p&15)*4];
  }
  float acc[4][4] = {};
  tile_syrk_step(acc, As, (bc==bi)? As : Bs, tx, ty);
  if (bi==kb+1 && bc==kb+1){
    __syncthreads();
    #pragma unroll
    for (int u=0;u<4;++u)
      #pragma unroll
      for (int v=0;v<4;++v) Bs[ty*4+u][tx*4+v] = acc[u][v];
    __syncthreads();
    for (int p=t;p<1024;p+=256){
      int i=p>>4, c4=p&15;
      float4 kv = *(const float4*)&kuu[(size_t)(bi*64+i)*MM + bi*64 + c4*4];
      float4 bv = *(float4*)&Bs[i][c4*4];
      float4 o; o.x=kv.x-bv.x; o.y=kv.y-bv.y; o.z=kv.z-bv.z; o.w=kv.w-bv.w;
      *(float4*)&As[i][c4*4] = o;
    }
    __syncthreads();
    factor64_reg(As, lkdiag, sdg, kb+1, t);
  } else {
    #pragma unroll
    for (int u=0;u<4;++u){
      float4* dst = (float4*)&kuu[(size_t)(bi*64+ty*4+u)*MM + bc*64 + tx*4];
      float4 o = *dst;
      o.x-=acc[u][0]; o.y-=acc[u][1]; o.z-=acc[u][2]; o.w-=acc[u][3];
      *dst = o;
    }
  }
}

// tail: panels kb=27..30 (20 tiles) in ONE block, sequential; next-panel diag
// kept in LDS (Ds/sd2) to avoid global read-back of own writes.
__global__ __launch_bounds__(256) void tail_kernel(
    float* __restrict__ kuu, float* __restrict__ lkdiag,
    float* __restrict__ sdg, float* __restrict__ ltri){
  __shared__ float As[64][68];
  __shared__ float Bs[64][68];
  __shared__ float Cs[64][68];
  __shared__ float Ds[64][68];
  __shared__ float sd[64], sd2[64];
  const int t = threadIdx.x, tx = t & 15, ty = t >> 4;
  stage64(Cs, lkdiag + 27*4096, 64, t);
  if (t < 64) sd[t] = sdg[27*64 + t];
  for (int kb=27; kb<31; ++kb){
    int T = 31-kb, ntiles = T*(T+1)/2;
    for (int idx=0; idx<ntiles; ++idx){
      int r=0; while ((r+1)*(r+2)/2 <= idx) ++r;
      int c = idx - r*(r+1)/2;
      int bi = kb+1+r, bc = kb+1+c;
      __syncthreads();
      stage64(As, kuu + (size_t)(bi*64)*MM + kb*64, MM, t);
      if (bc != bi) stage64(Bs, kuu + (size_t)(bc*64)*MM + kb*64, MM, t);
      __syncthreads();
      {
        int w = t>>6, l = t&63;
        if (w==0 || (w==1 && bc!=bi)){
          float (*S)[68] = (w==0)? As : Bs;
          float xr[64];
          #pragma unroll
          for (int c4=0;c4<16;++c4) *(float4*)&xr[c4*4] = *(const float4*)&S[l][c4*4];
          #pragma unroll
          for (int j=0;j<64;++j){
            float xj = xr[j]*sd[j];
            xr[j] = xj;
            #pragma unroll
            for (int cc=j+1;cc<64;++cc) xr[cc] -= xj*Cs[cc][j];
          }
          #pragma unroll
          for (int c4=0;c4<16;++c4) *(float4*)&S[l][c4*4] = *(float4*)&xr[c4*4];
        }
      }
      __syncthreads();
      if (bc == kb+1){
        for (int p=t;p<1024;p+=256)
          *(float4*)&ltri[(size_t)(bi*64+(p>>4))*MM + kb*64 + (p&15)*4] =
              *(float4*)&As[p>>4][(p&15)*4];
      }
      float acc[4][4] = {};
      tile_syrk_step(acc, As, (bc==bi)? As : Bs, tx, ty);
      if (bi==kb+1 && bc==kb+1){
        __syncthreads();
        #pragma unroll
        for (int u=0;u<4;++u)
          #pragma unroll
          for (int v=0;v<4;++v) Bs[ty*4+u][tx*4+v] = acc[u][v];
        __syncthreads();
        for (int p=t;p<1024;p+=256){
          int i=p>>4, c4=p&15;
          float4 kv = *(const float4*)&kuu[(size_t)(bi*64+i)*MM + bi*64 + c4*4];
          float4 bv = *(float4*)&Bs[i][c4*4];
          float4 o; o.x=kv.x-bv.x; o.y=kv.y-bv.y; o.z=kv.z-bv.z; o.w=kv.w-bv.w;
          *(float4*)&As[i][c4*4] = o;
        }
        __syncthreads();
        factor64_t(As, Ds, sd2, lkdiag, sdg, kb+1, t);
      } else {
        #pragma unroll
        for (int u=0;u<4;++u){
          float4* dst = (float4*)&kuu[(size_t)(bi*64+ty*4+u)*MM + bc*64 + tx*4];
          float4 o = *dst;
          o.x-=acc[u][0]; o.y-=acc[u][1]; o.z-=acc[u][2]; o.w-=acc[u][3];
          *dst = o;
        }
      }
    }
    __syncthreads();
    for (int p=t;p<1024;p+=256)
      *(float4*)&Cs[p>>4][(p&15)*4] = *(const float4*)&Ds[p>>4][(p&15)*4];
    if (t < 64) sd[t] = sd2[t];
  }
}

// p3head: phase2 + p3 level0 + p3 level1 fused; grid = 8 (block m owns
// diags 4m..4m+3, level-0 pairs 2m,2m+1, level-1 m). All deps block-local.
__global__ __launch_bounds__(256) void p3head_kernel(
    const float* __restrict__ lkdiag, const float* __restrict__ ltri,
    float* __restrict__ linv, float* __restrict__ ptmp){
  __shared__ float As[64][68];
  __shared__ float Bs[64][68];
  const int t = threadIdx.x, tx = t & 15, ty = t >> 4;
  const int m = blockIdx.x;
  // phase2: invert 4 diag blocks
  for (int d=4*m; d<4*m+4; ++d){
    __syncthreads();
    stage64(As, lkdiag + d*4096, 64, t);
    __syncthreads();
    if (t < 64){
      for (int j=0;j<64;++j){
        float s = (j==t)?1.f:0.f;
        for (int k=t;k<j;++k) s -= As[j][k]*Bs[k][t];
        Bs[j][t] = (j>=t)? s/As[j][j] : 0.f;
      }
    }
    __syncthreads();
    for (int p=t;p<1024;p+=256){ int i=p>>4, c4=p&15;
      *(float4*)&linv[(size_t)(d*64+i)*MM + d*64 + c4*4] = *(float4*)&Bs[i][c4*4]; }
  }
  // level 0 for mm = 2m, 2m+1
  for (int q2=0;q2<2;++q2){
    int mm = 2*m + q2;
    __syncthreads();
    stage64(As, ltri + (size_t)((2*mm+1)*64)*MM + (2*mm)*64, MM, t);
    stage64(Bs, linv + (size_t)((2*mm)*64)*MM   + (2*mm)*64, MM, t);
    __syncthreads();
    float acc[4][4]={};
    tile_gemm_step(acc, As, Bs, tx, ty);
    __syncthreads();
    #pragma unroll
    for (int u=0;u<4;++u)
      #pragma unroll
      for (int v=0;v<4;++v) Bs[ty*4+u][tx*4+v] = acc[u][v];
    stage64(As, linv + (size_t)((2*mm+1)*64)*MM + (2*mm+1)*64, MM, t);
    __syncthreads();
    float o[4][4]={};
    tile_gemm_step(o, As, Bs, tx, ty);
    #pragma unroll
    for (int u=0;u<4;++u)
      *(float4*)&linv[(size_t)((2*mm+1)*64+ty*4+u)*MM + (2*mm)*64 + tx*4] =
          make_float4(-o[u][0],-o[u][1],-o[u][2],-o[u][3]);
  }
  // level 1 for m
  float* pm = ptmp + (size_t)m*128*128;
  for (int ti=0; ti<2; ++ti)
    for (int tj=0; tj<2; ++tj){
      int rb = m*4 + 2 + ti, cb0 = m*4;
      float acc[4][4]={};
      for (int k=tj; k<2; ++k){
        __syncthreads();
        stage64(As, ltri + (size_t)(rb*64)*MM + (cb0+k)*64, MM, t);
        stage64(Bs, linv + (size_t)((cb0+k)*64)*MM + (cb0+tj)*64, MM, t);
        __syncthreads();
        tile_gemm_step(acc, As, Bs, tx, ty);
      }
      #pragma unroll
      for (int u=0;u<4;++u)
        *(float4*)&pm[(size_t)(ti*64+ty*4+u)*128 + tj*64 + tx*4] =
            make_float4(acc[u][0],acc[u][1],acc[u][2],acc[u][3]);
    }
  for (int ti=0; ti<2; ++ti)
    for (int tj=0; tj<2; ++tj){
      int rb = m*4 + 2 + ti;
      float acc[4][4]={};
      for (int k=0; k<=ti; ++k){
        __syncthreads();
        stage64(As, linv + (size_t)(rb*64)*MM + (m*4+2+k)*64, MM, t);
        stage64(Bs, pm + (size_t)(k*64)*128 + tj*64, 128, t);
        __syncthreads();
        tile_gemm_step(acc, As, Bs, tx, ty);
      }
      #pragma unroll
      for (int u=0;u<4;++u)
        *(float4*)&linv[(size_t)(rb*64+ty*4+u)*MM + (m*4+tj)*64 + tx*4] =
            make_float4(-acc[u][0],-acc[u][1],-acc[u][2],-acc[u][3]);
    }
}

// phase 3 levels 2..4 part A (P = A21 @ Linv_lower); grid = mc*nb*nb
__global__ __launch_bounds__(256) void p3lA_kernel(
    const float* __restrict__ ltri, const float* __restrict__ linv,
    float* __restrict__ ptmp, int s){
  __shared__ float As[64][68];
  __shared__ float Bs[64][68];
  const int t = threadIdx.x, tx = t & 15, ty = t >> 4;
  int nb = 1<<s, b = 64<<s;
  float* pmb = ptmp + (s==2 ? 131072 : (s==3 ? 393216 : 917504));
  int idx = blockIdx.x;
  int m = idx/(nb*nb), r2 = idx%(nb*nb);
  int ti = r2/nb, tj = r2%nb;
  int rb = m*2*nb + nb + ti, cb0 = m*2*nb;
  float acc[4][4]={};
  for (int k=tj; k<nb; ++k){
    __syncthreads();
    stage64(As, ltri + (size_t)(rb*64)*MM + (cb0+k)*64, MM, t);
    stage64(Bs, linv + (size_t)((cb0+k)*64)*MM + (cb0+tj)*64, MM, t);
    __syncthreads();
    tile_gemm_step(acc, As, Bs, tx, ty);
  }
  float* pm = pmb + (size_t)m*b*b;
  #pragma unroll
  for (int u=0;u<4;++u)
    *(float4*)&pm[(size_t)(ti*64+ty*4+u)*b + tj*64 + tx*4] =
        make_float4(acc[u][0],acc[u][1],acc[u][2],acc[u][3]);
}

// phase 3 levels 2..4 part B (Linv21 = -Linv_lower @ P); grid = mc*nb*nb
__global__ __launch_bounds__(256) void p3lB_kernel(
    float* __restrict__ linv, const float* __restrict__ ptmp, int s){
  __shared__ float As[64][68];
  __shared__ float Bs[64][68];
  const int t = threadIdx.x, tx = t & 15, ty = t >> 4;
  int nb = 1<<s, b = 64<<s;
  const float* pmb = ptmp + (s==2 ? 131072 : (s==3 ? 393216 : 917504));
  int idx = blockIdx.x;
  int m = idx/(nb*nb), r2 = idx%(nb*nb);
  int ti = r2/nb, tj = r2%nb;
  int rb = m*2*nb + nb + ti;
  const float* pm = pmb + (size_t)m*b*b;
  float acc[4][4]={};
  for (int k=0; k<=ti; ++k){
    __syncthreads();
    stage64(As, linv + (size_t)(rb*64)*MM + (m*2*nb+nb+k)*64, MM, t);
    stage64(Bs, pm + (size_t)(k*64)*b + tj*64, b, t);
    __syncthreads();
    tile_gemm_step(acc, As, Bs, tx, ty);
  }
  #pragma unroll
  for (int u=0;u<4;++u)
    *(float4*)&linv[(size_t)(rb*64+ty*4+u)*MM + (m*2*nb+tj)*64 + tx*4] =
        make_float4(-acc[u][0],-acc[u][1],-acc[u][2],-acc[u][3]);
}

// phase 4a: W = Linv @ tril(qL), both GPs; grid = 2*528
__global__ __launch_bounds__(256) void w_kernel(
    const float* __restrict__ linv, const float* __restrict__ qlf,
    const float* __restrict__ qlg, float* __restrict__ wf, float* __restrict__ wg){
  __shared__ float As[64][68];
  __shared__ float Bs[64][68];
  const int t = threadIdx.x, tx = t & 15, ty = t >> 4;
  int idx = blockIdx.x;
  int gp = idx/528, rem = idx%528;
  int bi=0; while ((bi+1)*(bi+2)/2 <= rem) ++bi;
  int bj = rem - bi*(bi+1)/2;
  const float* ql = gp ? qlg : qlf;
  float* w        = gp ? wg  : wf;
  float acc[4][4]={};
  for (int bk=bj; bk<=bi; ++bk){
    __syncthreads();
    stage64(As, linv + (size_t)(bi*64)*MM + bk*64, MM, t);
    stage64(Bs, ql   + (size_t)(bk*64)*MM + bj*64, MM, t);
    __syncthreads();
    if (bk==bj){
      for (int p=t;p<4096;p+=256){ int i=p>>6, c=p&63; if (i<c) Bs[i][c]=0.f; }
      __syncthreads();
    }
    tile_gemm_step(acc, As, Bs, tx, ty);
  }
  #pragma unroll
  for (int u=0;u<4;++u)
    *(float4*)&w[(size_t)(bi*64+ty*4+u)*MM + bj*64 + tx*4] =
        make_float4(acc[u][0],acc[u][1],acc[u][2],acc[u][3]);
}

// phase 4b: alpha = Linv @ qm, both GPs; grid = 256
__global__ __launch_bounds__(256) void alpha_kernel(
    const float* __restrict__ linv, const float* __restrict__ qmf,
    const float* __restrict__ qmg, float* __restrict__ af, float* __restrict__ ag){
  int t = threadIdx.x;
  int gw = blockIdx.x*4 + (t>>6), l = t&63;
  for (int job=gw; job<4096; job+=1024){
    int gp = job>>11, r = job&2047;
    const float* qm = gp ? qmg : qmf;
    float s=0.f;
    for (int c=l; c<=r; c+=64) s += linv[(size_t)r*MM+c]*qm[c];
    #pragma unroll
    for (int off=32; off; off>>=1) s += __shfl_down(s, off, 64);
    if (l==0) (gp ? ag : af)[r] = s;
  }
}

// ================= small kernels (pre/post) =================

__global__ __launch_bounds__(256) void red_small(const float* __restrict__ lkd,
    const float* __restrict__ qlf, const float* __restrict__ qlg,
    const float* __restrict__ af, const float* __restrict__ ag,
    float* __restrict__ scal){
  __shared__ float scratch[4];
  float ldk=0, ldf=0, ldg=0, a2f=0, a2g=0;
  for (int i=threadIdx.x;i<MM;i+=256){
    int kb = i>>6, r = i&63;
    ldk += __logf(lkd[kb*4096 + r*64 + r]);
    ldf += __logf(fabsf(qlf[(size_t)i*MM+i]));
    ldg += __logf(fabsf(qlg[(size_t)i*MM+i]));
    float v = af[i]; a2f += v*v;
    v = ag[i];       a2g += v*v;
  }
  float r;
  r = block_reduce(ldk, scratch); if (threadIdx.x==0) scal[0] = 2.f*r;
  r = block_reduce(ldf, scratch); if (threadIdx.x==0) scal[1] = 2.f*r;
  r = block_reduce(ldg, scratch); if (threadIdx.x==0) scal[2] = 2.f*r;
  r = block_reduce(a2f, scratch); if (threadIdx.x==0) scal[3] = r;
  r = block_reduce(a2g, scratch); if (threadIdx.x==0) scal[4] = r;
}

__global__ __launch_bounds__(256) void redw_kernel(const float* __restrict__ wf,
    const float* __restrict__ wg, float* __restrict__ scal){
  __shared__ float scratch[4];
  size_t start  = (size_t)blockIdx.x*256 + threadIdx.x;
  size_t stride = (size_t)gridDim.x*256;
  float sf=0, sg=0;
  for (size_t p=start;p<(size_t)MM*MM;p+=stride){
    float v=wf[p]; sf += v*v;
    v=wg[p];       sg += v*v;
  }
  float r = block_reduce(sf, scratch);
  if (threadIdx.x==0) atomicAdd(&scal[5], r);
  r = block_reduce(sg, scratch);
  if (threadIdx.x==0) atomicAdd(&scal[6], r);
}

__global__ void kl_kernel(const float* __restrict__ scal, float* __restrict__ out){
  float klf = 0.5f*(scal[5] + scal[3] - (float)MM + scal[0] - scal[1]);
  float klg = 0.5f*(scal[6] + scal[4] - (float)MM + scal[0] - scal[2]);
  out[0] += klf + klg;
}

// merged splits: blocks [0,16384) rowmajor(linv); [16384,24576) transpose wf/wg
__global__ __launch_bounds__(256) void split_all(
    const float* __restrict__ linv, const float* __restrict__ wf,
    const float* __restrict__ wg, short* __restrict__ lvh, short* __restrict__ lvl,
    short* __restrict__ wfh, short* __restrict__ wfl,
    short* __restrict__ wgh, short* __restrict__ wgl){
  __shared__ float tile[32][33];
  const int t = threadIdx.x;
  const int bid = blockIdx.x;
  if (bid < 16384){
    int p = bid*256 + t;
    int chunk = p >> 9, wi = p & 511;
    int mo = chunk >> 6, ko = chunk & 63;
    int row = mo*16 + (wi >> 5), col = ko*32 + (wi & 31);
    float v = linv[(size_t)row*MM + col];
    short h, lo; bfsplit(v, h, lo);
    lvh[p] = h; lvl[p] = lo;
    return;
  }
  int idx2 = bid - 16384;
  int zz = idx2 >> 12;
  int rem = idx2 & 4095;
  int mb = rem & 63, kb = rem >> 6;
  const float* src = zz ? wg : wf;
  short* dh = zz ? wgh : wfh;
  short* dl = zz ? wgl : wfl;
  #pragma unroll
  for (int k=0;k<4;++k){
    int idx = t + k*256;
    int lr = idx >> 5, lc = idx & 31;
    tile[lr][lc] = src[(size_t)(kb*32+lr)*MM + mb*32 + lc];
  }
  __syncthreads();
  #pragma unroll
  for (int e=0;e<4;++e){
    int p = t*4 + e;
    int c = p >> 9, wi = p & 511;
    int i = (wi >> 5) & 15, kk = wi & 31;
    float v = tile[kk][c*16 + i];
    short h, lo; bfsplit(v, h, lo);
    size_t gp = ((size_t)(mb*2 + c)*64 + kb)*512 + wi;
    dh[gp] = h; dl[gp] = lo;
  }
}

__global__ __launch_bounds__(256, 2) void tt_mfma(
    const float* __restrict__ x, const float* __restrict__ zn2,
    const short* __restrict__ zfh, const short* __restrict__ zfl,
    const short* __restrict__ lvh, const short* __restrict__ lvl,
    short* __restrict__ tth, short* __restrict__ ttl){
  __shared__ __align__(16) short lAh[8192], lAl[8192], lBh[8192], lBl[8192];
  int t = threadIdx.x;
  int l = t & 63, w = t >> 6;
  int istrip = blockIdx.x, bj2 = blockIdx.y;
  int li = l & 15, q = l >> 4;
  int lofs = li*32 + q*8;
  int wn4 = (w>>1)*4, wm4 = (w&1)*4;

  short8 xh[2], xl[2];
  float xn2v[8];
  {
    float xn2t[2];
    #pragma unroll
    for (int tn=0; tn<2; ++tn){
      int n = istrip*128 + w*32 + tn*16 + li;
      const float4* xp = (const float4*)(x + (size_t)n*DD);
      float4 p0 = xp[0], p1 = xp[1];
      float v[8] = {p0.x,p0.y,p0.z,p0.w,p1.x,p1.y,p1.z,p1.w};
      float s = 0.f;
      #pragma unroll
      for (int d=0; d<8; ++d) s += v[d]*v[d];
      xn2t[tn] = s;
      short8 hh, ll;
      #pragma unroll
      for (int j=0; j<8; ++j){
        short h=0, lo=0;
        if (q==0) bfsplit(v[j], h, lo);
        hh[j]=h; ll[j]=lo;
      }
      xh[tn]=hh; xl[tn]=ll;
    }
    #pragma unroll
    for (int tn=0; tn<2; ++tn)
      #pragma unroll
      for (int r=0; r<4; ++r)
        xn2v[tn*4+r] = __shfl(xn2t[tn], q*4 + r, 64);
  }

  float4v acc[4][4];
  #pragma unroll
  for (int i=0;i<4;++i)
    #pragma unroll
    for (int j=0;j<4;++j) acc[i][j] = f4zero();

  int nkt = 2*bj2 + 2;
  for (int bk=0; bk<nkt; ++bk){
    __syncthreads();
    {
      short8 zh[4], zl[4];
      float zt2[4];
      #pragma unroll
      for (int tz=0; tz<4; ++tz){
        size_t zo = (size_t)(bk*4 + tz)*512 + lofs;
        zh[tz] = *(const short8*)(zfh + zo);
        zl[tz] = *(const short8*)(zfl + zo);
        zt2[tz] = zn2[bk*64 + tz*16 + li];
      }
      #pragma unroll
      for (int tn=0; tn<2; ++tn){
        #pragma unroll
        for (int tz=0; tz<4; ++tz){
          float4v s4 = mfma3(xh[tn], xl[tn], zh[tz], zl[tz], f4zero());
          #pragma unroll
          for (int r=0; r<4; ++r){
            float e = __expf(4.f*s4[r] - 2.f*(xn2v[tn*4+r] + zt2[tz]));
            short h, lo; bfsplit(e, h, lo);
            int pos = ((w*2+tn)*2 + (tz>>1))*512 + (q*4+r)*32 + (tz&1)*16 + li;
            lAh[pos] = h; lAl[pos] = lo;
          }
        }
      }
    }
    #pragma unroll
    for (int c4 = t; c4 < 1024; c4 += 256){
      int ch = c4 >> 6, wdi = c4 & 63;
      size_t g = ((size_t)(bj2*8 + (ch>>1))*64 + (size_t)(bk*2 + (ch&1)))*64 + wdi;
      ((uint4*)lBh)[c4] = ((const uint4*)lvh)[g];
      ((uint4*)lBl)[c4] = ((const uint4*)lvl)[g];
    }
    __syncthreads();
    #pragma unroll
    for (int s=0; s<2; ++s){
      short8 ah[4], al[4], bh[4], bl[4];
      #pragma unroll
      for (int tn=0; tn<4; ++tn){
        int off = ((wn4+tn)*2 + s)*512 + lofs;
        ah[tn] = *(const short8*)&lAh[off];
        al[tn] = *(const short8*)&lAl[off];
      }
      #pragma unroll
      for (int tm=0; tm<4; ++tm){
        int off = ((wm4+tm)*2 + s)*512 + lofs;
        bh[tm] = *(const short8*)&lBh[off];
        bl[tm] = *(const short8*)&lBl[off];
      }
      #pragma unroll
      for (int tn=0; tn<4; ++tn)
        #pragma unroll
        for (int tm=0; tm<4; ++tm)
          acc[tn][tm] = mfma3(ah[tn], al[tn], bh[tm], bl[tm], acc[tn][tm]);
    }
  }
  #pragma unroll
  for (int tn=0; tn<4; ++tn){
    int no_g = istrip*8 + wn4 + tn;
    #pragma unroll
    for (int tm=0; tm<4; ++tm){
      int mo_g = bj2*4 + (w&1)*2 + (tm>>1);
      size_t cb = ((size_t)no_g*64 + mo_g)*512;
      #pragma unroll
      for (int r=0; r<4; ++r){
        short h, lo; bfsplit(acc[tn][tm][r], h, lo);
        size_t pos = cb + (q*4+r)*32 + (tm&1)*16 + li;
        tth[pos] = h; ttl[pos] = lo;
      }
    }
  }
}

__global__ __launch_bounds__(256) void lin_v2(const short* __restrict__ tth,
    const short* __restrict__ ttl, const float* __restrict__ af, const float* __restrict__ ag,
    float* __restrict__ t2, float* __restrict__ lf, float* __restrict__ lg){
  int t = threadIdx.x;
  int w = t >> 6, l = t & 63;
  int n = blockIdx.x*4 + w;
  int g = l >> 2, j = l & 3;
  float s2=0.f, sf=0.f, sg=0.f;
  #pragma unroll
  for (int it=0; it<4; ++it){
    int ck = g + it*16;
    size_t off = ((size_t)(n>>4)*64 + ck)*512 + (n&15)*32 + j*8;
    short8 h8 = *(const short8*)(tth + off);
    short8 l8 = *(const short8*)(ttl + off);
    int m0 = ck*32 + j*8;
    float4 a0 = *(const float4*)(af + m0), a1 = *(const float4*)(af + m0 + 4);
    float4 g0 = *(const float4*)(ag + m0), g1 = *(const float4*)(ag + m0 + 4);
    float av[8] = {a0.x,a0.y,a0.z,a0.w,a1.x,a1.y,a1.z,a1.w};
    float gv[8] = {g0.x,g0.y,g0.z,g0.w,g1.x,g1.y,g1.z,g1.w};
    #pragma unroll
    for (int e=0; e<8; ++e){
      float tv = bf2f(h8[e]) + bf2f(l8[e]);
      s2 += tv*tv; sf += tv*av[e]; sg += tv*gv[e];
    }
  }
  #pragma unroll
  for (int off=32; off; off>>=1){
    s2 += __shfl_down(s2, off, 64);
    sf += __shfl_down(sf, off, 64);
    sg += __shfl_down(sg, off, 64);
  }
  if (l==0){ t2[n] = s2; lf[n] = sf; lg[n] = sg; }
}

__global__ __launch_bounds__(256, 2) void quad_mfma(
    const short* __restrict__ tth, const short* __restrict__ ttl,
    const short* __restrict__ wfh, const short* __restrict__ wfl,
    const short* __restrict__ wgh, const short* __restrict__ wgl,
    float* __restrict__ vfq, float* __restrict__ vgq){
  __shared__ __align__(16) short lAh[8192], lAl[8192], lBh[8192], lBl[8192];
  int t = threadIdx.x, l = t & 63, w = t >> 6;
  int istrip = blockIdx.x, bj2 = blockIdx.y;
  const short* gbh = blockIdx.z ? wgh : wfh;
  const short* gbl = blockIdx.z ? wgl : wfl;
  float* vq = blockIdx.z ? vgq : vfq;
  int li = l & 15, q = l >> 4;
  int lofs = li*32 + q*8;
  int wn4 = (w>>1)*4, wm4 = (w&1)*4;

  float4v acc[4][4];
  #pragma unroll
  for (int i=0;i<4;++i)
    #pragma unroll
    for (int j=0;j<4;++j) acc[i][j] = f4zero();

  for (int bk=2*bj2; bk<32; ++bk){
    __syncthreads();
    #pragma unroll
    for (int c4 = t; c4 < 1024; c4 += 256){
      int ch = c4 >> 6, wdi = c4 & 63;
      size_t ga = ((size_t)(istrip*8 + (ch>>1))*64 + (size_t)(bk*2 + (ch&1)))*64 + wdi;
      ((uint4*)lAh)[c4] = ((const uint4*)tth)[ga];
      ((uint4*)lAl)[c4] = ((const uint4*)ttl)[ga];
      size_t gb = ((size_t)(bj2*8 + (ch>>1))*64 + (size_t)(bk*2 + (ch&1)))*64 + wdi;
      ((uint4*)lBh)[c4] = ((const uint4*)gbh)[gb];
      ((uint4*)lBl)[c4] = ((const uint4*)gbl)[gb];
    }
    __syncthreads();
    #pragma unroll
    for (int s=0; s<2; ++s){
      short8 ah[4], al[4], bh[4], bl[4];
      #pragma unroll
      for (int tn=0; tn<4; ++tn){
        int off = ((wn4+tn)*2 + s)*512 + lofs;
        ah[tn] = *(const short8*)&lAh[off];
        al[tn] = *(const short8*)&lAl[off];
      }
      #pragma unroll
      for (int tm=0; tm<4; ++tm){
        int off = ((wm4+tm)*2 + s)*512 + lofs;
        bh[tm] = *(const short8*)&lBh[off];
        bl[tm] = *(const short8*)&lBl[off];
      }
      #pragma unroll
      for (int tn=0; tn<4; ++tn)
        #pragma unroll
        for (int tm=0; tm<4; ++tm)
          acc[tn][tm] = mfma3(ah[tn], al[tn], bh[tm], bl[tm], acc[tn][tm]);
    }
  }
  float rs[16];
  #pragma unroll
  for (int tn=0; tn<4; ++tn)
    #pragma unroll
    for (int r=0; r<4; ++r){
      float s = 0.f;
      #pragma unroll
      for (int tm=0; tm<4; ++tm){ float v = acc[tn][tm][r]; s += v*v; }
      rs[tn*4+r] = s;
    }
  #pragma unroll
  for (int off=8; off; off>>=1)
    #pragma unroll
    for (int k=0; k<16; ++k) rs[k] += __shfl_down(rs[k], off, 16);
  if (li == 0){
    #pragma unroll
    for (int tn=0; tn<4; ++tn)
      #pragma unroll
      for (int r=0; r<4; ++r){
        int n = istrip*128 + (w>>1)*64 + tn*16 + q*4 + r;
        atomicAdd(&vq[n], rs[tn*4+r]);
      }
  }
}

__global__ __launch_bounds__(256) void final_kernel(const float* __restrict__ y,
    const float* __restrict__ t2, const float* __restrict__ lf, const float* __restrict__ lg,
    const float* __restrict__ vfq, const float* __restrict__ vgq, float* __restrict__ out){
  __shared__ float scratch[4];
  int i = blockIdx.x*256 + threadIdx.x;
  float mf = lf[i], mg = lg[i];
  float vf = 1.f + vfq[i] - t2[i];
  float vg = 1.f + vgq[i] - t2[i];
  float dy = y[i] - mf;
  float e = -HLOG2PI - 0.5f*mg - 0.5f*(dy*dy + vf)*__expf(-mg + 0.5f*vg);
  float r = block_reduce(e, scratch);
  if (threadIdx.x==0) atomicAdd(out, -r);
}

extern "C" void kernel_launch(void* const* d_in, const int* in_sizes, int n_in,
                              void* d_out, int out_size, void* d_ws, size_t ws_size,
                              hipStream_t stream){
  (void)in_sizes; (void)n_in; (void)out_size; (void)ws_size;
  const float* x   = (const float*)d_in[0];
  const float* y   = (const float*)d_in[1];
  const float* z   = (const float*)d_in[2];
  const float* qmf = (const float*)d_in[3];
  const float* qlf = (const float*)d_in[4];
  const float* qmg = (const float*)d_in[5];
  const float* qlg = (const float*)d_in[6];
  float* out = (float*)d_out;
  char* Bw = (char*)d_ws;

  float* kuu  = (float*)Bw;
  float* linv = (float*)(Bw + SZB);
  float* wf   = (float*)(Bw + 2*SZB);
  float* wg   = (float*)(Bw + 3*SZB);
  short* lvh  = (short*)Bw;
  short* lvl  = (short*)(Bw + SZB/2);
  short* wfh  = (short*)(Bw + SZB);
  short* wfl  = (short*)(Bw + SZB + SZB/2);
  short* wgh  = (short*)(Bw + 2*SZB);
  short* wgl  = (short*)(Bw + 2*SZB + SZB/2);
  short* tth  = (short*)(Bw + 3*SZB);
  short* ttl  = (short*)(Bw + 3*SZB + (size_t)NN*MM*2);
  // dead-tt region [64M,112M): ltri 16MB, ptmp 8MB (per-level disjoint),
  // lkdiag 512KB, sdg 8KB
  float* ltri   = (float*)(Bw + 4*SZB);
  float* ptmp   = (float*)(Bw + 5*SZB);
  float* lkdiag = (float*)(Bw + 5*SZB + (size_t)8388608);
  float* sdg    = (float*)(Bw + 5*SZB + (size_t)8388608 + (size_t)524288);
  float* sm   = (float*)(Bw + 3*SZB + (size_t)NN*MM*4);
  float* af = sm;          float* ag = af + MM;
  float* t2 = ag + MM;     float* lf = t2 + NN;   float* lg = lf + NN;
  float* vfq = lg + NN;    float* vgq = vfq + NN; float* scal = vgq + NN;
  float* zn2 = scal + 64 + 2048;
  short* zfh = (short*)(zn2 + MM);
  short* zfl = zfh + MM*32;

  hipMemsetAsync(out, 0, sizeof(float), stream);
  hipMemsetAsync(vfq, 0, (size_t)(2*NN + 64 + 2048)*sizeof(float), stream); // vfq,vgq,scal
  hipMemsetAsync(wf,  0, 2*SZB, stream);    // W upper triangles must be 0
  hipMemsetAsync(linv,0, SZB,   stream);    // Linv upper must be 0

  // ---- factorization: multi-launch, fused endpoints ----
  phase0_kernel<<<536, 256, 0, stream>>>(z, kuu, zfh, zfl, zn2, lkdiag, sdg);
  for (int kb = 0; kb < 27; ++kb){
    int T = NB - 1 - kb;
    panel_kernel<<<T*(T+1)/2, 256, 0, stream>>>(kuu, lkdiag, sdg, ltri, kb);
  }
  tail_kernel<<<1, 256, 0, stream>>>(kuu, lkdiag, sdg, ltri);
  p3head_kernel<<<8, 256, 0, stream>>>(lkdiag, ltri, linv, ptmp);
  for (int s = 2; s < 5; ++s){
    int nb = 1<<s, mc = 16>>s;
    p3lA_kernel<<<mc*nb*nb, 256, 0, stream>>>(ltri, linv, ptmp, s);
    p3lB_kernel<<<mc*nb*nb, 256, 0, stream>>>(linv, ptmp, s);
  }
  w_kernel<<<2*528, 256, 0, stream>>>(linv, qlf, qlg, wf, wg);
  alpha_kernel<<<256, 256, 0, stream>>>(linv, qmf, qmg, af, ag);

  red_small<<<1, 256, 0, stream>>>(lkdiag, qlf, qlg, af, ag, scal);
  redw_kernel<<<512, 256, 0, stream>>>(wf, wg, scal);
  kl_kernel<<<1, 1, 0, stream>>>(scal, out);

  split_all<<<24576, 256, 0, stream>>>(linv, wf, wg, lvh, lvl, wfh, wfl, wgh, wgl);

  tt_mfma<<<dim3(NN/128, MM/128), 256, 0, stream>>>(x, zn2, zfh, zfl, lvh, lvl, tth, ttl);
  lin_v2<<<NN/4, 256, 0, stream>>>(tth, ttl, af, ag, t2, lf, lg);
  quad_mfma<<<dim3(NN/128, MM/128, 2), 256, 0, stream>>>(tth, ttl, wfh, wfl, wgh, wgl, vfq, vgq);
  final_kernel<<<NN/256, 256, 0, stream>>>(y, t2, lf, lg, vfq, vgq, out);
}

// Round 11
// 4156.958 us; speedup vs baseline: 1.1796x; 1.0487x over previous
//
#include <hip/hip_runtime.h>
#include <math.h>

// ChainedGP v18: v17 minus tail_kernel (the 486us single-block pole —
// profile showed 20 tiles x ~24us serial, replacing only ~200us of
// boundaries: pole inflation again). Panels kb=0..30 are separate
// launches as in v15 (best non-pole structure). KEPT from v17 (net
// ~-300us of boundaries, low-risk): (1) zfrag+diag0 fused into phase0;
// (2) phase2+p3l0+p3l1 fused into 8-block p3head; (3) split_rowmajor +
// 2x split_transpose fused into split_all. Math identical everywhere.
// Calibration from v17's profile: ~24us/tile serial; ~45-50us per
// dependent launch boundary even under graph capture.
#define NN 16384
#define MM 2048
#define DD 8
#define NB 32                     // MM/64
#define SZB ((size_t)16777216)    // 2048*2048*4 bytes

constexpr float HLOG2PI = 0.91893853320467274178f;

using short8  = __attribute__((ext_vector_type(8))) short;
using float4v = __attribute__((ext_vector_type(4))) float;

__device__ __forceinline__ float4v f4zero(){ float4v v; v[0]=0.f; v[1]=0.f; v[2]=0.f; v[3]=0.f; return v; }

__device__ __forceinline__ void bfsplit(float v, short& h, short& lo){
  unsigned b = __float_as_uint(v);
  h = (short)(b >> 16);
  float hf = __uint_as_float(b & 0xFFFF0000u);
  lo = (short)(__float_as_uint(v - hf) >> 16);
}
__device__ __forceinline__ float bf2f(short s){
  return __uint_as_float(((unsigned)(unsigned short)s) << 16);
}
__device__ __forceinline__ float4v mfma3(short8 ah, short8 al, short8 bh, short8 bl, float4v c){
  c = __builtin_amdgcn_mfma_f32_16x16x32_bf16(ah, bh, c, 0, 0, 0);
  c = __builtin_amdgcn_mfma_f32_16x16x32_bf16(ah, bl, c, 0, 0, 0);
  c = __builtin_amdgcn_mfma_f32_16x16x32_bf16(al, bh, c, 0, 0, 0);
  return c;
}

__device__ __forceinline__ float block_reduce(float v, float* scratch){
  int lane = threadIdx.x & 63;
  int w    = threadIdx.x >> 6;
  #pragma unroll
  for (int off=32; off; off>>=1) v += __shfl_down(v, off, 64);
  __syncthreads();
  if (lane==0) scratch[w] = v;
  __syncthreads();
  float r = 0.f;
  if (threadIdx.x < 4) r = scratch[threadIdx.x];
  if (w==0){ r += __shfl_down(r, 2, 64); r += __shfl_down(r, 1, 64); }
  return r;
}

// ---- 64x64 tile helpers (LDS row stride 68 floats) ----
__device__ __forceinline__ void stage64(float (*S)[68], const float* __restrict__ g, int ld, int t){
  #pragma unroll
  for (int p=t; p<1024; p+=256)
    *(float4*)&S[p>>4][(p&15)*4] = *(const float4*)&g[(size_t)(p>>4)*ld + (p&15)*4];
}
__device__ __forceinline__ void tile_gemm_step(float acc[4][4], const float (*As)[68], const float (*Bs)[68], int tx, int ty){
  for (int k=0;k<64;++k){
    float ar[4], bc4[4];
    #pragma unroll
    for (int u=0;u<4;++u){ ar[u]=As[ty*4+u][k]; bc4[u]=Bs[k][tx*4+u]; }
    #pragma unroll
    for (int u=0;u<4;++u)
      #pragma unroll
      for (int v=0;v<4;++v) acc[u][v] += ar[u]*bc4[v];
  }
}
__device__ __forceinline__ void tile_syrk_step(float acc[4][4], const float (*P)[68], const float (*Q)[68], int tx, int ty){
  for (int k=0;k<64;++k){
    float pr[4], qc[4];
    #pragma unroll
    for (int u=0;u<4;++u){ pr[u]=P[ty*4+u][k]; qc[u]=Q[tx*4+u][k]; }
    #pragma unroll
    for (int u=0;u<4;++u)
      #pragma unroll
      for (int v=0;v<4;++v) acc[u][v] += pr[u]*qc[v];
  }
}

// wave-0 register Cholesky of a 64x64 tile staged in S (LDS); no __syncthreads.
__device__ __forceinline__ void factor64_reg(const float (*S)[68],
    float* __restrict__ lkd, float* __restrict__ sdg_, int d, int t){
  if (t < 64){
    float xr[64];
    #pragma unroll
    for (int c4=0;c4<16;++c4) *(float4*)&xr[c4*4] = *(const float4*)&S[t][c4*4];
    float myrp = 1.f;
    #pragma unroll
    for (int j=0;j<64;++j){
      float ajj = __shfl(xr[j], j, 64);
      float piv = sqrtf(fmaxf(ajj, 1e-20f));
      float rp  = 1.f/piv;
      float val = xr[j]*rp;
      if (t==j){ xr[j] = piv; myrp = rp; }
      else if (t>j) xr[j] = val;
      else val = 0.f;
      #pragma unroll
      for (int c=j+1;c<64;++c){
        float vc = __shfl(val, c, 64);
        if (c<=t) xr[c] -= val*vc;
      }
    }
    #pragma unroll
    for (int c=0;c<64;++c) if (c>t) xr[c] = 0.f;
    #pragma unroll
    for (int c4=0;c4<16;++c4)
      *(float4*)&lkd[d*4096 + t*64 + c4*4] = *(float4*)&xr[c4*4];
    sdg_[d*64 + t] = myrp;
  }
}

// ================= factorization kernels (multi-launch) =================

// phase 0: 528 Kuu tiles + (blocks 528..535) zfrag; block 0 factors diag(0).
__global__ __launch_bounds__(256) void phase0_kernel(
    const float* __restrict__ z, float* __restrict__ kuu,
    short* __restrict__ zfh, short* __restrict__ zfl, float* __restrict__ zn2,
    float* __restrict__ lkdiag, float* __restrict__ sdg){
  __shared__ float As[64][68];
  __shared__ float Bs[64][68];
  const int t = threadIdx.x, tx = t & 15, ty = t >> 4;
  const int bid = blockIdx.x;
  if (bid >= 528){
    int zr = (bid-528)*256 + t;
    float v[DD]; float s = 0.f;
    #pragma unroll
    for (int d=0; d<DD; ++d){ v[d] = z[zr*DD + d]; s += v[d]*v[d]; }
    zn2[zr] = s;
    size_t base = (size_t)(zr >> 4)*512 + (zr & 15)*32;
    #pragma unroll
    for (int k=0; k<32; ++k){
      short h = 0, lo = 0;
      if (k < DD) bfsplit(v[k], h, lo);
      zfh[base + k] = h; zfl[base + k] = lo;
    }
    return;
  }
  int idx = bid;
  int r=0; while ((r+1)*(r+2)/2 <= idx) ++r;
  int c = idx - r*(r+1)/2;
  for (int p=t; p<128; p+=256){ int i=p>>1, h=p&1;
    *(float4*)&As[i][h*4] = *(const float4*)&z[(size_t)(r*64+i)*DD + h*4];
    *(float4*)&Bs[i][h*4] = *(const float4*)&z[(size_t)(c*64+i)*DD + h*4]; }
  __syncthreads();
  float kv[4][4];
  #pragma unroll
  for (int u=0;u<4;++u)
    #pragma unroll
    for (int v=0;v<4;++v){
      float d2=0.f;
      #pragma unroll
      for (int d=0;d<8;++d){ float df=As[ty*4+u][d]-Bs[tx*4+v][d]; d2+=df*df; }
      float val = __expf(-2.f*d2);
      if (r*64+ty*4+u == c*64+tx*4+v) val += 1e-6f;
      kv[u][v] = val;
    }
  #pragma unroll
  for (int u=0;u<4;++u)
    *(float4*)&kuu[(size_t)(r*64+ty*4+u)*MM + c*64 + tx*4] =
        make_float4(kv[u][0],kv[u][1],kv[u][2],kv[u][3]);
  if (idx == 0){
    __syncthreads();
    #pragma unroll
    for (int u=0;u<4;++u)
      #pragma unroll
      for (int v=0;v<4;++v) As[ty*4+u][tx*4+v] = kv[u][v];
    __syncthreads();
    factor64_reg(As, lkdiag, sdg, 0, t);
  }
}

// panel kb (kb=0..30): fused TRSM+SYRK; grid = T(T+1)/2, T = 31-kb.
// tile 0 = (kb+1,kb+1): subtract in LDS + factor -> lkdiag[kb+1] (lookahead).
__global__ __launch_bounds__(256) void panel_kernel(
    float* __restrict__ kuu, float* __restrict__ lkdiag,
    float* __restrict__ sdg, float* __restrict__ ltri, int kb){
  __shared__ float As[64][68];
  __shared__ float Bs[64][68];
  __shared__ float Cs[64][68];
  __shared__ float sd[64];
  const int t = threadIdx.x, tx = t & 15, ty = t >> 4;
  int idx = blockIdx.x;
  int r=0; while ((r+1)*(r+2)/2 <= idx) ++r;
  int c = idx - r*(r+1)/2;
  int bi = kb+1+r, bc = kb+1+c;
  stage64(Cs, lkdiag + kb*4096, 64, t);
  if (t < 64) sd[t] = sdg[kb*64 + t];
  stage64(As, kuu + (size_t)(bi*64)*MM + kb*64, MM, t);
  if (bc != bi) stage64(Bs, kuu + (size_t)(bc*64)*MM + kb*64, MM, t);
  __syncthreads();
  {
    int w = t>>6, l = t&63;
    if (w==0 || (w==1 && bc!=bi)){
      float (*S)[68] = (w==0)? As : Bs;
      float xr[64];
      #pragma unroll
      for (int c4=0;c4<16;++c4) *(float4*)&xr[c4*4] = *(const float4*)&S[l][c4*4];
      #pragma unroll
      for (int j=0;j<64;++j){
        float xj = xr[j]*sd[j];
        xr[j] = xj;
        #pragma unroll
        for (int cc=j+1;cc<64;++cc) xr[cc] -= xj*Cs[cc][j];
      }
      #pragma unroll
      for (int c4=0;c4<16;++c4) *(float4*)&S[l][c4*4] = *(float4*)&xr[c4*4];
    }
  }
  __syncthreads();
  if (bc == kb+1){
    for (int p=t;p<1024;p+=256)
      *(float4*)&ltri[(size_t)(bi*64+(p>>4))*MM + kb*64 + (p&15)*4] =
          *(float4*)&As[p>>4][(p&15)*4];
  }
  float acc[4][4] = {};
  tile_syrk_step(acc, As, (bc==bi)? As : Bs, tx, ty);
  if (bi==kb+1 && bc==kb+1){
    __syncthreads();
    #pragma unroll
    for (int u=0;u<4;++u)
      #pragma unroll
      for (int v=0;v<4;++v) Bs[ty*4+u][tx*4+v] = acc[u][v];
    __syncthreads();
    for (int p=t;p<1024;p+=256){
      int i=p>>4, c4=p&15;
      float4 kv = *(const float4*)&kuu[(size_t)(bi*64+i)*MM + bi*64 + c4*4];
      float4 bv = *(float4*)&Bs[i][c4*4];
      float4 o; o.x=kv.x-bv.x; o.y=kv.y-bv.y; o.z=kv.z-bv.z; o.w=kv.w-bv.w;
      *(float4*)&As[i][c4*4] = o;
    }
    __syncthreads();
    factor64_reg(As, lkdiag, sdg, kb+1, t);
  } else {
    #pragma unroll
    for (int u=0;u<4;++u){
      float4* dst = (float4*)&kuu[(size_t)(bi*64+ty*4+u)*MM + bc*64 + tx*4];
      float4 o = *dst;
      o.x-=acc[u][0]; o.y-=acc[u][1]; o.z-=acc[u][2]; o.w-=acc[u][3];
      *dst = o;
    }
  }
}

// p3head: phase2 + p3 level0 + p3 level1 fused; grid = 8 (block m owns
// diags 4m..4m+3, level-0 pairs 2m,2m+1, level-1 m). All deps block-local.
__global__ __launch_bounds__(256) void p3head_kernel(
    const float* __restrict__ lkdiag, const float* __restrict__ ltri,
    float* __restrict__ linv, float* __restrict__ ptmp){
  __shared__ float As[64][68];
  __shared__ float Bs[64][68];
  const int t = threadIdx.x, tx = t & 15, ty = t >> 4;
  const int m = blockIdx.x;
  // phase2: invert 4 diag blocks
  for (int d=4*m; d<4*m+4; ++d){
    __syncthreads();
    stage64(As, lkdiag + d*4096, 64, t);
    __syncthreads();
    if (t < 64){
      for (int j=0;j<64;++j){
        float s = (j==t)?1.f:0.f;
        for (int k=t;k<j;++k) s -= As[j][k]*Bs[k][t];
        Bs[j][t] = (j>=t)? s/As[j][j] : 0.f;
      }
    }
    __syncthreads();
    for (int p=t;p<1024;p+=256){ int i=p>>4, c4=p&15;
      *(float4*)&linv[(size_t)(d*64+i)*MM + d*64 + c4*4] = *(float4*)&Bs[i][c4*4]; }
  }
  // level 0 for mm = 2m, 2m+1
  for (int q2=0;q2<2;++q2){
    int mm = 2*m + q2;
    __syncthreads();
    stage64(As, ltri + (size_t)((2*mm+1)*64)*MM + (2*mm)*64, MM, t);
    stage64(Bs, linv + (size_t)((2*mm)*64)*MM   + (2*mm)*64, MM, t);
    __syncthreads();
    float acc[4][4]={};
    tile_gemm_step(acc, As, Bs, tx, ty);
    __syncthreads();
    #pragma unroll
    for (int u=0;u<4;++u)
      #pragma unroll
      for (int v=0;v<4;++v) Bs[ty*4+u][tx*4+v] = acc[u][v];
    stage64(As, linv + (size_t)((2*mm+1)*64)*MM + (2*mm+1)*64, MM, t);
    __syncthreads();
    float o[4][4]={};
    tile_gemm_step(o, As, Bs, tx, ty);
    #pragma unroll
    for (int u=0;u<4;++u)
      *(float4*)&linv[(size_t)((2*mm+1)*64+ty*4+u)*MM + (2*mm)*64 + tx*4] =
          make_float4(-o[u][0],-o[u][1],-o[u][2],-o[u][3]);
  }
  // level 1 for m
  float* pm = ptmp + (size_t)m*128*128;
  for (int ti=0; ti<2; ++ti)
    for (int tj=0; tj<2; ++tj){
      int rb = m*4 + 2 + ti, cb0 = m*4;
      float acc[4][4]={};
      for (int k=tj; k<2; ++k){
        __syncthreads();
        stage64(As, ltri + (size_t)(rb*64)*MM + (cb0+k)*64, MM, t);
        stage64(Bs, linv + (size_t)((cb0+k)*64)*MM + (cb0+tj)*64, MM, t);
        __syncthreads();
        tile_gemm_step(acc, As, Bs, tx, ty);
      }
      #pragma unroll
      for (int u=0;u<4;++u)
        *(float4*)&pm[(size_t)(ti*64+ty*4+u)*128 + tj*64 + tx*4] =
            make_float4(acc[u][0],acc[u][1],acc[u][2],acc[u][3]);
    }
  for (int ti=0; ti<2; ++ti)
    for (int tj=0; tj<2; ++tj){
      int rb = m*4 + 2 + ti;
      float acc[4][4]={};
      for (int k=0; k<=ti; ++k){
        __syncthreads();
        stage64(As, linv + (size_t)(rb*64)*MM + (m*4+2+k)*64, MM, t);
        stage64(Bs, pm + (size_t)(k*64)*128 + tj*64, 128, t);
        __syncthreads();
        tile_gemm_step(acc, As, Bs, tx, ty);
      }
      #pragma unroll
      for (int u=0;u<4;++u)
        *(float4*)&linv[(size_t)(rb*64+ty*4+u)*MM + (m*4+tj)*64 + tx*4] =
            make_float4(-acc[u][0],-acc[u][1],-acc[u][2],-acc[u][3]);
    }
}

// phase 3 levels 2..4 part A (P = A21 @ Linv_lower); grid = mc*nb*nb
__global__ __launch_bounds__(256) void p3lA_kernel(
    const float* __restrict__ ltri, const float* __restrict__ linv,
    float* __restrict__ ptmp, int s){
  __shared__ float As[64][68];
  __shared__ float Bs[64][68];
  const int t = threadIdx.x, tx = t & 15, ty = t >> 4;
  int nb = 1<<s, b = 64<<s;
  float* pmb = ptmp + (s==2 ? 131072 : (s==3 ? 393216 : 917504));
  int idx = blockIdx.x;
  int m = idx/(nb*nb), r2 = idx%(nb*nb);
  int ti = r2/nb, tj = r2%nb;
  int rb = m*2*nb + nb + ti, cb0 = m*2*nb;
  float acc[4][4]={};
  for (int k=tj; k<nb; ++k){
    __syncthreads();
    stage64(As, ltri + (size_t)(rb*64)*MM + (cb0+k)*64, MM, t);
    stage64(Bs, linv + (size_t)((cb0+k)*64)*MM + (cb0+tj)*64, MM, t);
    __syncthreads();
    tile_gemm_step(acc, As, Bs, tx, ty);
  }
  float* pm = pmb + (size_t)m*b*b;
  #pragma unroll
  for (int u=0;u<4;++u)
    *(float4*)&pm[(size_t)(ti*64+ty*4+u)*b + tj*64 + tx*4] =
        make_float4(acc[u][0],acc[u][1],acc[u][2],acc[u][3]);
}

// phase 3 levels 2..4 part B (Linv21 = -Linv_lower @ P); grid = mc*nb*nb
__global__ __launch_bounds__(256) void p3lB_kernel(
    float* __restrict__ linv, const float* __restrict__ ptmp, int s){
  __shared__ float As[64][68];
  __shared__ float Bs[64][68];
  const int t = threadIdx.x, tx = t & 15, ty = t >> 4;
  int nb = 1<<s, b = 64<<s;
  const float* pmb = ptmp + (s==2 ? 131072 : (s==3 ? 393216 : 917504));
  int idx = blockIdx.x;
  int m = idx/(nb*nb), r2 = idx%(nb*nb);
  int ti = r2/nb, tj = r2%nb;
  int rb = m*2*nb + nb + ti;
  const float* pm = pmb + (size_t)m*b*b;
  float acc[4][4]={};
  for (int k=0; k<=ti; ++k){
    __syncthreads();
    stage64(As, linv + (size_t)(rb*64)*MM + (m*2*nb+nb+k)*64, MM, t);
    stage64(Bs, pm + (size_t)(k*64)*b + tj*64, b, t);
    __syncthreads();
    tile_gemm_step(acc, As, Bs, tx, ty);
  }
  #pragma unroll
  for (int u=0;u<4;++u)
    *(float4*)&linv[(size_t)(rb*64+ty*4+u)*MM + (m*2*nb+tj)*64 + tx*4] =
        make_float4(-acc[u][0],-acc[u][1],-acc[u][2],-acc[u][3]);
}

// phase 4a: W = Linv @ tril(qL), both GPs; grid = 2*528
__global__ __launch_bounds__(256) void w_kernel(
    const float* __restrict__ linv, const float* __restrict__ qlf,
    const float* __restrict__ qlg, float* __restrict__ wf, float* __restrict__ wg){
  __shared__ float As[64][68];
  __shared__ float Bs[64][68];
  const int t = threadIdx.x, tx = t & 15, ty = t >> 4;
  int idx = blockIdx.x;
  int gp = idx/528, rem = idx%528;
  int bi=0; while ((bi+1)*(bi+2)/2 <= rem) ++bi;
  int bj = rem - bi*(bi+1)/2;
  const float* ql = gp ? qlg : qlf;
  float* w        = gp ? wg  : wf;
  float acc[4][4]={};
  for (int bk=bj; bk<=bi; ++bk){
    __syncthreads();
    stage64(As, linv + (size_t)(bi*64)*MM + bk*64, MM, t);
    stage64(Bs, ql   + (size_t)(bk*64)*MM + bj*64, MM, t);
    __syncthreads();
    if (bk==bj){
      for (int p=t;p<4096;p+=256){ int i=p>>6, c=p&63; if (i<c) Bs[i][c]=0.f; }
      __syncthreads();
    }
    tile_gemm_step(acc, As, Bs, tx, ty);
  }
  #pragma unroll
  for (int u=0;u<4;++u)
    *(float4*)&w[(size_t)(bi*64+ty*4+u)*MM + bj*64 + tx*4] =
        make_float4(acc[u][0],acc[u][1],acc[u][2],acc[u][3]);
}

// phase 4b: alpha = Linv @ qm, both GPs; grid = 256
__global__ __launch_bounds__(256) void alpha_kernel(
    const float* __restrict__ linv, const float* __restrict__ qmf,
    const float* __restrict__ qmg, float* __restrict__ af, float* __restrict__ ag){
  int t = threadIdx.x;
  int gw = blockIdx.x*4 + (t>>6), l = t&63;
  for (int job=gw; job<4096; job+=1024){
    int gp = job>>11, r = job&2047;
    const float* qm = gp ? qmg : qmf;
    float s=0.f;
    for (int c=l; c<=r; c+=64) s += linv[(size_t)r*MM+c]*qm[c];
    #pragma unroll
    for (int off=32; off; off>>=1) s += __shfl_down(s, off, 64);
    if (l==0) (gp ? ag : af)[r] = s;
  }
}

// ================= small kernels (pre/post) =================

__global__ __launch_bounds__(256) void red_small(const float* __restrict__ lkd,
    const float* __restrict__ qlf, const float* __restrict__ qlg,
    const float* __restrict__ af, const float* __restrict__ ag,
    float* __restrict__ scal){
  __shared__ float scratch[4];
  float ldk=0, ldf=0, ldg=0, a2f=0, a2g=0;
  for (int i=threadIdx.x;i<MM;i+=256){
    int kb = i>>6, r = i&63;
    ldk += __logf(lkd[kb*4096 + r*64 + r]);
    ldf += __logf(fabsf(qlf[(size_t)i*MM+i]));
    ldg += __logf(fabsf(qlg[(size_t)i*MM+i]));
    float v = af[i]; a2f += v*v;
    v = ag[i];       a2g += v*v;
  }
  float r;
  r = block_reduce(ldk, scratch); if (threadIdx.x==0) scal[0] = 2.f*r;
  r = block_reduce(ldf, scratch); if (threadIdx.x==0) scal[1] = 2.f*r;
  r = block_reduce(ldg, scratch); if (threadIdx.x==0) scal[2] = 2.f*r;
  r = block_reduce(a2f, scratch); if (threadIdx.x==0) scal[3] = r;
  r = block_reduce(a2g, scratch); if (threadIdx.x==0) scal[4] = r;
}

__global__ __launch_bounds__(256) void redw_kernel(const float* __restrict__ wf,
    const float* __restrict__ wg, float* __restrict__ scal){
  __shared__ float scratch[4];
  size_t start  = (size_t)blockIdx.x*256 + threadIdx.x;
  size_t stride = (size_t)gridDim.x*256;
  float sf=0, sg=0;
  for (size_t p=start;p<(size_t)MM*MM;p+=stride){
    float v=wf[p]; sf += v*v;
    v=wg[p];       sg += v*v;
  }
  float r = block_reduce(sf, scratch);
  if (threadIdx.x==0) atomicAdd(&scal[5], r);
  r = block_reduce(sg, scratch);
  if (threadIdx.x==0) atomicAdd(&scal[6], r);
}

__global__ void kl_kernel(const float* __restrict__ scal, float* __restrict__ out){
  float klf = 0.5f*(scal[5] + scal[3] - (float)MM + scal[0] - scal[1]);
  float klg = 0.5f*(scal[6] + scal[4] - (float)MM + scal[0] - scal[2]);
  out[0] += klf + klg;
}

// merged splits: blocks [0,16384) rowmajor(linv); [16384,24576) transpose wf/wg
__global__ __launch_bounds__(256) void split_all(
    const float* __restrict__ linv, const float* __restrict__ wf,
    const float* __restrict__ wg, short* __restrict__ lvh, short* __restrict__ lvl,
    short* __restrict__ wfh, short* __restrict__ wfl,
    short* __restrict__ wgh, short* __restrict__ wgl){
  __shared__ float tile[32][33];
  const int t = threadIdx.x;
  const int bid = blockIdx.x;
  if (bid < 16384){
    int p = bid*256 + t;
    int chunk = p >> 9, wi = p & 511;
    int mo = chunk >> 6, ko = chunk & 63;
    int row = mo*16 + (wi >> 5), col = ko*32 + (wi & 31);
    float v = linv[(size_t)row*MM + col];
    short h, lo; bfsplit(v, h, lo);
    lvh[p] = h; lvl[p] = lo;
    return;
  }
  int idx2 = bid - 16384;
  int zz = idx2 >> 12;
  int rem = idx2 & 4095;
  int mb = rem & 63, kb = rem >> 6;
  const float* src = zz ? wg : wf;
  short* dh = zz ? wgh : wfh;
  short* dl = zz ? wgl : wfl;
  #pragma unroll
  for (int k=0;k<4;++k){
    int idx = t + k*256;
    int lr = idx >> 5, lc = idx & 31;
    tile[lr][lc] = src[(size_t)(kb*32+lr)*MM + mb*32 + lc];
  }
  __syncthreads();
  #pragma unroll
  for (int e=0;e<4;++e){
    int p = t*4 + e;
    int c = p >> 9, wi = p & 511;
    int i = (wi >> 5) & 15, kk = wi & 31;
    float v = tile[kk][c*16 + i];
    short h, lo; bfsplit(v, h, lo);
    size_t gp = ((size_t)(mb*2 + c)*64 + kb)*512 + wi;
    dh[gp] = h; dl[gp] = lo;
  }
}

__global__ __launch_bounds__(256, 2) void tt_mfma(
    const float* __restrict__ x, const float* __restrict__ zn2,
    const short* __restrict__ zfh, const short* __restrict__ zfl,
    const short* __restrict__ lvh, const short* __restrict__ lvl,
    short* __restrict__ tth, short* __restrict__ ttl){
  __shared__ __align__(16) short lAh[8192], lAl[8192], lBh[8192], lBl[8192];
  int t = threadIdx.x;
  int l = t & 63, w = t >> 6;
  int istrip = blockIdx.x, bj2 = blockIdx.y;
  int li = l & 15, q = l >> 4;
  int lofs = li*32 + q*8;
  int wn4 = (w>>1)*4, wm4 = (w&1)*4;

  short8 xh[2], xl[2];
  float xn2v[8];
  {
    float xn2t[2];
    #pragma unroll
    for (int tn=0; tn<2; ++tn){
      int n = istrip*128 + w*32 + tn*16 + li;
      const float4* xp = (const float4*)(x + (size_t)n*DD);
      float4 p0 = xp[0], p1 = xp[1];
      float v[8] = {p0.x,p0.y,p0.z,p0.w,p1.x,p1.y,p1.z,p1.w};
      float s = 0.f;
      #pragma unroll
      for (int d=0; d<8; ++d) s += v[d]*v[d];
      xn2t[tn] = s;
      short8 hh, ll;
      #pragma unroll
      for (int j=0; j<8; ++j){
        short h=0, lo=0;
        if (q==0) bfsplit(v[j], h, lo);
        hh[j]=h; ll[j]=lo;
      }
      xh[tn]=hh; xl[tn]=ll;
    }
    #pragma unroll
    for (int tn=0; tn<2; ++tn)
      #pragma unroll
      for (int r=0; r<4; ++r)
        xn2v[tn*4+r] = __shfl(xn2t[tn], q*4 + r, 64);
  }

  float4v acc[4][4];
  #pragma unroll
  for (int i=0;i<4;++i)
    #pragma unroll
    for (int j=0;j<4;++j) acc[i][j] = f4zero();

  int nkt = 2*bj2 + 2;
  for (int bk=0; bk<nkt; ++bk){
    __syncthreads();
    {
      short8 zh[4], zl[4];
      float zt2[4];
      #pragma unroll
      for (int tz=0; tz<4; ++tz){
        size_t zo = (size_t)(bk*4 + tz)*512 + lofs;
        zh[tz] = *(const short8*)(zfh + zo);
        zl[tz] = *(const short8*)(zfl + zo);
        zt2[tz] = zn2[bk*64 + tz*16 + li];
      }
      #pragma unroll
      for (int tn=0; tn<2; ++tn){
        #pragma unroll
        for (int tz=0; tz<4; ++tz){
          float4v s4 = mfma3(xh[tn], xl[tn], zh[tz], zl[tz], f4zero());
          #pragma unroll
          for (int r=0; r<4; ++r){
            float e = __expf(4.f*s4[r] - 2.f*(xn2v[tn*4+r] + zt2[tz]));
            short h, lo; bfsplit(e, h, lo);
            int pos = ((w*2+tn)*2 + (tz>>1))*512 + (q*4+r)*32 + (tz&1)*16 + li;
            lAh[pos] = h; lAl[pos] = lo;
          }
        }
      }
    }
    #pragma unroll
    for (int c4 = t; c4 < 1024; c4 += 256){
      int ch = c4 >> 6, wdi = c4 & 63;
      size_t g = ((size_t)(bj2*8 + (ch>>1))*64 + (size_t)(bk*2 + (ch&1)))*64 + wdi;
      ((uint4*)lBh)[c4] = ((const uint4*)lvh)[g];
      ((uint4*)lBl)[c4] = ((const uint4*)lvl)[g];
    }
    __syncthreads();
    #pragma unroll
    for (int s=0; s<2; ++s){
      short8 ah[4], al[4], bh[4], bl[4];
      #pragma unroll
      for (int tn=0; tn<4; ++tn){
        int off = ((wn4+tn)*2 + s)*512 + lofs;
        ah[tn] = *(const short8*)&lAh[off];
        al[tn] = *(const short8*)&lAl[off];
      }
      #pragma unroll
      for (int tm=0; tm<4; ++tm){
        int off = ((wm4+tm)*2 + s)*512 + lofs;
        bh[tm] = *(const short8*)&lBh[off];
        bl[tm] = *(const short8*)&lBl[off];
      }
      #pragma unroll
      for (int tn=0; tn<4; ++tn)
        #pragma unroll
        for (int tm=0; tm<4; ++tm)
          acc[tn][tm] = mfma3(ah[tn], al[tn], bh[tm], bl[tm], acc[tn][tm]);
    }
  }
  #pragma unroll
  for (int tn=0; tn<4; ++tn){
    int no_g = istrip*8 + wn4 + tn;
    #pragma unroll
    for (int tm=0; tm<4; ++tm){
      int mo_g = bj2*4 + (w&1)*2 + (tm>>1);
      size_t cb = ((size_t)no_g*64 + mo_g)*512;
      #pragma unroll
      for (int r=0; r<4; ++r){
        short h, lo; bfsplit(acc[tn][tm][r], h, lo);
        size_t pos = cb + (q*4+r)*32 + (tm&1)*16 + li;
        tth[pos] = h; ttl[pos] = lo;
      }
    }
  }
}

__global__ __launch_bounds__(256) void lin_v2(const short* __restrict__ tth,
    const short* __restrict__ ttl, const float* __restrict__ af, const float* __restrict__ ag,
    float* __restrict__ t2, float* __restrict__ lf, float* __restrict__ lg){
  int t = threadIdx.x;
  int w = t >> 6, l = t & 63;
  int n = blockIdx.x*4 + w;
  int g = l >> 2, j = l & 3;
  float s2=0.f, sf=0.f, sg=0.f;
  #pragma unroll
  for (int it=0; it<4; ++it){
    int ck = g + it*16;
    size_t off = ((size_t)(n>>4)*64 + ck)*512 + (n&15)*32 + j*8;
    short8 h8 = *(const short8*)(tth + off);
    short8 l8 = *(const short8*)(ttl + off);
    int m0 = ck*32 + j*8;
    float4 a0 = *(const float4*)(af + m0), a1 = *(const float4*)(af + m0 + 4);
    float4 g0 = *(const float4*)(ag + m0), g1 = *(const float4*)(ag + m0 + 4);
    float av[8] = {a0.x,a0.y,a0.z,a0.w,a1.x,a1.y,a1.z,a1.w};
    float gv[8] = {g0.x,g0.y,g0.z,g0.w,g1.x,g1.y,g1.z,g1.w};
    #pragma unroll
    for (int e=0; e<8; ++e){
      float tv = bf2f(h8[e]) + bf2f(l8[e]);
      s2 += tv*tv; sf += tv*av[e]; sg += tv*gv[e];
    }
  }
  #pragma unroll
  for (int off=32; off; off>>=1){
    s2 += __shfl_down(s2, off, 64);
    sf += __shfl_down(sf, off, 64);
    sg += __shfl_down(sg, off, 64);
  }
  if (l==0){ t2[n] = s2; lf[n] = sf; lg[n] = sg; }
}

__global__ __launch_bounds__(256, 2) void quad_mfma(
    const short* __restrict__ tth, const short* __restrict__ ttl,
    const short* __restrict__ wfh, const short* __restrict__ wfl,
    const short* __restrict__ wgh, const short* __restrict__ wgl,
    float* __restrict__ vfq, float* __restrict__ vgq){
  __shared__ __align__(16) short lAh[8192], lAl[8192], lBh[8192], lBl[8192];
  int t = threadIdx.x, l = t & 63, w = t >> 6;
  int istrip = blockIdx.x, bj2 = blockIdx.y;
  const short* gbh = blockIdx.z ? wgh : wfh;
  const short* gbl = blockIdx.z ? wgl : wfl;
  float* vq = blockIdx.z ? vgq : vfq;
  int li = l & 15, q = l >> 4;
  int lofs = li*32 + q*8;
  int wn4 = (w>>1)*4, wm4 = (w&1)*4;

  float4v acc[4][4];
  #pragma unroll
  for (int i=0;i<4;++i)
    #pragma unroll
    for (int j=0;j<4;++j) acc[i][j] = f4zero();

  for (int bk=2*bj2; bk<32; ++bk){
    __syncthreads();
    #pragma unroll
    for (int c4 = t; c4 < 1024; c4 += 256){
      int ch = c4 >> 6, wdi = c4 & 63;
      size_t ga = ((size_t)(istrip*8 + (ch>>1))*64 + (size_t)(bk*2 + (ch&1)))*64 + wdi;
      ((uint4*)lAh)[c4] = ((const uint4*)tth)[ga];
      ((uint4*)lAl)[c4] = ((const uint4*)ttl)[ga];
      size_t gb = ((size_t)(bj2*8 + (ch>>1))*64 + (size_t)(bk*2 + (ch&1)))*64 + wdi;
      ((uint4*)lBh)[c4] = ((const uint4*)gbh)[gb];
      ((uint4*)lBl)[c4] = ((const uint4*)gbl)[gb];
    }
    __syncthreads();
    #pragma unroll
    for (int s=0; s<2; ++s){
      short8 ah[4], al[4], bh[4], bl[4];
      #pragma unroll
      for (int tn=0; tn<4; ++tn){
        int off = ((wn4+tn)*2 + s)*512 + lofs;
        ah[tn] = *(const short8*)&lAh[off];
        al[tn] = *(const short8*)&lAl[off];
      }
      #pragma unroll
      for (int tm=0; tm<4; ++tm){
        int off = ((wm4+tm)*2 + s)*512 + lofs;
        bh[tm] = *(const short8*)&lBh[off];
        bl[tm] = *(const short8*)&lBl[off];
      }
      #pragma unroll
      for (int tn=0; tn<4; ++tn)
        #pragma unroll
        for (int tm=0; tm<4; ++tm)
          acc[tn][tm] = mfma3(ah[tn], al[tn], bh[tm], bl[tm], acc[tn][tm]);
    }
  }
  float rs[16];
  #pragma unroll
  for (int tn=0; tn<4; ++tn)
    #pragma unroll
    for (int r=0; r<4; ++r){
      float s = 0.f;
      #pragma unroll
      for (int tm=0; tm<4; ++tm){ float v = acc[tn][tm][r]; s += v*v; }
      rs[tn*4+r] = s;
    }
  #pragma unroll
  for (int off=8; off; off>>=1)
    #pragma unroll
    for (int k=0; k<16; ++k) rs[k] += __shfl_down(rs[k], off, 16);
  if (li == 0){
    #pragma unroll
    for (int tn=0; tn<4; ++tn)
      #pragma unroll
      for (int r=0; r<4; ++r){
        int n = istrip*128 + (w>>1)*64 + tn*16 + q*4 + r;
        atomicAdd(&vq[n], rs[tn*4+r]);
      }
  }
}

__global__ __launch_bounds__(256) void final_kernel(const float* __restrict__ y,
    const float* __restrict__ t2, const float* __restrict__ lf, const float* __restrict__ lg,
    const float* __restrict__ vfq, const float* __restrict__ vgq, float* __restrict__ out){
  __shared__ float scratch[4];
  int i = blockIdx.x*256 + threadIdx.x;
  float mf = lf[i], mg = lg[i];
  float vf = 1.f + vfq[i] - t2[i];
  float vg = 1.f + vgq[i] - t2[i];
  float dy = y[i] - mf;
  float e = -HLOG2PI - 0.5f*mg - 0.5f*(dy*dy + vf)*__expf(-mg + 0.5f*vg);
  float r = block_reduce(e, scratch);
  if (threadIdx.x==0) atomicAdd(out, -r);
}

extern "C" void kernel_launch(void* const* d_in, const int* in_sizes, int n_in,
                              void* d_out, int out_size, void* d_ws, size_t ws_size,
                              hipStream_t stream){
  (void)in_sizes; (void)n_in; (void)out_size; (void)ws_size;
  const float* x   = (const float*)d_in[0];
  const float* y   = (const float*)d_in[1];
  const float* z   = (const float*)d_in[2];
  const float* qmf = (const float*)d_in[3];
  const float* qlf = (const float*)d_in[4];
  const float* qmg = (const float*)d_in[5];
  const float* qlg = (const float*)d_in[6];
  float* out = (float*)d_out;
  char* Bw = (char*)d_ws;

  float* kuu  = (float*)Bw;
  float* linv = (float*)(Bw + SZB);
  float* wf   = (float*)(Bw + 2*SZB);
  float* wg   = (float*)(Bw + 3*SZB);
  short* lvh  = (short*)Bw;
  short* lvl  = (short*)(Bw + SZB/2);
  short* wfh  = (short*)(Bw + SZB);
  short* wfl  = (short*)(Bw + SZB + SZB/2);
  short* wgh  = (short*)(Bw + 2*SZB);
  short* wgl  = (short*)(Bw + 2*SZB + SZB/2);
  short* tth  = (short*)(Bw + 3*SZB);
  short* ttl  = (short*)(Bw + 3*SZB + (size_t)NN*MM*2);
  // dead-tt region [64M,112M): ltri 16MB, ptmp 8MB (per-level disjoint),
  // lkdiag 512KB, sdg 8KB
  float* ltri   = (float*)(Bw + 4*SZB);
  float* ptmp   = (float*)(Bw + 5*SZB);
  float* lkdiag = (float*)(Bw + 5*SZB + (size_t)8388608);
  float* sdg    = (float*)(Bw + 5*SZB + (size_t)8388608 + (size_t)524288);
  float* sm   = (float*)(Bw + 3*SZB + (size_t)NN*MM*4);
  float* af = sm;          float* ag = af + MM;
  float* t2 = ag + MM;     float* lf = t2 + NN;   float* lg = lf + NN;
  float* vfq = lg + NN;    float* vgq = vfq + NN; float* scal = vgq + NN;
  float* zn2 = scal + 64 + 2048;
  short* zfh = (short*)(zn2 + MM);
  short* zfl = zfh + MM*32;

  hipMemsetAsync(out, 0, sizeof(float), stream);
  hipMemsetAsync(vfq, 0, (size_t)(2*NN + 64 + 2048)*sizeof(float), stream); // vfq,vgq,scal
  hipMemsetAsync(wf,  0, 2*SZB, stream);    // W upper triangles must be 0
  hipMemsetAsync(linv,0, SZB,   stream);    // Linv upper must be 0

  // ---- factorization: multi-launch, fused endpoints ----
  phase0_kernel<<<536, 256, 0, stream>>>(z, kuu, zfh, zfl, zn2, lkdiag, sdg);
  for (int kb = 0; kb < 31; ++kb){
    int T = NB - 1 - kb;
    panel_kernel<<<T*(T+1)/2, 256, 0, stream>>>(kuu, lkdiag, sdg, ltri, kb);
  }
  p3head_kernel<<<8, 256, 0, stream>>>(lkdiag, ltri, linv, ptmp);
  for (int s = 2; s < 5; ++s){
    int nb = 1<<s, mc = 16>>s;
    p3lA_kernel<<<mc*nb*nb, 256, 0, stream>>>(ltri, linv, ptmp, s);
    p3lB_kernel<<<mc*nb*nb, 256, 0, stream>>>(linv, ptmp, s);
  }
  w_kernel<<<2*528, 256, 0, stream>>>(linv, qlf, qlg, wf, wg);
  alpha_kernel<<<256, 256, 0, stream>>>(linv, qmf, qmg, af, ag);

  red_small<<<1, 256, 0, stream>>>(lkdiag, qlf, qlg, af, ag, scal);
  redw_kernel<<<512, 256, 0, stream>>>(wf, wg, scal);
  kl_kernel<<<1, 1, 0, stream>>>(scal, out);

  split_all<<<24576, 256, 0, stream>>>(linv, wf, wg, lvh, lvl, wfh, wfl, wgh, wgl);

  tt_mfma<<<dim3(NN/128, MM/128), 256, 0, stream>>>(x, zn2, zfh, zfl, lvh, lvl, tth, ttl);
  lin_v2<<<NN/4, 256, 0, stream>>>(tth, ttl, af, ag, t2, lf, lg);
  quad_mfma<<<dim3(NN/128, MM/128, 2), 256, 0, stream>>>(tth, ttl, wfh, wfl, wgh, wgl, vfq, vgq);
  final_kernel<<<NN/256, 256, 0, stream>>>(y, t2, lf, lg, vfq, vgq, out);
}

// Round 12
// 3874.736 us; speedup vs baseline: 1.2655x; 1.0728x over previous
//
#include <hip/hip_runtime.h>
#include <math.h>

// ChainedGP v19: v15 structure (best@3914; v18 showed the phase0-fusion and
// p3head fusions are net-negative — serial poles, esp. p3head's 4 sequential
// triangular inversions — so both reverted) + the one safe fusion (split_all:
// 3 independent split launches -> 1) + LDS bank-conflict XOR-swizzle in
// tt_mfma/quad_mfma. quad showed SQ_LDS_BANK_CONFLICT=3.57e7: short8 LDS
// reads at 64B row stride = ~8-way conflict. Swizzle slot^=(row>>1)&3 on
// BOTH store and read (LDS-private; global layouts untouched => identical
// math): staging wdi'=(wdi&60)|((wdi^(wdi>>3))&3); reads
// lofs_s=li*32+(q^((li>>1)&3))*8; tt scalar P-store slot'=slot^((rowc>>1)&3).
#define NN 16384
#define MM 2048
#define DD 8
#define NB 32                     // MM/64
#define SZB ((size_t)16777216)    // 2048*2048*4 bytes

constexpr float HLOG2PI = 0.91893853320467274178f;

using short8  = __attribute__((ext_vector_type(8))) short;
using float4v = __attribute__((ext_vector_type(4))) float;

__device__ __forceinline__ float4v f4zero(){ float4v v; v[0]=0.f; v[1]=0.f; v[2]=0.f; v[3]=0.f; return v; }

__device__ __forceinline__ void bfsplit(float v, short& h, short& lo){
  unsigned b = __float_as_uint(v);
  h = (short)(b >> 16);
  float hf = __uint_as_float(b & 0xFFFF0000u);
  lo = (short)(__float_as_uint(v - hf) >> 16);
}
__device__ __forceinline__ float bf2f(short s){
  return __uint_as_float(((unsigned)(unsigned short)s) << 16);
}
__device__ __forceinline__ float4v mfma3(short8 ah, short8 al, short8 bh, short8 bl, float4v c){
  c = __builtin_amdgcn_mfma_f32_16x16x32_bf16(ah, bh, c, 0, 0, 0);
  c = __builtin_amdgcn_mfma_f32_16x16x32_bf16(ah, bl, c, 0, 0, 0);
  c = __builtin_amdgcn_mfma_f32_16x16x32_bf16(al, bh, c, 0, 0, 0);
  return c;
}

__device__ __forceinline__ float block_reduce(float v, float* scratch){
  int lane = threadIdx.x & 63;
  int w    = threadIdx.x >> 6;
  #pragma unroll
  for (int off=32; off; off>>=1) v += __shfl_down(v, off, 64);
  __syncthreads();
  if (lane==0) scratch[w] = v;
  __syncthreads();
  float r = 0.f;
  if (threadIdx.x < 4) r = scratch[threadIdx.x];
  if (w==0){ r += __shfl_down(r, 2, 64); r += __shfl_down(r, 1, 64); }
  return r;
}

// ---- 64x64 tile helpers (LDS row stride 68 floats) ----
__device__ __forceinline__ void stage64(float (*S)[68], const float* __restrict__ g, int ld, int t){
  #pragma unroll
  for (int p=t; p<1024; p+=256)
    *(float4*)&S[p>>4][(p&15)*4] = *(const float4*)&g[(size_t)(p>>4)*ld + (p&15)*4];
}
__device__ __forceinline__ void tile_gemm_step(float acc[4][4], const float (*As)[68], const float (*Bs)[68], int tx, int ty){
  for (int k=0;k<64;++k){
    float ar[4], bc4[4];
    #pragma unroll
    for (int u=0;u<4;++u){ ar[u]=As[ty*4+u][k]; bc4[u]=Bs[k][tx*4+u]; }
    #pragma unroll
    for (int u=0;u<4;++u)
      #pragma unroll
      for (int v=0;v<4;++v) acc[u][v] += ar[u]*bc4[v];
  }
}
__device__ __forceinline__ void tile_syrk_step(float acc[4][4], const float (*P)[68], const float (*Q)[68], int tx, int ty){
  for (int k=0;k<64;++k){
    float pr[4], qc[4];
    #pragma unroll
    for (int u=0;u<4;++u){ pr[u]=P[ty*4+u][k]; qc[u]=Q[tx*4+u][k]; }
    #pragma unroll
    for (int u=0;u<4;++u)
      #pragma unroll
      for (int v=0;v<4;++v) acc[u][v] += pr[u]*qc[v];
  }
}

// wave-0 register Cholesky of a 64x64 tile staged in S (LDS); no __syncthreads.
__device__ __forceinline__ void factor64_reg(const float (*S)[68],
    float* __restrict__ lkd, float* __restrict__ sdg_, int d, int t){
  if (t < 64){
    float xr[64];
    #pragma unroll
    for (int c4=0;c4<16;++c4) *(float4*)&xr[c4*4] = *(const float4*)&S[t][c4*4];
    float myrp = 1.f;
    #pragma unroll
    for (int j=0;j<64;++j){
      float ajj = __shfl(xr[j], j, 64);
      float piv = sqrtf(fmaxf(ajj, 1e-20f));
      float rp  = 1.f/piv;
      float val = xr[j]*rp;
      if (t==j){ xr[j] = piv; myrp = rp; }
      else if (t>j) xr[j] = val;
      else val = 0.f;
      #pragma unroll
      for (int c=j+1;c<64;++c){
        float vc = __shfl(val, c, 64);
        if (c<=t) xr[c] -= val*vc;
      }
    }
    #pragma unroll
    for (int c=0;c<64;++c) if (c>t) xr[c] = 0.f;
    #pragma unroll
    for (int c4=0;c4<16;++c4)
      *(float4*)&lkd[d*4096 + t*64 + c4*4] = *(float4*)&xr[c4*4];
    sdg_[d*64 + t] = myrp;
  }
}

// ================= factorization kernels (multi-launch) =================

// phase 0: all 528 lower Kuu tiles; grid = 528
__global__ __launch_bounds__(256) void phase0_kernel(
    const float* __restrict__ z, float* __restrict__ kuu){
  __shared__ float As[64][68];
  __shared__ float Bs[64][68];
  const int t = threadIdx.x, tx = t & 15, ty = t >> 4;
  int idx = blockIdx.x;
  int r=0; while ((r+1)*(r+2)/2 <= idx) ++r;
  int c = idx - r*(r+1)/2;
  for (int p=t; p<128; p+=256){ int i=p>>1, h=p&1;
    *(float4*)&As[i][h*4] = *(const float4*)&z[(size_t)(r*64+i)*DD + h*4];
    *(float4*)&Bs[i][h*4] = *(const float4*)&z[(size_t)(c*64+i)*DD + h*4]; }
  __syncthreads();
  #pragma unroll
  for (int u=0;u<4;++u){
    float4 o;
    float* ov = (float*)&o;
    #pragma unroll
    for (int v=0;v<4;++v){
      float d2=0.f;
      #pragma unroll
      for (int d=0;d<8;++d){ float df=As[ty*4+u][d]-Bs[tx*4+v][d]; d2+=df*df; }
      float val = __expf(-2.f*d2);
      if (r*64+ty*4+u == c*64+tx*4+v) val += 1e-6f;
      ov[v] = val;
    }
    *(float4*)&kuu[(size_t)(r*64+ty*4+u)*MM + c*64 + tx*4] = o;
  }
}

// factor diag(0); grid = 1
__global__ __launch_bounds__(256) void diag0_kernel(
    const float* __restrict__ kuu, float* __restrict__ lkdiag, float* __restrict__ sdg){
  __shared__ float As[64][68];
  const int t = threadIdx.x;
  stage64(As, kuu, MM, t);
  __syncthreads();
  factor64_reg(As, lkdiag, sdg, 0, t);
}

// panel kb: fused TRSM+SYRK; grid = T(T+1)/2, T = 31-kb.
// tile 0 = (kb+1,kb+1): subtract in LDS + factor -> lkdiag[kb+1] (lookahead).
__global__ __launch_bounds__(256) void panel_kernel(
    float* __restrict__ kuu, float* __restrict__ lkdiag,
    float* __restrict__ sdg, float* __restrict__ ltri, int kb){
  __shared__ float As[64][68];
  __shared__ float Bs[64][68];
  __shared__ float Cs[64][68];
  __shared__ float sd[64];
  const int t = threadIdx.x, tx = t & 15, ty = t >> 4;
  int idx = blockIdx.x;
  int r=0; while ((r+1)*(r+2)/2 <= idx) ++r;
  int c = idx - r*(r+1)/2;
  int bi = kb+1+r, bc = kb+1+c;
  stage64(Cs, lkdiag + kb*4096, 64, t);
  if (t < 64) sd[t] = sdg[kb*64 + t];
  stage64(As, kuu + (size_t)(bi*64)*MM + kb*64, MM, t);
  if (bc != bi) stage64(Bs, kuu + (size_t)(bc*64)*MM + kb*64, MM, t);
  __syncthreads();
  {
    int w = t>>6, l = t&63;
    if (w==0 || (w==1 && bc!=bi)){
      float (*S)[68] = (w==0)? As : Bs;
      float xr[64];
      #pragma unroll
      for (int c4=0;c4<16;++c4) *(float4*)&xr[c4*4] = *(const float4*)&S[l][c4*4];
      #pragma unroll
      for (int j=0;j<64;++j){
        float xj = xr[j]*sd[j];
        xr[j] = xj;
        #pragma unroll
        for (int cc=j+1;cc<64;++cc) xr[cc] -= xj*Cs[cc][j];
      }
      #pragma unroll
      for (int c4=0;c4<16;++c4) *(float4*)&S[l][c4*4] = *(float4*)&xr[c4*4];
    }
  }
  __syncthreads();
  if (bc == kb+1){
    for (int p=t;p<1024;p+=256)
      *(float4*)&ltri[(size_t)(bi*64+(p>>4))*MM + kb*64 + (p&15)*4] =
          *(float4*)&As[p>>4][(p&15)*4];
  }
  float acc[4][4] = {};
  tile_syrk_step(acc, As, (bc==bi)? As : Bs, tx, ty);
  if (bi==kb+1 && bc==kb+1){
    __syncthreads();
    #pragma unroll
    for (int u=0;u<4;++u)
      #pragma unroll
      for (int v=0;v<4;++v) Bs[ty*4+u][tx*4+v] = acc[u][v];
    __syncthreads();
    for (int p=t;p<1024;p+=256){
      int i=p>>4, c4=p&15;
      float4 kv = *(const float4*)&kuu[(size_t)(bi*64+i)*MM + bi*64 + c4*4];
      float4 bv = *(float4*)&Bs[i][c4*4];
      float4 o; o.x=kv.x-bv.x; o.y=kv.y-bv.y; o.z=kv.z-bv.z; o.w=kv.w-bv.w;
      *(float4*)&As[i][c4*4] = o;
    }
    __syncthreads();
    factor64_reg(As, lkdiag, sdg, kb+1, t);
  } else {
    #pragma unroll
    for (int u=0;u<4;++u){
      float4* dst = (float4*)&kuu[(size_t)(bi*64+ty*4+u)*MM + bc*64 + tx*4];
      float4 o = *dst;
      o.x-=acc[u][0]; o.y-=acc[u][1]; o.z-=acc[u][2]; o.w-=acc[u][3];
      *dst = o;
    }
  }
}

// phase 2: invert 64x64 diagonal blocks; grid = 32
__global__ __launch_bounds__(256) void phase2_kernel(
    const float* __restrict__ lkdiag, float* __restrict__ linv){
  __shared__ float As[64][68];
  __shared__ float Bs[64][68];
  const int t = threadIdx.x, bid = blockIdx.x;
  stage64(As, lkdiag + bid*4096, 64, t);
  __syncthreads();
  if (t < 64){
    for (int j=0;j<64;++j){
      float s = (j==t)?1.f:0.f;
      for (int k=t;k<j;++k) s -= As[j][k]*Bs[k][t];
      Bs[j][t] = (j>=t)? s/As[j][j] : 0.f;
    }
  }
  __syncthreads();
  for (int p=t;p<1024;p+=256){ int i=p>>4, c4=p&15;
    *(float4*)&linv[(size_t)(bid*64+i)*MM + bid*64 + c4*4] = *(float4*)&Bs[i][c4*4]; }
}

// phase 3 level 0 (fused); grid = 16
__global__ __launch_bounds__(256) void p3l0_kernel(
    const float* __restrict__ ltri, float* __restrict__ linv){
  __shared__ float As[64][68];
  __shared__ float Bs[64][68];
  const int t = threadIdx.x, tx = t & 15, ty = t >> 4;
  int m = blockIdx.x;
  stage64(As, ltri + (size_t)((2*m+1)*64)*MM + (2*m)*64, MM, t);
  stage64(Bs, linv + (size_t)((2*m)*64)*MM   + (2*m)*64, MM, t);
  __syncthreads();
  float acc[4][4]={};
  tile_gemm_step(acc, As, Bs, tx, ty);
  __syncthreads();
  #pragma unroll
  for (int u=0;u<4;++u)
    #pragma unroll
    for (int v=0;v<4;++v) Bs[ty*4+u][tx*4+v] = acc[u][v];
  stage64(As, linv + (size_t)((2*m+1)*64)*MM + (2*m+1)*64, MM, t);
  __syncthreads();
  float o[4][4]={};
  tile_gemm_step(o, As, Bs, tx, ty);
  #pragma unroll
  for (int u=0;u<4;++u)
    *(float4*)&linv[(size_t)((2*m+1)*64+ty*4+u)*MM + (2*m)*64 + tx*4] =
        make_float4(-o[u][0],-o[u][1],-o[u][2],-o[u][3]);
}

// phase 3 level 1 (fused per-m); grid = 8
__global__ __launch_bounds__(256) void p3l1_kernel(
    const float* __restrict__ ltri, float* __restrict__ linv, float* __restrict__ ptmp){
  __shared__ float As[64][68];
  __shared__ float Bs[64][68];
  const int t = threadIdx.x, tx = t & 15, ty = t >> 4;
  int m = blockIdx.x;
  float* pm = ptmp + (size_t)m*128*128;
  for (int ti=0; ti<2; ++ti)
    for (int tj=0; tj<2; ++tj){
      int rb = m*4 + 2 + ti, cb0 = m*4;
      float acc[4][4]={};
      for (int k=tj; k<2; ++k){
        __syncthreads();
        stage64(As, ltri + (size_t)(rb*64)*MM + (cb0+k)*64, MM, t);
        stage64(Bs, linv + (size_t)((cb0+k)*64)*MM + (cb0+tj)*64, MM, t);
        __syncthreads();
        tile_gemm_step(acc, As, Bs, tx, ty);
      }
      #pragma unroll
      for (int u=0;u<4;++u)
        *(float4*)&pm[(size_t)(ti*64+ty*4+u)*128 + tj*64 + tx*4] =
            make_float4(acc[u][0],acc[u][1],acc[u][2],acc[u][3]);
    }
  for (int ti=0; ti<2; ++ti)
    for (int tj=0; tj<2; ++tj){
      int rb = m*4 + 2 + ti;
      float acc[4][4]={};
      for (int k=0; k<=ti; ++k){
        __syncthreads();
        stage64(As, linv + (size_t)(rb*64)*MM + (m*4+2+k)*64, MM, t);
        stage64(Bs, pm + (size_t)(k*64)*128 + tj*64, 128, t);
        __syncthreads();
        tile_gemm_step(acc, As, Bs, tx, ty);
      }
      #pragma unroll
      for (int u=0;u<4;++u)
        *(float4*)&linv[(size_t)(rb*64+ty*4+u)*MM + (m*4+tj)*64 + tx*4] =
            make_float4(-acc[u][0],-acc[u][1],-acc[u][2],-acc[u][3]);
    }
}

// phase 3 levels 2..4 part A (P = A21 @ Linv_lower); grid = mc*nb*nb
__global__ __launch_bounds__(256) void p3lA_kernel(
    const float* __restrict__ ltri, const float* __restrict__ linv,
    float* __restrict__ ptmp, int s){
  __shared__ float As[64][68];
  __shared__ float Bs[64][68];
  const int t = threadIdx.x, tx = t & 15, ty = t >> 4;
  int nb = 1<<s, b = 64<<s;
  float* pmb = ptmp + (s==2 ? 131072 : (s==3 ? 393216 : 917504));
  int idx = blockIdx.x;
  int m = idx/(nb*nb), r2 = idx%(nb*nb);
  int ti = r2/nb, tj = r2%nb;
  int rb = m*2*nb + nb + ti, cb0 = m*2*nb;
  float acc[4][4]={};
  for (int k=tj; k<nb; ++k){
    __syncthreads();
    stage64(As, ltri + (size_t)(rb*64)*MM + (cb0+k)*64, MM, t);
    stage64(Bs, linv + (size_t)((cb0+k)*64)*MM + (cb0+tj)*64, MM, t);
    __syncthreads();
    tile_gemm_step(acc, As, Bs, tx, ty);
  }
  float* pm = pmb + (size_t)m*b*b;
  #pragma unroll
  for (int u=0;u<4;++u)
    *(float4*)&pm[(size_t)(ti*64+ty*4+u)*b + tj*64 + tx*4] =
        make_float4(acc[u][0],acc[u][1],acc[u][2],acc[u][3]);
}

// phase 3 levels 2..4 part B (Linv21 = -Linv_lower @ P); grid = mc*nb*nb
__global__ __launch_bounds__(256) void p3lB_kernel(
    float* __restrict__ linv, const float* __restrict__ ptmp, int s){
  __shared__ float As[64][68];
  __shared__ float Bs[64][68];
  const int t = threadIdx.x, tx = t & 15, ty = t >> 4;
  int nb = 1<<s, b = 64<<s;
  const float* pmb = ptmp + (s==2 ? 131072 : (s==3 ? 393216 : 917504));
  int idx = blockIdx.x;
  int m = idx/(nb*nb), r2 = idx%(nb*nb);
  int ti = r2/nb, tj = r2%nb;
  int rb = m*2*nb + nb + ti;
  const float* pm = pmb + (size_t)m*b*b;
  float acc[4][4]={};
  for (int k=0; k<=ti; ++k){
    __syncthreads();
    stage64(As, linv + (size_t)(rb*64)*MM + (m*2*nb+nb+k)*64, MM, t);
    stage64(Bs, pm + (size_t)(k*64)*b + tj*64, b, t);
    __syncthreads();
    tile_gemm_step(acc, As, Bs, tx, ty);
  }
  #pragma unroll
  for (int u=0;u<4;++u)
    *(float4*)&linv[(size_t)(rb*64+ty*4+u)*MM + (m*2*nb+tj)*64 + tx*4] =
        make_float4(-acc[u][0],-acc[u][1],-acc[u][2],-acc[u][3]);
}

// phase 4a: W = Linv @ tril(qL), both GPs; grid = 2*528
__global__ __launch_bounds__(256) void w_kernel(
    const float* __restrict__ linv, const float* __restrict__ qlf,
    const float* __restrict__ qlg, float* __restrict__ wf, float* __restrict__ wg){
  __shared__ float As[64][68];
  __shared__ float Bs[64][68];
  const int t = threadIdx.x, tx = t & 15, ty = t >> 4;
  int idx = blockIdx.x;
  int gp = idx/528, rem = idx%528;
  int bi=0; while ((bi+1)*(bi+2)/2 <= rem) ++bi;
  int bj = rem - bi*(bi+1)/2;
  const float* ql = gp ? qlg : qlf;
  float* w        = gp ? wg  : wf;
  float acc[4][4]={};
  for (int bk=bj; bk<=bi; ++bk){
    __syncthreads();
    stage64(As, linv + (size_t)(bi*64)*MM + bk*64, MM, t);
    stage64(Bs, ql   + (size_t)(bk*64)*MM + bj*64, MM, t);
    __syncthreads();
    if (bk==bj){
      for (int p=t;p<4096;p+=256){ int i=p>>6, c=p&63; if (i<c) Bs[i][c]=0.f; }
      __syncthreads();
    }
    tile_gemm_step(acc, As, Bs, tx, ty);
  }
  #pragma unroll
  for (int u=0;u<4;++u)
    *(float4*)&w[(size_t)(bi*64+ty*4+u)*MM + bj*64 + tx*4] =
        make_float4(acc[u][0],acc[u][1],acc[u][2],acc[u][3]);
}

// phase 4b: alpha = Linv @ qm, both GPs; grid = 256
__global__ __launch_bounds__(256) void alpha_kernel(
    const float* __restrict__ linv, const float* __restrict__ qmf,
    const float* __restrict__ qmg, float* __restrict__ af, float* __restrict__ ag){
  int t = threadIdx.x;
  int gw = blockIdx.x*4 + (t>>6), l = t&63;
  for (int job=gw; job<4096; job+=1024){
    int gp = job>>11, r = job&2047;
    const float* qm = gp ? qmg : qmf;
    float s=0.f;
    for (int c=l; c<=r; c+=64) s += linv[(size_t)r*MM+c]*qm[c];
    #pragma unroll
    for (int off=32; off; off>>=1) s += __shfl_down(s, off, 64);
    if (l==0) (gp ? ag : af)[r] = s;
  }
}

// ================= small kernels (pre/post) =================

__global__ __launch_bounds__(256) void zfrag_kernel(const float* __restrict__ z,
    short* __restrict__ zfh, short* __restrict__ zfl, float* __restrict__ zn2){
  int zr = blockIdx.x*256 + threadIdx.x;
  float v[DD]; float s = 0.f;
  #pragma unroll
  for (int d=0; d<DD; ++d){ v[d] = z[zr*DD + d]; s += v[d]*v[d]; }
  zn2[zr] = s;
  size_t base = (size_t)(zr >> 4)*512 + (zr & 15)*32;
  #pragma unroll
  for (int k=0; k<32; ++k){
    short h = 0, lo = 0;
    if (k < DD) bfsplit(v[k], h, lo);
    zfh[base + k] = h; zfl[base + k] = lo;
  }
}

__global__ __launch_bounds__(256) void red_small(const float* __restrict__ lkd,
    const float* __restrict__ qlf, const float* __restrict__ qlg,
    const float* __restrict__ af, const float* __restrict__ ag,
    float* __restrict__ scal){
  __shared__ float scratch[4];
  float ldk=0, ldf=0, ldg=0, a2f=0, a2g=0;
  for (int i=threadIdx.x;i<MM;i+=256){
    int kb = i>>6, r = i&63;
    ldk += __logf(lkd[kb*4096 + r*64 + r]);
    ldf += __logf(fabsf(qlf[(size_t)i*MM+i]));
    ldg += __logf(fabsf(qlg[(size_t)i*MM+i]));
    float v = af[i]; a2f += v*v;
    v = ag[i];       a2g += v*v;
  }
  float r;
  r = block_reduce(ldk, scratch); if (threadIdx.x==0) scal[0] = 2.f*r;
  r = block_reduce(ldf, scratch); if (threadIdx.x==0) scal[1] = 2.f*r;
  r = block_reduce(ldg, scratch); if (threadIdx.x==0) scal[2] = 2.f*r;
  r = block_reduce(a2f, scratch); if (threadIdx.x==0) scal[3] = r;
  r = block_reduce(a2g, scratch); if (threadIdx.x==0) scal[4] = r;
}

__global__ __launch_bounds__(256) void redw_kernel(const float* __restrict__ wf,
    const float* __restrict__ wg, float* __restrict__ scal){
  __shared__ float scratch[4];
  size_t start  = (size_t)blockIdx.x*256 + threadIdx.x;
  size_t stride = (size_t)gridDim.x*256;
  float sf=0, sg=0;
  for (size_t p=start;p<(size_t)MM*MM;p+=stride){
    float v=wf[p]; sf += v*v;
    v=wg[p];       sg += v*v;
  }
  float r = block_reduce(sf, scratch);
  if (threadIdx.x==0) atomicAdd(&scal[5], r);
  r = block_reduce(sg, scratch);
  if (threadIdx.x==0) atomicAdd(&scal[6], r);
}

__global__ void kl_kernel(const float* __restrict__ scal, float* __restrict__ out){
  float klf = 0.5f*(scal[5] + scal[3] - (float)MM + scal[0] - scal[1]);
  float klg = 0.5f*(scal[6] + scal[4] - (float)MM + scal[0] - scal[2]);
  out[0] += klf + klg;
}

// merged splits: blocks [0,16384) rowmajor(linv); [16384,24576) transpose wf/wg
__global__ __launch_bounds__(256) void split_all(
    const float* __restrict__ linv, const float* __restrict__ wf,
    const float* __restrict__ wg, short* __restrict__ lvh, short* __restrict__ lvl,
    short* __restrict__ wfh, short* __restrict__ wfl,
    short* __restrict__ wgh, short* __restrict__ wgl){
  __shared__ float tile[32][33];
  const int t = threadIdx.x;
  const int bid = blockIdx.x;
  if (bid < 16384){
    int p = bid*256 + t;
    int chunk = p >> 9, wi = p & 511;
    int mo = chunk >> 6, ko = chunk & 63;
    int row = mo*16 + (wi >> 5), col = ko*32 + (wi & 31);
    float v = linv[(size_t)row*MM + col];
    short h, lo; bfsplit(v, h, lo);
    lvh[p] = h; lvl[p] = lo;
    return;
  }
  int idx2 = bid - 16384;
  int zz = idx2 >> 12;
  int rem = idx2 & 4095;
  int mb = rem & 63, kb = rem >> 6;
  const float* src = zz ? wg : wf;
  short* dh = zz ? wgh : wfh;
  short* dl = zz ? wgl : wfl;
  #pragma unroll
  for (int k=0;k<4;++k){
    int idx = t + k*256;
    int lr = idx >> 5, lc = idx & 31;
    tile[lr][lc] = src[(size_t)(kb*32+lr)*MM + mb*32 + lc];
  }
  __syncthreads();
  #pragma unroll
  for (int e=0;e<4;++e){
    int p = t*4 + e;
    int c = p >> 9, wi = p & 511;
    int i = (wi >> 5) & 15, kk = wi & 31;
    float v = tile[kk][c*16 + i];
    short h, lo; bfsplit(v, h, lo);
    size_t gp = ((size_t)(mb*2 + c)*64 + kb)*512 + wi;
    dh[gp] = h; dl[gp] = lo;
  }
}

__global__ __launch_bounds__(256, 2) void tt_mfma(
    const float* __restrict__ x, const float* __restrict__ zn2,
    const short* __restrict__ zfh, const short* __restrict__ zfl,
    const short* __restrict__ lvh, const short* __restrict__ lvl,
    short* __restrict__ tth, short* __restrict__ ttl){
  __shared__ __align__(16) short lAh[8192], lAl[8192], lBh[8192], lBl[8192];
  int t = threadIdx.x;
  int l = t & 63, w = t >> 6;
  int istrip = blockIdx.x, bj2 = blockIdx.y;
  int li = l & 15, q = l >> 4;
  int lofs = li*32 + q*8;                              // global z layout (unswizzled)
  int lofs_s = li*32 + ((q ^ ((li>>1)&3)))*8;          // swizzled LDS reads
  int wn4 = (w>>1)*4, wm4 = (w&1)*4;

  short8 xh[2], xl[2];
  float xn2v[8];
  {
    float xn2t[2];
    #pragma unroll
    for (int tn=0; tn<2; ++tn){
      int n = istrip*128 + w*32 + tn*16 + li;
      const float4* xp = (const float4*)(x + (size_t)n*DD);
      float4 p0 = xp[0], p1 = xp[1];
      float v[8] = {p0.x,p0.y,p0.z,p0.w,p1.x,p1.y,p1.z,p1.w};
      float s = 0.f;
      #pragma unroll
      for (int d=0; d<8; ++d) s += v[d]*v[d];
      xn2t[tn] = s;
      short8 hh, ll;
      #pragma unroll
      for (int j=0; j<8; ++j){
        short h=0, lo=0;
        if (q==0) bfsplit(v[j], h, lo);
        hh[j]=h; ll[j]=lo;
      }
      xh[tn]=hh; xl[tn]=ll;
    }
    #pragma unroll
    for (int tn=0; tn<2; ++tn)
      #pragma unroll
      for (int r=0; r<4; ++r)
        xn2v[tn*4+r] = __shfl(xn2t[tn], q*4 + r, 64);
  }

  float4v acc[4][4];
  #pragma unroll
  for (int i=0;i<4;++i)
    #pragma unroll
    for (int j=0;j<4;++j) acc[i][j] = f4zero();

  int nkt = 2*bj2 + 2;
  for (int bk=0; bk<nkt; ++bk){
    __syncthreads();
    {
      short8 zh[4], zl[4];
      float zt2[4];
      #pragma unroll
      for (int tz=0; tz<4; ++tz){
        size_t zo = (size_t)(bk*4 + tz)*512 + lofs;
        zh[tz] = *(const short8*)(zfh + zo);
        zl[tz] = *(const short8*)(zfl + zo);
        zt2[tz] = zn2[bk*64 + tz*16 + li];
      }
      #pragma unroll
      for (int tn=0; tn<2; ++tn){
        #pragma unroll
        for (int tz=0; tz<4; ++tz){
          float4v s4 = mfma3(xh[tn], xl[tn], zh[tz], zl[tz], f4zero());
          #pragma unroll
          for (int r=0; r<4; ++r){
            float e = __expf(4.f*s4[r] - 2.f*(xn2v[tn*4+r] + zt2[tz]));
            short h, lo; bfsplit(e, h, lo);
            // swizzled scalar store: rowc=q*4+r, slot=(tz&1)*2+(li>>3)
            int rowc = q*4 + r;
            int slot2 = (((tz&1)*2 + (li>>3)) ^ ((rowc>>1)&3));
            int pos = ((w*2+tn)*2 + (tz>>1))*512 + rowc*32 + slot2*8 + (li&7);
            lAh[pos] = h; lAl[pos] = lo;
          }
        }
      }
    }
    #pragma unroll
    for (int c4 = t; c4 < 1024; c4 += 256){
      int ch = c4 >> 6, wdi = c4 & 63;
      int wsw = (wdi & 60) | ((wdi ^ (wdi >> 3)) & 3);
      int dst = ch*64 + wsw;
      size_t g = ((size_t)(bj2*8 + (ch>>1))*64 + (size_t)(bk*2 + (ch&1)))*64 + wdi;
      ((uint4*)lBh)[dst] = ((const uint4*)lvh)[g];
      ((uint4*)lBl)[dst] = ((const uint4*)lvl)[g];
    }
    __syncthreads();
    #pragma unroll
    for (int s=0; s<2; ++s){
      short8 ah[4], al[4], bh[4], bl[4];
      #pragma unroll
      for (int tn=0; tn<4; ++tn){
        int off = ((wn4+tn)*2 + s)*512 + lofs_s;
        ah[tn] = *(const short8*)&lAh[off];
        al[tn] = *(const short8*)&lAl[off];
      }
      #pragma unroll
      for (int tm=0; tm<4; ++tm){
        int off = ((wm4+tm)*2 + s)*512 + lofs_s;
        bh[tm] = *(const short8*)&lBh[off];
        bl[tm] = *(const short8*)&lBl[off];
      }
      #pragma unroll
      for (int tn=0; tn<4; ++tn)
        #pragma unroll
        for (int tm=0; tm<4; ++tm)
          acc[tn][tm] = mfma3(ah[tn], al[tn], bh[tm], bl[tm], acc[tn][tm]);
    }
  }
  #pragma unroll
  for (int tn=0; tn<4; ++tn){
    int no_g = istrip*8 + wn4 + tn;
    #pragma unroll
    for (int tm=0; tm<4; ++tm){
      int mo_g = bj2*4 + (w&1)*2 + (tm>>1);
      size_t cb = ((size_t)no_g*64 + mo_g)*512;
      #pragma unroll
      for (int r=0; r<4; ++r){
        short h, lo; bfsplit(acc[tn][tm][r], h, lo);
        size_t pos = cb + (q*4+r)*32 + (tm&1)*16 + li;
        tth[pos] = h; ttl[pos] = lo;
      }
    }
  }
}

__global__ __launch_bounds__(256) void lin_v2(const short* __restrict__ tth,
    const short* __restrict__ ttl, const float* __restrict__ af, const float* __restrict__ ag,
    float* __restrict__ t2, float* __restrict__ lf, float* __restrict__ lg){
  int t = threadIdx.x;
  int w = t >> 6, l = t & 63;
  int n = blockIdx.x*4 + w;
  int g = l >> 2, j = l & 3;
  float s2=0.f, sf=0.f, sg=0.f;
  #pragma unroll
  for (int it=0; it<4; ++it){
    int ck = g + it*16;
    size_t off = ((size_t)(n>>4)*64 + ck)*512 + (n&15)*32 + j*8;
    short8 h8 = *(const short8*)(tth + off);
    short8 l8 = *(const short8*)(ttl + off);
    int m0 = ck*32 + j*8;
    float4 a0 = *(const float4*)(af + m0), a1 = *(const float4*)(af + m0 + 4);
    float4 g0 = *(const float4*)(ag + m0), g1 = *(const float4*)(ag + m0 + 4);
    float av[8] = {a0.x,a0.y,a0.z,a0.w,a1.x,a1.y,a1.z,a1.w};
    float gv[8] = {g0.x,g0.y,g0.z,g0.w,g1.x,g1.y,g1.z,g1.w};
    #pragma unroll
    for (int e=0; e<8; ++e){
      float tv = bf2f(h8[e]) + bf2f(l8[e]);
      s2 += tv*tv; sf += tv*av[e]; sg += tv*gv[e];
    }
  }
  #pragma unroll
  for (int off=32; off; off>>=1){
    s2 += __shfl_down(s2, off, 64);
    sf += __shfl_down(sf, off, 64);
    sg += __shfl_down(sg, off, 64);
  }
  if (l==0){ t2[n] = s2; lf[n] = sf; lg[n] = sg; }
}

__global__ __launch_bounds__(256, 2) void quad_mfma(
    const short* __restrict__ tth, const short* __restrict__ ttl,
    const short* __restrict__ wfh, const short* __restrict__ wfl,
    const short* __restrict__ wgh, const short* __restrict__ wgl,
    float* __restrict__ vfq, float* __restrict__ vgq){
  __shared__ __align__(16) short lAh[8192], lAl[8192], lBh[8192], lBl[8192];
  int t = threadIdx.x, l = t & 63, w = t >> 6;
  int istrip = blockIdx.x, bj2 = blockIdx.y;
  const short* gbh = blockIdx.z ? wgh : wfh;
  const short* gbl = blockIdx.z ? wgl : wfl;
  float* vq = blockIdx.z ? vgq : vfq;
  int li = l & 15, q = l >> 4;
  int lofs_s = li*32 + ((q ^ ((li>>1)&3)))*8;          // swizzled LDS reads
  int wn4 = (w>>1)*4, wm4 = (w&1)*4;

  float4v acc[4][4];
  #pragma unroll
  for (int i=0;i<4;++i)
    #pragma unroll
    for (int j=0;j<4;++j) acc[i][j] = f4zero();

  for (int bk=2*bj2; bk<32; ++bk){
    __syncthreads();
    #pragma unroll
    for (int c4 = t; c4 < 1024; c4 += 256){
      int ch = c4 >> 6, wdi = c4 & 63;
      int wsw = (wdi & 60) | ((wdi ^ (wdi >> 3)) & 3);
      int dst = ch*64 + wsw;
      size_t ga = ((size_t)(istrip*8 + (ch>>1))*64 + (size_t)(bk*2 + (ch&1)))*64 + wdi;
      ((uint4*)lAh)[dst] = ((const uint4*)tth)[ga];
      ((uint4*)lAl)[dst] = ((const uint4*)ttl)[ga];
      size_t gb = ((size_t)(bj2*8 + (ch>>1))*64 + (size_t)(bk*2 + (ch&1)))*64 + wdi;
      ((uint4*)lBh)[dst] = ((const uint4*)gbh)[gb];
      ((uint4*)lBl)[dst] = ((const uint4*)gbl)[gb];
    }
    __syncthreads();
    #pragma unroll
    for (int s=0; s<2; ++s){
      short8 ah[4], al[4], bh[4], bl[4];
      #pragma unroll
      for (int tn=0; tn<4; ++tn){
        int off = ((wn4+tn)*2 + s)*512 + lofs_s;
        ah[tn] = *(const short8*)&lAh[off];
        al[tn] = *(const short8*)&lAl[off];
      }
      #pragma unroll
      for (int tm=0; tm<4; ++tm){
        int off = ((wm4+tm)*2 + s)*512 + lofs_s;
        bh[tm] = *(const short8*)&lBh[off];
        bl[tm] = *(const short8*)&lBl[off];
      }
      #pragma unroll
      for (int tn=0; tn<4; ++tn)
        #pragma unroll
        for (int tm=0; tm<4; ++tm)
          acc[tn][tm] = mfma3(ah[tn], al[tn], bh[tm], bl[tm], acc[tn][tm]);
    }
  }
  float rs[16];
  #pragma unroll
  for (int tn=0; tn<4; ++tn)
    #pragma unroll
    for (int r=0; r<4; ++r){
      float s = 0.f;
      #pragma unroll
      for (int tm=0; tm<4; ++tm){ float v = acc[tn][tm][r]; s += v*v; }
      rs[tn*4+r] = s;
    }
  #pragma unroll
  for (int off=8; off; off>>=1)
    #pragma unroll
    for (int k=0; k<16; ++k) rs[k] += __shfl_down(rs[k], off, 16);
  if (li == 0){
    #pragma unroll
    for (int tn=0; tn<4; ++tn)
      #pragma unroll
      for (int r=0; r<4; ++r){
        int n = istrip*128 + (w>>1)*64 + tn*16 + q*4 + r;
        atomicAdd(&vq[n], rs[tn*4+r]);
      }
  }
}

__global__ __launch_bounds__(256) void final_kernel(const float* __restrict__ y,
    const float* __restrict__ t2, const float* __restrict__ lf, const float* __restrict__ lg,
    const float* __restrict__ vfq, const float* __restrict__ vgq, float* __restrict__ out){
  __shared__ float scratch[4];
  int i = blockIdx.x*256 + threadIdx.x;
  float mf = lf[i], mg = lg[i];
  float vf = 1.f + vfq[i] - t2[i];
  float vg = 1.f + vgq[i] - t2[i];
  float dy = y[i] - mf;
  float e = -HLOG2PI - 0.5f*mg - 0.5f*(dy*dy + vf)*__expf(-mg + 0.5f*vg);
  float r = block_reduce(e, scratch);
  if (threadIdx.x==0) atomicAdd(out, -r);
}

extern "C" void kernel_launch(void* const* d_in, const int* in_sizes, int n_in,
                              void* d_out, int out_size, void* d_ws, size_t ws_size,
                              hipStream_t stream){
  (void)in_sizes; (void)n_in; (void)out_size; (void)ws_size;
  const float* x   = (const float*)d_in[0];
  const float* y   = (const float*)d_in[1];
  const float* z   = (const float*)d_in[2];
  const float* qmf = (const float*)d_in[3];
  const float* qlf = (const float*)d_in[4];
  const float* qmg = (const float*)d_in[5];
  const float* qlg = (const float*)d_in[6];
  float* out = (float*)d_out;
  char* Bw = (char*)d_ws;

  float* kuu  = (float*)Bw;
  float* linv = (float*)(Bw + SZB);
  float* wf   = (float*)(Bw + 2*SZB);
  float* wg   = (float*)(Bw + 3*SZB);
  short* lvh  = (short*)Bw;
  short* lvl  = (short*)(Bw + SZB/2);
  short* wfh  = (short*)(Bw + SZB);
  short* wfl  = (short*)(Bw + SZB + SZB/2);
  short* wgh  = (short*)(Bw + 2*SZB);
  short* wgl  = (short*)(Bw + 2*SZB + SZB/2);
  short* tth  = (short*)(Bw + 3*SZB);
  short* ttl  = (short*)(Bw + 3*SZB + (size_t)NN*MM*2);
  // dead-tt region [64M,112M): ltri 16MB, ptmp 8MB (per-level disjoint),
  // lkdiag 512KB, sdg 8KB
  float* ltri   = (float*)(Bw + 4*SZB);
  float* ptmp   = (float*)(Bw + 5*SZB);
  float* lkdiag = (float*)(Bw + 5*SZB + (size_t)8388608);
  float* sdg    = (float*)(Bw + 5*SZB + (size_t)8388608 + (size_t)524288);
  float* sm   = (float*)(Bw + 3*SZB + (size_t)NN*MM*4);
  float* af = sm;          float* ag = af + MM;
  float* t2 = ag + MM;     float* lf = t2 + NN;   float* lg = lf + NN;
  float* vfq = lg + NN;    float* vgq = vfq + NN; float* scal = vgq + NN;
  float* zn2 = scal + 64 + 2048;
  short* zfh = (short*)(zn2 + MM);
  short* zfl = zfh + MM*32;

  hipMemsetAsync(out, 0, sizeof(float), stream);
  hipMemsetAsync(vfq, 0, (size_t)(2*NN + 64 + 2048)*sizeof(float), stream); // vfq,vgq,scal
  hipMemsetAsync(wf,  0, 2*SZB, stream);    // W upper triangles must be 0
  hipMemsetAsync(linv,0, SZB,   stream);    // Linv upper must be 0

  zfrag_kernel<<<MM/256, 256, 0, stream>>>(z, zfh, zfl, zn2);

  // ---- factorization: multi-launch (v15 structure) ----
  phase0_kernel<<<528, 256, 0, stream>>>(z, kuu);
  diag0_kernel<<<1, 256, 0, stream>>>(kuu, lkdiag, sdg);
  for (int kb = 0; kb < 31; ++kb){
    int T = NB - 1 - kb;
    panel_kernel<<<T*(T+1)/2, 256, 0, stream>>>(kuu, lkdiag, sdg, ltri, kb);
  }
  phase2_kernel<<<NB, 256, 0, stream>>>(lkdiag, linv);
  p3l0_kernel<<<16, 256, 0, stream>>>(ltri, linv);
  p3l1_kernel<<<8, 256, 0, stream>>>(ltri, linv, ptmp);
  for (int s = 2; s < 5; ++s){
    int nb = 1<<s, mc = 16>>s;
    p3lA_kernel<<<mc*nb*nb, 256, 0, stream>>>(ltri, linv, ptmp, s);
    p3lB_kernel<<<mc*nb*nb, 256, 0, stream>>>(linv, ptmp, s);
  }
  w_kernel<<<2*528, 256, 0, stream>>>(linv, qlf, qlg, wf, wg);
  alpha_kernel<<<256, 256, 0, stream>>>(linv, qmf, qmg, af, ag);

  red_small<<<1, 256, 0, stream>>>(lkdiag, qlf, qlg, af, ag, scal);
  redw_kernel<<<512, 256, 0, stream>>>(wf, wg, scal);
  kl_kernel<<<1, 1, 0, stream>>>(scal, out);

  split_all<<<24576, 256, 0, stream>>>(linv, wf, wg, lvh, lvl, wfh, wfl, wgh, wgl);

  tt_mfma<<<dim3(NN/128, MM/128), 256, 0, stream>>>(x, zn2, zfh, zfl, lvh, lvl, tth, ttl);
  lin_v2<<<NN/4, 256, 0, stream>>>(tth, ttl, af, ag, t2, lf, lg);
  quad_mfma<<<dim3(NN/128, MM/128, 2), 256, 0, stream>>>(tth, ttl, wfh, wfl, wgh, wgl, vfq, vgq);
  final_kernel<<<NN/256, 256, 0, stream>>>(y, t2, lf, lg, vfq, vgq, out);
}

// Round 13
// 3852.705 us; speedup vs baseline: 1.2727x; 1.0057x over previous
//
#include <hip/hip_runtime.h>
#include <math.h>

// ChainedGP v20: v19 (best@3875: v15 multi-launch structure + split_all +
// LDS swizzle in tt/quad, conflicts 3.6e7->0) + THREE zero-pole merges of
// INDEPENDENT-work kernels (v18 lesson: fusion fails only when it adds
// serial content; these add none):
//  (1) zfrag into phase0 (grid 536; no factor64 -> no reg-pressure bump)
//  (2) red_small+redw -> reduce_kernel (grid 513; disjoint scal slots)
//  (3) w+alpha -> walpha_kernel (grid 1312; both read only linv)
// Bodies byte-identical -> identical rounding -> absmax unchanged.
// Calibration: boundary ~45-50us; panel tile latency ~24us.
#define NN 16384
#define MM 2048
#define DD 8
#define NB 32                     // MM/64
#define SZB ((size_t)16777216)    // 2048*2048*4 bytes

constexpr float HLOG2PI = 0.91893853320467274178f;

using short8  = __attribute__((ext_vector_type(8))) short;
using float4v = __attribute__((ext_vector_type(4))) float;

__device__ __forceinline__ float4v f4zero(){ float4v v; v[0]=0.f; v[1]=0.f; v[2]=0.f; v[3]=0.f; return v; }

__device__ __forceinline__ void bfsplit(float v, short& h, short& lo){
  unsigned b = __float_as_uint(v);
  h = (short)(b >> 16);
  float hf = __uint_as_float(b & 0xFFFF0000u);
  lo = (short)(__float_as_uint(v - hf) >> 16);
}
__device__ __forceinline__ float bf2f(short s){
  return __uint_as_float(((unsigned)(unsigned short)s) << 16);
}
__device__ __forceinline__ float4v mfma3(short8 ah, short8 al, short8 bh, short8 bl, float4v c){
  c = __builtin_amdgcn_mfma_f32_16x16x32_bf16(ah, bh, c, 0, 0, 0);
  c = __builtin_amdgcn_mfma_f32_16x16x32_bf16(ah, bl, c, 0, 0, 0);
  c = __builtin_amdgcn_mfma_f32_16x16x32_bf16(al, bh, c, 0, 0, 0);
  return c;
}

__device__ __forceinline__ float block_reduce(float v, float* scratch){
  int lane = threadIdx.x & 63;
  int w    = threadIdx.x >> 6;
  #pragma unroll
  for (int off=32; off; off>>=1) v += __shfl_down(v, off, 64);
  __syncthreads();
  if (lane==0) scratch[w] = v;
  __syncthreads();
  float r = 0.f;
  if (threadIdx.x < 4) r = scratch[threadIdx.x];
  if (w==0){ r += __shfl_down(r, 2, 64); r += __shfl_down(r, 1, 64); }
  return r;
}

// ---- 64x64 tile helpers (LDS row stride 68 floats) ----
__device__ __forceinline__ void stage64(float (*S)[68], const float* __restrict__ g, int ld, int t){
  #pragma unroll
  for (int p=t; p<1024; p+=256)
    *(float4*)&S[p>>4][(p&15)*4] = *(const float4*)&g[(size_t)(p>>4)*ld + (p&15)*4];
}
__device__ __forceinline__ void tile_gemm_step(float acc[4][4], const float (*As)[68], const float (*Bs)[68], int tx, int ty){
  for (int k=0;k<64;++k){
    float ar[4], bc4[4];
    #pragma unroll
    for (int u=0;u<4;++u){ ar[u]=As[ty*4+u][k]; bc4[u]=Bs[k][tx*4+u]; }
    #pragma unroll
    for (int u=0;u<4;++u)
      #pragma unroll
      for (int v=0;v<4;++v) acc[u][v] += ar[u]*bc4[v];
  }
}
__device__ __forceinline__ void tile_syrk_step(float acc[4][4], const float (*P)[68], const float (*Q)[68], int tx, int ty){
  for (int k=0;k<64;++k){
    float pr[4], qc[4];
    #pragma unroll
    for (int u=0;u<4;++u){ pr[u]=P[ty*4+u][k]; qc[u]=Q[tx*4+u][k]; }
    #pragma unroll
    for (int u=0;u<4;++u)
      #pragma unroll
      for (int v=0;v<4;++v) acc[u][v] += pr[u]*qc[v];
  }
}

// wave-0 register Cholesky of a 64x64 tile staged in S (LDS); no __syncthreads.
__device__ __forceinline__ void factor64_reg(const float (*S)[68],
    float* __restrict__ lkd, float* __restrict__ sdg_, int d, int t){
  if (t < 64){
    float xr[64];
    #pragma unroll
    for (int c4=0;c4<16;++c4) *(float4*)&xr[c4*4] = *(const float4*)&S[t][c4*4];
    float myrp = 1.f;
    #pragma unroll
    for (int j=0;j<64;++j){
      float ajj = __shfl(xr[j], j, 64);
      float piv = sqrtf(fmaxf(ajj, 1e-20f));
      float rp  = 1.f/piv;
      float val = xr[j]*rp;
      if (t==j){ xr[j] = piv; myrp = rp; }
      else if (t>j) xr[j] = val;
      else val = 0.f;
      #pragma unroll
      for (int c=j+1;c<64;++c){
        float vc = __shfl(val, c, 64);
        if (c<=t) xr[c] -= val*vc;
      }
    }
    #pragma unroll
    for (int c=0;c<64;++c) if (c>t) xr[c] = 0.f;
    #pragma unroll
    for (int c4=0;c4<16;++c4)
      *(float4*)&lkd[d*4096 + t*64 + c4*4] = *(float4*)&xr[c4*4];
    sdg_[d*64 + t] = myrp;
  }
}

// ================= factorization kernels (multi-launch) =================

// phase 0: 528 Kuu tiles + (blocks 528..535) zfrag; grid = 536
__global__ __launch_bounds__(256) void phase0_kernel(
    const float* __restrict__ z, float* __restrict__ kuu,
    short* __restrict__ zfh, short* __restrict__ zfl, float* __restrict__ zn2){
  __shared__ float As[64][68];
  __shared__ float Bs[64][68];
  const int t = threadIdx.x, tx = t & 15, ty = t >> 4;
  const int bid = blockIdx.x;
  if (bid >= 528){
    int zr = (bid-528)*256 + t;
    float v[DD]; float s = 0.f;
    #pragma unroll
    for (int d=0; d<DD; ++d){ v[d] = z[zr*DD + d]; s += v[d]*v[d]; }
    zn2[zr] = s;
    size_t base = (size_t)(zr >> 4)*512 + (zr & 15)*32;
    #pragma unroll
    for (int k=0; k<32; ++k){
      short h = 0, lo = 0;
      if (k < DD) bfsplit(v[k], h, lo);
      zfh[base + k] = h; zfl[base + k] = lo;
    }
    return;
  }
  int idx = bid;
  int r=0; while ((r+1)*(r+2)/2 <= idx) ++r;
  int c = idx - r*(r+1)/2;
  for (int p=t; p<128; p+=256){ int i=p>>1, h=p&1;
    *(float4*)&As[i][h*4] = *(const float4*)&z[(size_t)(r*64+i)*DD + h*4];
    *(float4*)&Bs[i][h*4] = *(const float4*)&z[(size_t)(c*64+i)*DD + h*4]; }
  __syncthreads();
  #pragma unroll
  for (int u=0;u<4;++u){
    float4 o;
    float* ov = (float*)&o;
    #pragma unroll
    for (int v=0;v<4;++v){
      float d2=0.f;
      #pragma unroll
      for (int d=0;d<8;++d){ float df=As[ty*4+u][d]-Bs[tx*4+v][d]; d2+=df*df; }
      float val = __expf(-2.f*d2);
      if (r*64+ty*4+u == c*64+tx*4+v) val += 1e-6f;
      ov[v] = val;
    }
    *(float4*)&kuu[(size_t)(r*64+ty*4+u)*MM + c*64 + tx*4] = o;
  }
}

// factor diag(0); grid = 1
__global__ __launch_bounds__(256) void diag0_kernel(
    const float* __restrict__ kuu, float* __restrict__ lkdiag, float* __restrict__ sdg){
  __shared__ float As[64][68];
  const int t = threadIdx.x;
  stage64(As, kuu, MM, t);
  __syncthreads();
  factor64_reg(As, lkdiag, sdg, 0, t);
}

// panel kb: fused TRSM+SYRK; grid = T(T+1)/2, T = 31-kb.
// tile 0 = (kb+1,kb+1): subtract in LDS + factor -> lkdiag[kb+1] (lookahead).
__global__ __launch_bounds__(256) void panel_kernel(
    float* __restrict__ kuu, float* __restrict__ lkdiag,
    float* __restrict__ sdg, float* __restrict__ ltri, int kb){
  __shared__ float As[64][68];
  __shared__ float Bs[64][68];
  __shared__ float Cs[64][68];
  __shared__ float sd[64];
  const int t = threadIdx.x, tx = t & 15, ty = t >> 4;
  int idx = blockIdx.x;
  int r=0; while ((r+1)*(r+2)/2 <= idx) ++r;
  int c = idx - r*(r+1)/2;
  int bi = kb+1+r, bc = kb+1+c;
  stage64(Cs, lkdiag + kb*4096, 64, t);
  if (t < 64) sd[t] = sdg[kb*64 + t];
  stage64(As, kuu + (size_t)(bi*64)*MM + kb*64, MM, t);
  if (bc != bi) stage64(Bs, kuu + (size_t)(bc*64)*MM + kb*64, MM, t);
  __syncthreads();
  {
    int w = t>>6, l = t&63;
    if (w==0 || (w==1 && bc!=bi)){
      float (*S)[68] = (w==0)? As : Bs;
      float xr[64];
      #pragma unroll
      for (int c4=0;c4<16;++c4) *(float4*)&xr[c4*4] = *(const float4*)&S[l][c4*4];
      #pragma unroll
      for (int j=0;j<64;++j){
        float xj = xr[j]*sd[j];
        xr[j] = xj;
        #pragma unroll
        for (int cc=j+1;cc<64;++cc) xr[cc] -= xj*Cs[cc][j];
      }
      #pragma unroll
      for (int c4=0;c4<16;++c4) *(float4*)&S[l][c4*4] = *(float4*)&xr[c4*4];
    }
  }
  __syncthreads();
  if (bc == kb+1){
    for (int p=t;p<1024;p+=256)
      *(float4*)&ltri[(size_t)(bi*64+(p>>4))*MM + kb*64 + (p&15)*4] =
          *(float4*)&As[p>>4][(p&15)*4];
  }
  float acc[4][4] = {};
  tile_syrk_step(acc, As, (bc==bi)? As : Bs, tx, ty);
  if (bi==kb+1 && bc==kb+1){
    __syncthreads();
    #pragma unroll
    for (int u=0;u<4;++u)
      #pragma unroll
      for (int v=0;v<4;++v) Bs[ty*4+u][tx*4+v] = acc[u][v];
    __syncthreads();
    for (int p=t;p<1024;p+=256){
      int i=p>>4, c4=p&15;
      float4 kv = *(const float4*)&kuu[(size_t)(bi*64+i)*MM + bi*64 + c4*4];
      float4 bv = *(float4*)&Bs[i][c4*4];
      float4 o; o.x=kv.x-bv.x; o.y=kv.y-bv.y; o.z=kv.z-bv.z; o.w=kv.w-bv.w;
      *(float4*)&As[i][c4*4] = o;
    }
    __syncthreads();
    factor64_reg(As, lkdiag, sdg, kb+1, t);
  } else {
    #pragma unroll
    for (int u=0;u<4;++u){
      float4* dst = (float4*)&kuu[(size_t)(bi*64+ty*4+u)*MM + bc*64 + tx*4];
      float4 o = *dst;
      o.x-=acc[u][0]; o.y-=acc[u][1]; o.z-=acc[u][2]; o.w-=acc[u][3];
      *dst = o;
    }
  }
}

// phase 2: invert 64x64 diagonal blocks; grid = 32
__global__ __launch_bounds__(256) void phase2_kernel(
    const float* __restrict__ lkdiag, float* __restrict__ linv){
  __shared__ float As[64][68];
  __shared__ float Bs[64][68];
  const int t = threadIdx.x, bid = blockIdx.x;
  stage64(As, lkdiag + bid*4096, 64, t);
  __syncthreads();
  if (t < 64){
    for (int j=0;j<64;++j){
      float s = (j==t)?1.f:0.f;
      for (int k=t;k<j;++k) s -= As[j][k]*Bs[k][t];
      Bs[j][t] = (j>=t)? s/As[j][j] : 0.f;
    }
  }
  __syncthreads();
  for (int p=t;p<1024;p+=256){ int i=p>>4, c4=p&15;
    *(float4*)&linv[(size_t)(bid*64+i)*MM + bid*64 + c4*4] = *(float4*)&Bs[i][c4*4]; }
}

// phase 3 level 0 (fused); grid = 16
__global__ __launch_bounds__(256) void p3l0_kernel(
    const float* __restrict__ ltri, float* __restrict__ linv){
  __shared__ float As[64][68];
  __shared__ float Bs[64][68];
  const int t = threadIdx.x, tx = t & 15, ty = t >> 4;
  int m = blockIdx.x;
  stage64(As, ltri + (size_t)((2*m+1)*64)*MM + (2*m)*64, MM, t);
  stage64(Bs, linv + (size_t)((2*m)*64)*MM   + (2*m)*64, MM, t);
  __syncthreads();
  float acc[4][4]={};
  tile_gemm_step(acc, As, Bs, tx, ty);
  __syncthreads();
  #pragma unroll
  for (int u=0;u<4;++u)
    #pragma unroll
    for (int v=0;v<4;++v) Bs[ty*4+u][tx*4+v] = acc[u][v];
  stage64(As, linv + (size_t)((2*m+1)*64)*MM + (2*m+1)*64, MM, t);
  __syncthreads();
  float o[4][4]={};
  tile_gemm_step(o, As, Bs, tx, ty);
  #pragma unroll
  for (int u=0;u<4;++u)
    *(float4*)&linv[(size_t)((2*m+1)*64+ty*4+u)*MM + (2*m)*64 + tx*4] =
        make_float4(-o[u][0],-o[u][1],-o[u][2],-o[u][3]);
}

// phase 3 level 1 (fused per-m); grid = 8
__global__ __launch_bounds__(256) void p3l1_kernel(
    const float* __restrict__ ltri, float* __restrict__ linv, float* __restrict__ ptmp){
  __shared__ float As[64][68];
  __shared__ float Bs[64][68];
  const int t = threadIdx.x, tx = t & 15, ty = t >> 4;
  int m = blockIdx.x;
  float* pm = ptmp + (size_t)m*128*128;
  for (int ti=0; ti<2; ++ti)
    for (int tj=0; tj<2; ++tj){
      int rb = m*4 + 2 + ti, cb0 = m*4;
      float acc[4][4]={};
      for (int k=tj; k<2; ++k){
        __syncthreads();
        stage64(As, ltri + (size_t)(rb*64)*MM + (cb0+k)*64, MM, t);
        stage64(Bs, linv + (size_t)((cb0+k)*64)*MM + (cb0+tj)*64, MM, t);
        __syncthreads();
        tile_gemm_step(acc, As, Bs, tx, ty);
      }
      #pragma unroll
      for (int u=0;u<4;++u)
        *(float4*)&pm[(size_t)(ti*64+ty*4+u)*128 + tj*64 + tx*4] =
            make_float4(acc[u][0],acc[u][1],acc[u][2],acc[u][3]);
    }
  for (int ti=0; ti<2; ++ti)
    for (int tj=0; tj<2; ++tj){
      int rb = m*4 + 2 + ti;
      float acc[4][4]={};
      for (int k=0; k<=ti; ++k){
        __syncthreads();
        stage64(As, linv + (size_t)(rb*64)*MM + (m*4+2+k)*64, MM, t);
        stage64(Bs, pm + (size_t)(k*64)*128 + tj*64, 128, t);
        __syncthreads();
        tile_gemm_step(acc, As, Bs, tx, ty);
      }
      #pragma unroll
      for (int u=0;u<4;++u)
        *(float4*)&linv[(size_t)(rb*64+ty*4+u)*MM + (m*4+tj)*64 + tx*4] =
            make_float4(-acc[u][0],-acc[u][1],-acc[u][2],-acc[u][3]);
    }
}

// phase 3 levels 2..4 part A (P = A21 @ Linv_lower); grid = mc*nb*nb
__global__ __launch_bounds__(256) void p3lA_kernel(
    const float* __restrict__ ltri, const float* __restrict__ linv,
    float* __restrict__ ptmp, int s){
  __shared__ float As[64][68];
  __shared__ float Bs[64][68];
  const int t = threadIdx.x, tx = t & 15, ty = t >> 4;
  int nb = 1<<s, b = 64<<s;
  float* pmb = ptmp + (s==2 ? 131072 : (s==3 ? 393216 : 917504));
  int idx = blockIdx.x;
  int m = idx/(nb*nb), r2 = idx%(nb*nb);
  int ti = r2/nb, tj = r2%nb;
  int rb = m*2*nb + nb + ti, cb0 = m*2*nb;
  float acc[4][4]={};
  for (int k=tj; k<nb; ++k){
    __syncthreads();
    stage64(As, ltri + (size_t)(rb*64)*MM + (cb0+k)*64, MM, t);
    stage64(Bs, linv + (size_t)((cb0+k)*64)*MM + (cb0+tj)*64, MM, t);
    __syncthreads();
    tile_gemm_step(acc, As, Bs, tx, ty);
  }
  float* pm = pmb + (size_t)m*b*b;
  #pragma unroll
  for (int u=0;u<4;++u)
    *(float4*)&pm[(size_t)(ti*64+ty*4+u)*b + tj*64 + tx*4] =
        make_float4(acc[u][0],acc[u][1],acc[u][2],acc[u][3]);
}

// phase 3 levels 2..4 part B (Linv21 = -Linv_lower @ P); grid = mc*nb*nb
__global__ __launch_bounds__(256) void p3lB_kernel(
    float* __restrict__ linv, const float* __restrict__ ptmp, int s){
  __shared__ float As[64][68];
  __shared__ float Bs[64][68];
  const int t = threadIdx.x, tx = t & 15, ty = t >> 4;
  int nb = 1<<s, b = 64<<s;
  const float* pmb = ptmp + (s==2 ? 131072 : (s==3 ? 393216 : 917504));
  int idx = blockIdx.x;
  int m = idx/(nb*nb), r2 = idx%(nb*nb);
  int ti = r2/nb, tj = r2%nb;
  int rb = m*2*nb + nb + ti;
  const float* pm = pmb + (size_t)m*b*b;
  float acc[4][4]={};
  for (int k=0; k<=ti; ++k){
    __syncthreads();
    stage64(As, linv + (size_t)(rb*64)*MM + (m*2*nb+nb+k)*64, MM, t);
    stage64(Bs, pm + (size_t)(k*64)*b + tj*64, b, t);
    __syncthreads();
    tile_gemm_step(acc, As, Bs, tx, ty);
  }
  #pragma unroll
  for (int u=0;u<4;++u)
    *(float4*)&linv[(size_t)(rb*64+ty*4+u)*MM + (m*2*nb+tj)*64 + tx*4] =
        make_float4(-acc[u][0],-acc[u][1],-acc[u][2],-acc[u][3]);
}

// phase 4 merged: blocks [0,1056) W = Linv @ tril(qL); [1056,1312) alpha.
__global__ __launch_bounds__(256) void walpha_kernel(
    const float* __restrict__ linv, const float* __restrict__ qlf,
    const float* __restrict__ qlg, const float* __restrict__ qmf,
    const float* __restrict__ qmg, float* __restrict__ wf, float* __restrict__ wg,
    float* __restrict__ af, float* __restrict__ ag){
  __shared__ float As[64][68];
  __shared__ float Bs[64][68];
  const int t = threadIdx.x, tx = t & 15, ty = t >> 4;
  int idx = blockIdx.x;
  if (idx >= 1056){
    int abid = idx - 1056;
    int gw = abid*4 + (t>>6), l = t&63;
    for (int job=gw; job<4096; job+=1024){
      int gp = job>>11, r = job&2047;
      const float* qm = gp ? qmg : qmf;
      float s=0.f;
      for (int c=l; c<=r; c+=64) s += linv[(size_t)r*MM+c]*qm[c];
      #pragma unroll
      for (int off=32; off; off>>=1) s += __shfl_down(s, off, 64);
      if (l==0) (gp ? ag : af)[r] = s;
    }
    return;
  }
  int gp = idx/528, rem = idx%528;
  int bi=0; while ((bi+1)*(bi+2)/2 <= rem) ++bi;
  int bj = rem - bi*(bi+1)/2;
  const float* ql = gp ? qlg : qlf;
  float* w        = gp ? wg  : wf;
  float acc[4][4]={};
  for (int bk=bj; bk<=bi; ++bk){
    __syncthreads();
    stage64(As, linv + (size_t)(bi*64)*MM + bk*64, MM, t);
    stage64(Bs, ql   + (size_t)(bk*64)*MM + bj*64, MM, t);
    __syncthreads();
    if (bk==bj){
      for (int p=t;p<4096;p+=256){ int i=p>>6, c=p&63; if (i<c) Bs[i][c]=0.f; }
      __syncthreads();
    }
    tile_gemm_step(acc, As, Bs, tx, ty);
  }
  #pragma unroll
  for (int u=0;u<4;++u)
    *(float4*)&w[(size_t)(bi*64+ty*4+u)*MM + bj*64 + tx*4] =
        make_float4(acc[u][0],acc[u][1],acc[u][2],acc[u][3]);
}

// ================= small kernels (pre/post) =================

// merged reductions: blocks [0,512) redw (wf/wg sq-sums, atomic into scal[5,6]);
// block 512 red_small (logdets + alpha sq-sums into scal[0..4]).
__global__ __launch_bounds__(256) void reduce_kernel(
    const float* __restrict__ lkd, const float* __restrict__ qlf,
    const float* __restrict__ qlg, const float* __restrict__ af,
    const float* __restrict__ ag, const float* __restrict__ wf,
    const float* __restrict__ wg, float* __restrict__ scal){
  __shared__ float scratch[4];
  if (blockIdx.x == 512){
    float ldk=0, ldf=0, ldg=0, a2f=0, a2g=0;
    for (int i=threadIdx.x;i<MM;i+=256){
      int kb = i>>6, r = i&63;
      ldk += __logf(lkd[kb*4096 + r*64 + r]);
      ldf += __logf(fabsf(qlf[(size_t)i*MM+i]));
      ldg += __logf(fabsf(qlg[(size_t)i*MM+i]));
      float v = af[i]; a2f += v*v;
      v = ag[i];       a2g += v*v;
    }
    float r;
    r = block_reduce(ldk, scratch); if (threadIdx.x==0) scal[0] = 2.f*r;
    r = block_reduce(ldf, scratch); if (threadIdx.x==0) scal[1] = 2.f*r;
    r = block_reduce(ldg, scratch); if (threadIdx.x==0) scal[2] = 2.f*r;
    r = block_reduce(a2f, scratch); if (threadIdx.x==0) scal[3] = r;
    r = block_reduce(a2g, scratch); if (threadIdx.x==0) scal[4] = r;
    return;
  }
  size_t start  = (size_t)blockIdx.x*256 + threadIdx.x;
  size_t stride = (size_t)512*256;
  float sf=0, sg=0;
  for (size_t p=start;p<(size_t)MM*MM;p+=stride){
    float v=wf[p]; sf += v*v;
    v=wg[p];       sg += v*v;
  }
  float r = block_reduce(sf, scratch);
  if (threadIdx.x==0) atomicAdd(&scal[5], r);
  r = block_reduce(sg, scratch);
  if (threadIdx.x==0) atomicAdd(&scal[6], r);
}

__global__ void kl_kernel(const float* __restrict__ scal, float* __restrict__ out){
  float klf = 0.5f*(scal[5] + scal[3] - (float)MM + scal[0] - scal[1]);
  float klg = 0.5f*(scal[6] + scal[4] - (float)MM + scal[0] - scal[2]);
  out[0] += klf + klg;
}

// merged splits: blocks [0,16384) rowmajor(linv); [16384,24576) transpose wf/wg
__global__ __launch_bounds__(256) void split_all(
    const float* __restrict__ linv, const float* __restrict__ wf,
    const float* __restrict__ wg, short* __restrict__ lvh, short* __restrict__ lvl,
    short* __restrict__ wfh, short* __restrict__ wfl,
    short* __restrict__ wgh, short* __restrict__ wgl){
  __shared__ float tile[32][33];
  const int t = threadIdx.x;
  const int bid = blockIdx.x;
  if (bid < 16384){
    int p = bid*256 + t;
    int chunk = p >> 9, wi = p & 511;
    int mo = chunk >> 6, ko = chunk & 63;
    int row = mo*16 + (wi >> 5), col = ko*32 + (wi & 31);
    float v = linv[(size_t)row*MM + col];
    short h, lo; bfsplit(v, h, lo);
    lvh[p] = h; lvl[p] = lo;
    return;
  }
  int idx2 = bid - 16384;
  int zz = idx2 >> 12;
  int rem = idx2 & 4095;
  int mb = rem & 63, kb = rem >> 6;
  const float* src = zz ? wg : wf;
  short* dh = zz ? wgh : wfh;
  short* dl = zz ? wgl : wfl;
  #pragma unroll
  for (int k=0;k<4;++k){
    int idx = t + k*256;
    int lr = idx >> 5, lc = idx & 31;
    tile[lr][lc] = src[(size_t)(kb*32+lr)*MM + mb*32 + lc];
  }
  __syncthreads();
  #pragma unroll
  for (int e=0;e<4;++e){
    int p = t*4 + e;
    int c = p >> 9, wi = p & 511;
    int i = (wi >> 5) & 15, kk = wi & 31;
    float v = tile[kk][c*16 + i];
    short h, lo; bfsplit(v, h, lo);
    size_t gp = ((size_t)(mb*2 + c)*64 + kb)*512 + wi;
    dh[gp] = h; dl[gp] = lo;
  }
}

__global__ __launch_bounds__(256, 2) void tt_mfma(
    const float* __restrict__ x, const float* __restrict__ zn2,
    const short* __restrict__ zfh, const short* __restrict__ zfl,
    const short* __restrict__ lvh, const short* __restrict__ lvl,
    short* __restrict__ tth, short* __restrict__ ttl){
  __shared__ __align__(16) short lAh[8192], lAl[8192], lBh[8192], lBl[8192];
  int t = threadIdx.x;
  int l = t & 63, w = t >> 6;
  int istrip = blockIdx.x, bj2 = blockIdx.y;
  int li = l & 15, q = l >> 4;
  int lofs = li*32 + q*8;                              // global z layout (unswizzled)
  int lofs_s = li*32 + ((q ^ ((li>>1)&3)))*8;          // swizzled LDS reads
  int wn4 = (w>>1)*4, wm4 = (w&1)*4;

  short8 xh[2], xl[2];
  float xn2v[8];
  {
    float xn2t[2];
    #pragma unroll
    for (int tn=0; tn<2; ++tn){
      int n = istrip*128 + w*32 + tn*16 + li;
      const float4* xp = (const float4*)(x + (size_t)n*DD);
      float4 p0 = xp[0], p1 = xp[1];
      float v[8] = {p0.x,p0.y,p0.z,p0.w,p1.x,p1.y,p1.z,p1.w};
      float s = 0.f;
      #pragma unroll
      for (int d=0; d<8; ++d) s += v[d]*v[d];
      xn2t[tn] = s;
      short8 hh, ll;
      #pragma unroll
      for (int j=0; j<8; ++j){
        short h=0, lo=0;
        if (q==0) bfsplit(v[j], h, lo);
        hh[j]=h; ll[j]=lo;
      }
      xh[tn]=hh; xl[tn]=ll;
    }
    #pragma unroll
    for (int tn=0; tn<2; ++tn)
      #pragma unroll
      for (int r=0; r<4; ++r)
        xn2v[tn*4+r] = __shfl(xn2t[tn], q*4 + r, 64);
  }

  float4v acc[4][4];
  #pragma unroll
  for (int i=0;i<4;++i)
    #pragma unroll
    for (int j=0;j<4;++j) acc[i][j] = f4zero();

  int nkt = 2*bj2 + 2;
  for (int bk=0; bk<nkt; ++bk){
    __syncthreads();
    {
      short8 zh[4], zl[4];
      float zt2[4];
      #pragma unroll
      for (int tz=0; tz<4; ++tz){
        size_t zo = (size_t)(bk*4 + tz)*512 + lofs;
        zh[tz] = *(const short8*)(zfh + zo);
        zl[tz] = *(const short8*)(zfl + zo);
        zt2[tz] = zn2[bk*64 + tz*16 + li];
      }
      #pragma unroll
      for (int tn=0; tn<2; ++tn){
        #pragma unroll
        for (int tz=0; tz<4; ++tz){
          float4v s4 = mfma3(xh[tn], xl[tn], zh[tz], zl[tz], f4zero());
          #pragma unroll
          for (int r=0; r<4; ++r){
            float e = __expf(4.f*s4[r] - 2.f*(xn2v[tn*4+r] + zt2[tz]));
            short h, lo; bfsplit(e, h, lo);
            // swizzled scalar store: rowc=q*4+r, slot=(tz&1)*2+(li>>3)
            int rowc = q*4 + r;
            int slot2 = (((tz&1)*2 + (li>>3)) ^ ((rowc>>1)&3));
            int pos = ((w*2+tn)*2 + (tz>>1))*512 + rowc*32 + slot2*8 + (li&7);
            lAh[pos] = h; lAl[pos] = lo;
          }
        }
      }
    }
    #pragma unroll
    for (int c4 = t; c4 < 1024; c4 += 256){
      int ch = c4 >> 6, wdi = c4 & 63;
      int wsw = (wdi & 60) | ((wdi ^ (wdi >> 3)) & 3);
      int dst = ch*64 + wsw;
      size_t g = ((size_t)(bj2*8 + (ch>>1))*64 + (size_t)(bk*2 + (ch&1)))*64 + wdi;
      ((uint4*)lBh)[dst] = ((const uint4*)lvh)[g];
      ((uint4*)lBl)[dst] = ((const uint4*)lvl)[g];
    }
    __syncthreads();
    #pragma unroll
    for (int s=0; s<2; ++s){
      short8 ah[4], al[4], bh[4], bl[4];
      #pragma unroll
      for (int tn=0; tn<4; ++tn){
        int off = ((wn4+tn)*2 + s)*512 + lofs_s;
        ah[tn] = *(const short8*)&lAh[off];
        al[tn] = *(const short8*)&lAl[off];
      }
      #pragma unroll
      for (int tm=0; tm<4; ++tm){
        int off = ((wm4+tm)*2 + s)*512 + lofs_s;
        bh[tm] = *(const short8*)&lBh[off];
        bl[tm] = *(const short8*)&lBl[off];
      }
      #pragma unroll
      for (int tn=0; tn<4; ++tn)
        #pragma unroll
        for (int tm=0; tm<4; ++tm)
          acc[tn][tm] = mfma3(ah[tn], al[tn], bh[tm], bl[tm], acc[tn][tm]);
    }
  }
  #pragma unroll
  for (int tn=0; tn<4; ++tn){
    int no_g = istrip*8 + wn4 + tn;
    #pragma unroll
    for (int tm=0; tm<4; ++tm){
      int mo_g = bj2*4 + (w&1)*2 + (tm>>1);
      size_t cb = ((size_t)no_g*64 + mo_g)*512;
      #pragma unroll
      for (int r=0; r<4; ++r){
        short h, lo; bfsplit(acc[tn][tm][r], h, lo);
        size_t pos = cb + (q*4+r)*32 + (tm&1)*16 + li;
        tth[pos] = h; ttl[pos] = lo;
      }
    }
  }
}

__global__ __launch_bounds__(256) void lin_v2(const short* __restrict__ tth,
    const short* __restrict__ ttl, const float* __restrict__ af, const float* __restrict__ ag,
    float* __restrict__ t2, float* __restrict__ lf, float* __restrict__ lg){
  int t = threadIdx.x;
  int w = t >> 6, l = t & 63;
  int n = blockIdx.x*4 + w;
  int g = l >> 2, j = l & 3;
  float s2=0.f, sf=0.f, sg=0.f;
  #pragma unroll
  for (int it=0; it<4; ++it){
    int ck = g + it*16;
    size_t off = ((size_t)(n>>4)*64 + ck)*512 + (n&15)*32 + j*8;
    short8 h8 = *(const short8*)(tth + off);
    short8 l8 = *(const short8*)(ttl + off);
    int m0 = ck*32 + j*8;
    float4 a0 = *(const float4*)(af + m0), a1 = *(const float4*)(af + m0 + 4);
    float4 g0 = *(const float4*)(ag + m0), g1 = *(const float4*)(ag + m0 + 4);
    float av[8] = {a0.x,a0.y,a0.z,a0.w,a1.x,a1.y,a1.z,a1.w};
    float gv[8] = {g0.x,g0.y,g0.z,g0.w,g1.x,g1.y,g1.z,g1.w};
    #pragma unroll
    for (int e=0; e<8; ++e){
      float tv = bf2f(h8[e]) + bf2f(l8[e]);
      s2 += tv*tv; sf += tv*av[e]; sg += tv*gv[e];
    }
  }
  #pragma unroll
  for (int off=32; off; off>>=1){
    s2 += __shfl_down(s2, off, 64);
    sf += __shfl_down(sf, off, 64);
    sg += __shfl_down(sg, off, 64);
  }
  if (l==0){ t2[n] = s2; lf[n] = sf; lg[n] = sg; }
}

__global__ __launch_bounds__(256, 2) void quad_mfma(
    const short* __restrict__ tth, const short* __restrict__ ttl,
    const short* __restrict__ wfh, const short* __restrict__ wfl,
    const short* __restrict__ wgh, const short* __restrict__ wgl,
    float* __restrict__ vfq, float* __restrict__ vgq){
  __shared__ __align__(16) short lAh[8192], lAl[8192], lBh[8192], lBl[8192];
  int t = threadIdx.x, l = t & 63, w = t >> 6;
  int istrip = blockIdx.x, bj2 = blockIdx.y;
  const short* gbh = blockIdx.z ? wgh : wfh;
  const short* gbl = blockIdx.z ? wgl : wfl;
  float* vq = blockIdx.z ? vgq : vfq;
  int li = l & 15, q = l >> 4;
  int lofs_s = li*32 + ((q ^ ((li>>1)&3)))*8;          // swizzled LDS reads
  int wn4 = (w>>1)*4, wm4 = (w&1)*4;

  float4v acc[4][4];
  #pragma unroll
  for (int i=0;i<4;++i)
    #pragma unroll
    for (int j=0;j<4;++j) acc[i][j] = f4zero();

  for (int bk=2*bj2; bk<32; ++bk){
    __syncthreads();
    #pragma unroll
    for (int c4 = t; c4 < 1024; c4 += 256){
      int ch = c4 >> 6, wdi = c4 & 63;
      int wsw = (wdi & 60) | ((wdi ^ (wdi >> 3)) & 3);
      int dst = ch*64 + wsw;
      size_t ga = ((size_t)(istrip*8 + (ch>>1))*64 + (size_t)(bk*2 + (ch&1)))*64 + wdi;
      ((uint4*)lAh)[dst] = ((const uint4*)tth)[ga];
      ((uint4*)lAl)[dst] = ((const uint4*)ttl)[ga];
      size_t gb = ((size_t)(bj2*8 + (ch>>1))*64 + (size_t)(bk*2 + (ch&1)))*64 + wdi;
      ((uint4*)lBh)[dst] = ((const uint4*)gbh)[gb];
      ((uint4*)lBl)[dst] = ((const uint4*)gbl)[gb];
    }
    __syncthreads();
    #pragma unroll
    for (int s=0; s<2; ++s){
      short8 ah[4], al[4], bh[4], bl[4];
      #pragma unroll
      for (int tn=0; tn<4; ++tn){
        int off = ((wn4+tn)*2 + s)*512 + lofs_s;
        ah[tn] = *(const short8*)&lAh[off];
        al[tn] = *(const short8*)&lAl[off];
      }
      #pragma unroll
      for (int tm=0; tm<4; ++tm){
        int off = ((wm4+tm)*2 + s)*512 + lofs_s;
        bh[tm] = *(const short8*)&lBh[off];
        bl[tm] = *(const short8*)&lBl[off];
      }
      #pragma unroll
      for (int tn=0; tn<4; ++tn)
        #pragma unroll
        for (int tm=0; tm<4; ++tm)
          acc[tn][tm] = mfma3(ah[tn], al[tn], bh[tm], bl[tm], acc[tn][tm]);
    }
  }
  float rs[16];
  #pragma unroll
  for (int tn=0; tn<4; ++tn)
    #pragma unroll
    for (int r=0; r<4; ++r){
      float s = 0.f;
      #pragma unroll
      for (int tm=0; tm<4; ++tm){ float v = acc[tn][tm][r]; s += v*v; }
      rs[tn*4+r] = s;
    }
  #pragma unroll
  for (int off=8; off; off>>=1)
    #pragma unroll
    for (int k=0; k<16; ++k) rs[k] += __shfl_down(rs[k], off, 16);
  if (li == 0){
    #pragma unroll
    for (int tn=0; tn<4; ++tn)
      #pragma unroll
      for (int r=0; r<4; ++r){
        int n = istrip*128 + (w>>1)*64 + tn*16 + q*4 + r;
        atomicAdd(&vq[n], rs[tn*4+r]);
      }
  }
}

__global__ __launch_bounds__(256) void final_kernel(const float* __restrict__ y,
    const float* __restrict__ t2, const float* __restrict__ lf, const float* __restrict__ lg,
    const float* __restrict__ vfq, const float* __restrict__ vgq, float* __restrict__ out){
  __shared__ float scratch[4];
  int i = blockIdx.x*256 + threadIdx.x;
  float mf = lf[i], mg = lg[i];
  float vf = 1.f + vfq[i] - t2[i];
  float vg = 1.f + vgq[i] - t2[i];
  float dy = y[i] - mf;
  float e = -HLOG2PI - 0.5f*mg - 0.5f*(dy*dy + vf)*__expf(-mg + 0.5f*vg);
  float r = block_reduce(e, scratch);
  if (threadIdx.x==0) atomicAdd(out, -r);
}

extern "C" void kernel_launch(void* const* d_in, const int* in_sizes, int n_in,
                              void* d_out, int out_size, void* d_ws, size_t ws_size,
                              hipStream_t stream){
  (void)in_sizes; (void)n_in; (void)out_size; (void)ws_size;
  const float* x   = (const float*)d_in[0];
  const float* y   = (const float*)d_in[1];
  const float* z   = (const float*)d_in[2];
  const float* qmf = (const float*)d_in[3];
  const float* qlf = (const float*)d_in[4];
  const float* qmg = (const float*)d_in[5];
  const float* qlg = (const float*)d_in[6];
  float* out = (float*)d_out;
  char* Bw = (char*)d_ws;

  float* kuu  = (float*)Bw;
  float* linv = (float*)(Bw + SZB);
  float* wf   = (float*)(Bw + 2*SZB);
  float* wg   = (float*)(Bw + 3*SZB);
  short* lvh  = (short*)Bw;
  short* lvl  = (short*)(Bw + SZB/2);
  short* wfh  = (short*)(Bw + SZB);
  short* wfl  = (short*)(Bw + SZB + SZB/2);
  short* wgh  = (short*)(Bw + 2*SZB);
  short* wgl  = (short*)(Bw + 2*SZB + SZB/2);
  short* tth  = (short*)(Bw + 3*SZB);
  short* ttl  = (short*)(Bw + 3*SZB + (size_t)NN*MM*2);
  // dead-tt region [64M,112M): ltri 16MB, ptmp 8MB (per-level disjoint),
  // lkdiag 512KB, sdg 8KB
  float* ltri   = (float*)(Bw + 4*SZB);
  float* ptmp   = (float*)(Bw + 5*SZB);
  float* lkdiag = (float*)(Bw + 5*SZB + (size_t)8388608);
  float* sdg    = (float*)(Bw + 5*SZB + (size_t)8388608 + (size_t)524288);
  float* sm   = (float*)(Bw + 3*SZB + (size_t)NN*MM*4);
  float* af = sm;          float* ag = af + MM;
  float* t2 = ag + MM;     float* lf = t2 + NN;   float* lg = lf + NN;
  float* vfq = lg + NN;    float* vgq = vfq + NN; float* scal = vgq + NN;
  float* zn2 = scal + 64 + 2048;
  short* zfh = (short*)(zn2 + MM);
  short* zfl = zfh + MM*32;

  hipMemsetAsync(out, 0, sizeof(float), stream);
  hipMemsetAsync(vfq, 0, (size_t)(2*NN + 64 + 2048)*sizeof(float), stream); // vfq,vgq,scal
  hipMemsetAsync(wf,  0, 2*SZB, stream);    // W upper triangles must be 0
  hipMemsetAsync(linv,0, SZB,   stream);    // Linv upper must be 0

  // ---- factorization: multi-launch (v15 structure, merged endpoints) ----
  phase0_kernel<<<536, 256, 0, stream>>>(z, kuu, zfh, zfl, zn2);
  diag0_kernel<<<1, 256, 0, stream>>>(kuu, lkdiag, sdg);
  for (int kb = 0; kb < 31; ++kb){
    int T = NB - 1 - kb;
    panel_kernel<<<T*(T+1)/2, 256, 0, stream>>>(kuu, lkdiag, sdg, ltri, kb);
  }
  phase2_kernel<<<NB, 256, 0, stream>>>(lkdiag, linv);
  p3l0_kernel<<<16, 256, 0, stream>>>(ltri, linv);
  p3l1_kernel<<<8, 256, 0, stream>>>(ltri, linv, ptmp);
  for (int s = 2; s < 5; ++s){
    int nb = 1<<s, mc = 16>>s;
    p3lA_kernel<<<mc*nb*nb, 256, 0, stream>>>(ltri, linv, ptmp, s);
    p3lB_kernel<<<mc*nb*nb, 256, 0, stream>>>(linv, ptmp, s);
  }
  walpha_kernel<<<1312, 256, 0, stream>>>(linv, qlf, qlg, qmf, qmg, wf, wg, af, ag);

  reduce_kernel<<<513, 256, 0, stream>>>(lkdiag, qlf, qlg, af, ag, wf, wg, scal);
  kl_kernel<<<1, 1, 0, stream>>>(scal, out);

  split_all<<<24576, 256, 0, stream>>>(linv, wf, wg, lvh, lvl, wfh, wfl, wgh, wgl);

  tt_mfma<<<dim3(NN/128, MM/128), 256, 0, stream>>>(x, zn2, zfh, zfl, lvh, lvl, tth, ttl);
  lin_v2<<<NN/4, 256, 0, stream>>>(tth, ttl, af, ag, t2, lf, lg);
  quad_mfma<<<dim3(NN/128, MM/128, 2), 256, 0, stream>>>(tth, ttl, wfh, wfl, wgh, wgl, vfq, vgq);
  final_kernel<<<NN/256, 256, 0, stream>>>(y, t2, lf, lg, vfq, vgq, out);
}

// Round 14
// 3826.628 us; speedup vs baseline: 1.2814x; 1.0068x over previous
//
#include <hip/hip_runtime.h>
#include <math.h>

// ChainedGP v21: v20 (best@3853) + FIVE zero/low-pole merges of the end
// phases (launches 50 -> 45; boundary ~45us each):
//  (1) diag0 fused into phase0 block 0 (computes Kuu(0,0) then factors it)
//  (2) panel kb=30 + phase2 -> one grid-32 launch (block 0: tile + invert
//      diag 31; blocks 1..31: invert diags 0..30)
//  (3) linv rowmajor-split merged into walpha (both only read linv)
//  (4) wfg transpose-split + tt_mfma -> one launch (independent)
//  (5) lin + quad + kl -> one launch (all dep only on prior launch)
// reduce stays separate (must read wf before wgh overwrite). Bodies
// byte-identical, only block-index decoding changed -> absmax unchanged.
#define NN 16384
#define MM 2048
#define DD 8
#define NB 32                     // MM/64
#define SZB ((size_t)16777216)    // 2048*2048*4 bytes

constexpr float HLOG2PI = 0.91893853320467274178f;

using short8  = __attribute__((ext_vector_type(8))) short;
using float4v = __attribute__((ext_vector_type(4))) float;

__device__ __forceinline__ float4v f4zero(){ float4v v; v[0]=0.f; v[1]=0.f; v[2]=0.f; v[3]=0.f; return v; }

__device__ __forceinline__ void bfsplit(float v, short& h, short& lo){
  unsigned b = __float_as_uint(v);
  h = (short)(b >> 16);
  float hf = __uint_as_float(b & 0xFFFF0000u);
  lo = (short)(__float_as_uint(v - hf) >> 16);
}
__device__ __forceinline__ float bf2f(short s){
  return __uint_as_float(((unsigned)(unsigned short)s) << 16);
}
__device__ __forceinline__ float4v mfma3(short8 ah, short8 al, short8 bh, short8 bl, float4v c){
  c = __builtin_amdgcn_mfma_f32_16x16x32_bf16(ah, bh, c, 0, 0, 0);
  c = __builtin_amdgcn_mfma_f32_16x16x32_bf16(ah, bl, c, 0, 0, 0);
  c = __builtin_amdgcn_mfma_f32_16x16x32_bf16(al, bh, c, 0, 0, 0);
  return c;
}

__device__ __forceinline__ float block_reduce(float v, float* scratch){
  int lane = threadIdx.x & 63;
  int w    = threadIdx.x >> 6;
  #pragma unroll
  for (int off=32; off; off>>=1) v += __shfl_down(v, off, 64);
  __syncthreads();
  if (lane==0) scratch[w] = v;
  __syncthreads();
  float r = 0.f;
  if (threadIdx.x < 4) r = scratch[threadIdx.x];
  if (w==0){ r += __shfl_down(r, 2, 64); r += __shfl_down(r, 1, 64); }
  return r;
}

// ---- 64x64 tile helpers (LDS row stride 68 floats) ----
__device__ __forceinline__ void stage64(float (*S)[68], const float* __restrict__ g, int ld, int t){
  #pragma unroll
  for (int p=t; p<1024; p+=256)
    *(float4*)&S[p>>4][(p&15)*4] = *(const float4*)&g[(size_t)(p>>4)*ld + (p&15)*4];
}
__device__ __forceinline__ void tile_gemm_step(float acc[4][4], const float (*As)[68], const float (*Bs)[68], int tx, int ty){
  for (int k=0;k<64;++k){
    float ar[4], bc4[4];
    #pragma unroll
    for (int u=0;u<4;++u){ ar[u]=As[ty*4+u][k]; bc4[u]=Bs[k][tx*4+u]; }
    #pragma unroll
    for (int u=0;u<4;++u)
      #pragma unroll
      for (int v=0;v<4;++v) acc[u][v] += ar[u]*bc4[v];
  }
}
__device__ __forceinline__ void tile_syrk_step(float acc[4][4], const float (*P)[68], const float (*Q)[68], int tx, int ty){
  for (int k=0;k<64;++k){
    float pr[4], qc[4];
    #pragma unroll
    for (int u=0;u<4;++u){ pr[u]=P[ty*4+u][k]; qc[u]=Q[tx*4+u][k]; }
    #pragma unroll
    for (int u=0;u<4;++u)
      #pragma unroll
      for (int v=0;v<4;++v) acc[u][v] += pr[u]*qc[v];
  }
}

// wave-0 register Cholesky of a 64x64 tile staged in S (LDS); no __syncthreads.
__device__ __forceinline__ void factor64_reg(const float (*S)[68],
    float* __restrict__ lkd, float* __restrict__ sdg_, int d, int t){
  if (t < 64){
    float xr[64];
    #pragma unroll
    for (int c4=0;c4<16;++c4) *(float4*)&xr[c4*4] = *(const float4*)&S[t][c4*4];
    float myrp = 1.f;
    #pragma unroll
    for (int j=0;j<64;++j){
      float ajj = __shfl(xr[j], j, 64);
      float piv = sqrtf(fmaxf(ajj, 1e-20f));
      float rp  = 1.f/piv;
      float val = xr[j]*rp;
      if (t==j){ xr[j] = piv; myrp = rp; }
      else if (t>j) xr[j] = val;
      else val = 0.f;
      #pragma unroll
      for (int c=j+1;c<64;++c){
        float vc = __shfl(val, c, 64);
        if (c<=t) xr[c] -= val*vc;
      }
    }
    #pragma unroll
    for (int c=0;c<64;++c) if (c>t) xr[c] = 0.f;
    #pragma unroll
    for (int c4=0;c4<16;++c4)
      *(float4*)&lkd[d*4096 + t*64 + c4*4] = *(float4*)&xr[c4*4];
    sdg_[d*64 + t] = myrp;
  }
}

// ================= factorization kernels (multi-launch) =================

// phase 0: 528 Kuu tiles + (blocks 528..535) zfrag; block 0 factors diag(0).
__global__ __launch_bounds__(256) void phase0_kernel(
    const float* __restrict__ z, float* __restrict__ kuu,
    short* __restrict__ zfh, short* __restrict__ zfl, float* __restrict__ zn2,
    float* __restrict__ lkdiag, float* __restrict__ sdg){
  __shared__ float As[64][68];
  __shared__ float Bs[64][68];
  const int t = threadIdx.x, tx = t & 15, ty = t >> 4;
  const int bid = blockIdx.x;
  if (bid >= 528){
    int zr = (bid-528)*256 + t;
    float v[DD]; float s = 0.f;
    #pragma unroll
    for (int d=0; d<DD; ++d){ v[d] = z[zr*DD + d]; s += v[d]*v[d]; }
    zn2[zr] = s;
    size_t base = (size_t)(zr >> 4)*512 + (zr & 15)*32;
    #pragma unroll
    for (int k=0; k<32; ++k){
      short h = 0, lo = 0;
      if (k < DD) bfsplit(v[k], h, lo);
      zfh[base + k] = h; zfl[base + k] = lo;
    }
    return;
  }
  int idx = bid;
  int r=0; while ((r+1)*(r+2)/2 <= idx) ++r;
  int c = idx - r*(r+1)/2;
  for (int p=t; p<128; p+=256){ int i=p>>1, h=p&1;
    *(float4*)&As[i][h*4] = *(const float4*)&z[(size_t)(r*64+i)*DD + h*4];
    *(float4*)&Bs[i][h*4] = *(const float4*)&z[(size_t)(c*64+i)*DD + h*4]; }
  __syncthreads();
  float kv[4][4];
  #pragma unroll
  for (int u=0;u<4;++u)
    #pragma unroll
    for (int v=0;v<4;++v){
      float d2=0.f;
      #pragma unroll
      for (int d=0;d<8;++d){ float df=As[ty*4+u][d]-Bs[tx*4+v][d]; d2+=df*df; }
      float val = __expf(-2.f*d2);
      if (r*64+ty*4+u == c*64+tx*4+v) val += 1e-6f;
      kv[u][v] = val;
    }
  #pragma unroll
  for (int u=0;u<4;++u)
    *(float4*)&kuu[(size_t)(r*64+ty*4+u)*MM + c*64 + tx*4] =
        make_float4(kv[u][0],kv[u][1],kv[u][2],kv[u][3]);
  if (idx == 0){
    __syncthreads();
    #pragma unroll
    for (int u=0;u<4;++u)
      #pragma unroll
      for (int v=0;v<4;++v) As[ty*4+u][tx*4+v] = kv[u][v];
    __syncthreads();
    factor64_reg(As, lkdiag, sdg, 0, t);
  }
}

// panel kb (kb=0..29): fused TRSM+SYRK; grid = T(T+1)/2, T = 31-kb.
// tile 0 = (kb+1,kb+1): subtract in LDS + factor -> lkdiag[kb+1] (lookahead).
__global__ __launch_bounds__(256) void panel_kernel(
    float* __restrict__ kuu, float* __restrict__ lkdiag,
    float* __restrict__ sdg, float* __restrict__ ltri, int kb){
  __shared__ float As[64][68];
  __shared__ float Bs[64][68];
  __shared__ float Cs[64][68];
  __shared__ float sd[64];
  const int t = threadIdx.x, tx = t & 15, ty = t >> 4;
  int idx = blockIdx.x;
  int r=0; while ((r+1)*(r+2)/2 <= idx) ++r;
  int c = idx - r*(r+1)/2;
  int bi = kb+1+r, bc = kb+1+c;
  stage64(Cs, lkdiag + kb*4096, 64, t);
  if (t < 64) sd[t] = sdg[kb*64 + t];
  stage64(As, kuu + (size_t)(bi*64)*MM + kb*64, MM, t);
  if (bc != bi) stage64(Bs, kuu + (size_t)(bc*64)*MM + kb*64, MM, t);
  __syncthreads();
  {
    int w = t>>6, l = t&63;
    if (w==0 || (w==1 && bc!=bi)){
      float (*S)[68] = (w==0)? As : Bs;
      float xr[64];
      #pragma unroll
      for (int c4=0;c4<16;++c4) *(float4*)&xr[c4*4] = *(const float4*)&S[l][c4*4];
      #pragma unroll
      for (int j=0;j<64;++j){
        float xj = xr[j]*sd[j];
        xr[j] = xj;
        #pragma unroll
        for (int cc=j+1;cc<64;++cc) xr[cc] -= xj*Cs[cc][j];
      }
      #pragma unroll
      for (int c4=0;c4<16;++c4) *(float4*)&S[l][c4*4] = *(float4*)&xr[c4*4];
    }
  }
  __syncthreads();
  if (bc == kb+1){
    for (int p=t;p<1024;p+=256)
      *(float4*)&ltri[(size_t)(bi*64+(p>>4))*MM + kb*64 + (p&15)*4] =
          *(float4*)&As[p>>4][(p&15)*4];
  }
  float acc[4][4] = {};
  tile_syrk_step(acc, As, (bc==bi)? As : Bs, tx, ty);
  if (bi==kb+1 && bc==kb+1){
    __syncthreads();
    #pragma unroll
    for (int u=0;u<4;++u)
      #pragma unroll
      for (int v=0;v<4;++v) Bs[ty*4+u][tx*4+v] = acc[u][v];
    __syncthreads();
    for (int p=t;p<1024;p+=256){
      int i=p>>4, c4=p&15;
      float4 kv = *(const float4*)&kuu[(size_t)(bi*64+i)*MM + bi*64 + c4*4];
      float4 bv = *(float4*)&Bs[i][c4*4];
      float4 o; o.x=kv.x-bv.x; o.y=kv.y-bv.y; o.z=kv.z-bv.z; o.w=kv.w-bv.w;
      *(float4*)&As[i][c4*4] = o;
    }
    __syncthreads();
    factor64_reg(As, lkdiag, sdg, kb+1, t);
  } else {
    #pragma unroll
    for (int u=0;u<4;++u){
      float4* dst = (float4*)&kuu[(size_t)(bi*64+ty*4+u)*MM + bc*64 + tx*4];
      float4 o = *dst;
      o.x-=acc[u][0]; o.y-=acc[u][1]; o.z-=acc[u][2]; o.w-=acc[u][3];
      *dst = o;
    }
  }
}

// merged: panel kb=30 (1 tile) + phase2. grid = 32.
// block 0: panel tile (31,31) -> factors lkdiag[31], then inverts diag 31.
// blocks 1..31: invert diag d = bid-1 (0..30, ready from earlier panels).
__global__ __launch_bounds__(256) void panel30_phase2_kernel(
    float* __restrict__ kuu, float* __restrict__ lkdiag,
    float* __restrict__ sdg, float* __restrict__ ltri, float* __restrict__ linv){
  __shared__ float As[64][68];
  __shared__ float Bs[64][68];
  __shared__ float Cs[64][68];
  __shared__ float sd[64];
  const int t = threadIdx.x, tx = t & 15, ty = t >> 4;
  const int bid = blockIdx.x;
  int d;
  if (bid == 0){
    const int kb = 30, bi = 31;
    stage64(Cs, lkdiag + kb*4096, 64, t);
    if (t < 64) sd[t] = sdg[kb*64 + t];
    stage64(As, kuu + (size_t)(bi*64)*MM + kb*64, MM, t);
    __syncthreads();
    {
      int w = t>>6, l = t&63;
      if (w==0){
        float xr[64];
        #pragma unroll
        for (int c4=0;c4<16;++c4) *(float4*)&xr[c4*4] = *(const float4*)&As[l][c4*4];
        #pragma unroll
        for (int j=0;j<64;++j){
          float xj = xr[j]*sd[j];
          xr[j] = xj;
          #pragma unroll
          for (int cc=j+1;cc<64;++cc) xr[cc] -= xj*Cs[cc][j];
        }
        #pragma unroll
        for (int c4=0;c4<16;++c4) *(float4*)&As[l][c4*4] = *(float4*)&xr[c4*4];
      }
    }
    __syncthreads();
    for (int p=t;p<1024;p+=256)
      *(float4*)&ltri[(size_t)(bi*64+(p>>4))*MM + kb*64 + (p&15)*4] =
          *(float4*)&As[p>>4][(p&15)*4];
    float acc[4][4] = {};
    tile_syrk_step(acc, As, As, tx, ty);
    __syncthreads();
    #pragma unroll
    for (int u=0;u<4;++u)
      #pragma unroll
      for (int v=0;v<4;++v) Bs[ty*4+u][tx*4+v] = acc[u][v];
    __syncthreads();
    for (int p=t;p<1024;p+=256){
      int i=p>>4, c4=p&15;
      float4 kv = *(const float4*)&kuu[(size_t)(bi*64+i)*MM + bi*64 + c4*4];
      float4 bv = *(float4*)&Bs[i][c4*4];
      float4 o; o.x=kv.x-bv.x; o.y=kv.y-bv.y; o.z=kv.z-bv.z; o.w=kv.w-bv.w;
      *(float4*)&As[i][c4*4] = o;
    }
    __syncthreads();
    factor64_reg(As, lkdiag, sdg, 31, t);
    __syncthreads();
    d = 31;
  } else {
    d = bid - 1;
  }
  // phase2 body for diag d
  stage64(As, lkdiag + d*4096, 64, t);
  __syncthreads();
  if (t < 64){
    for (int j=0;j<64;++j){
      float s = (j==t)?1.f:0.f;
      for (int k=t;k<j;++k) s -= As[j][k]*Bs[k][t];
      Bs[j][t] = (j>=t)? s/As[j][j] : 0.f;
    }
  }
  __syncthreads();
  for (int p=t;p<1024;p+=256){ int i=p>>4, c4=p&15;
    *(float4*)&linv[(size_t)(d*64+i)*MM + d*64 + c4*4] = *(float4*)&Bs[i][c4*4]; }
}

// phase 3 level 0 (fused); grid = 16
__global__ __launch_bounds__(256) void p3l0_kernel(
    const float* __restrict__ ltri, float* __restrict__ linv){
  __shared__ float As[64][68];
  __shared__ float Bs[64][68];
  const int t = threadIdx.x, tx = t & 15, ty = t >> 4;
  int m = blockIdx.x;
  stage64(As, ltri + (size_t)((2*m+1)*64)*MM + (2*m)*64, MM, t);
  stage64(Bs, linv + (size_t)((2*m)*64)*MM   + (2*m)*64, MM, t);
  __syncthreads();
  float acc[4][4]={};
  tile_gemm_step(acc, As, Bs, tx, ty);
  __syncthreads();
  #pragma unroll
  for (int u=0;u<4;++u)
    #pragma unroll
    for (int v=0;v<4;++v) Bs[ty*4+u][tx*4+v] = acc[u][v];
  stage64(As, linv + (size_t)((2*m+1)*64)*MM + (2*m+1)*64, MM, t);
  __syncthreads();
  float o[4][4]={};
  tile_gemm_step(o, As, Bs, tx, ty);
  #pragma unroll
  for (int u=0;u<4;++u)
    *(float4*)&linv[(size_t)((2*m+1)*64+ty*4+u)*MM + (2*m)*64 + tx*4] =
        make_float4(-o[u][0],-o[u][1],-o[u][2],-o[u][3]);
}

// phase 3 level 1 (fused per-m); grid = 8
__global__ __launch_bounds__(256) void p3l1_kernel(
    const float* __restrict__ ltri, float* __restrict__ linv, float* __restrict__ ptmp){
  __shared__ float As[64][68];
  __shared__ float Bs[64][68];
  const int t = threadIdx.x, tx = t & 15, ty = t >> 4;
  int m = blockIdx.x;
  float* pm = ptmp + (size_t)m*128*128;
  for (int ti=0; ti<2; ++ti)
    for (int tj=0; tj<2; ++tj){
      int rb = m*4 + 2 + ti, cb0 = m*4;
      float acc[4][4]={};
      for (int k=tj; k<2; ++k){
        __syncthreads();
        stage64(As, ltri + (size_t)(rb*64)*MM + (cb0+k)*64, MM, t);
        stage64(Bs, linv + (size_t)((cb0+k)*64)*MM + (cb0+tj)*64, MM, t);
        __syncthreads();
        tile_gemm_step(acc, As, Bs, tx, ty);
      }
      #pragma unroll
      for (int u=0;u<4;++u)
        *(float4*)&pm[(size_t)(ti*64+ty*4+u)*128 + tj*64 + tx*4] =
            make_float4(acc[u][0],acc[u][1],acc[u][2],acc[u][3]);
    }
  for (int ti=0; ti<2; ++ti)
    for (int tj=0; tj<2; ++tj){
      int rb = m*4 + 2 + ti;
      float acc[4][4]={};
      for (int k=0; k<=ti; ++k){
        __syncthreads();
        stage64(As, linv + (size_t)(rb*64)*MM + (m*4+2+k)*64, MM, t);
        stage64(Bs, pm + (size_t)(k*64)*128 + tj*64, 128, t);
        __syncthreads();
        tile_gemm_step(acc, As, Bs, tx, ty);
      }
      #pragma unroll
      for (int u=0;u<4;++u)
        *(float4*)&linv[(size_t)(rb*64+ty*4+u)*MM + (m*4+tj)*64 + tx*4] =
            make_float4(-acc[u][0],-acc[u][1],-acc[u][2],-acc[u][3]);
    }
}

// phase 3 levels 2..4 part A (P = A21 @ Linv_lower); grid = mc*nb*nb
__global__ __launch_bounds__(256) void p3lA_kernel(
    const float* __restrict__ ltri, const float* __restrict__ linv,
    float* __restrict__ ptmp, int s){
  __shared__ float As[64][68];
  __shared__ float Bs[64][68];
  const int t = threadIdx.x, tx = t & 15, ty = t >> 4;
  int nb = 1<<s, b = 64<<s;
  float* pmb = ptmp + (s==2 ? 131072 : (s==3 ? 393216 : 917504));
  int idx = blockIdx.x;
  int m = idx/(nb*nb), r2 = idx%(nb*nb);
  int ti = r2/nb, tj = r2%nb;
  int rb = m*2*nb + nb + ti, cb0 = m*2*nb;
  float acc[4][4]={};
  for (int k=tj; k<nb; ++k){
    __syncthreads();
    stage64(As, ltri + (size_t)(rb*64)*MM + (cb0+k)*64, MM, t);
    stage64(Bs, linv + (size_t)((cb0+k)*64)*MM + (cb0+tj)*64, MM, t);
    __syncthreads();
    tile_gemm_step(acc, As, Bs, tx, ty);
  }
  float* pm = pmb + (size_t)m*b*b;
  #pragma unroll
  for (int u=0;u<4;++u)
    *(float4*)&pm[(size_t)(ti*64+ty*4+u)*b + tj*64 + tx*4] =
        make_float4(acc[u][0],acc[u][1],acc[u][2],acc[u][3]);
}

// phase 3 levels 2..4 part B (Linv21 = -Linv_lower @ P); grid = mc*nb*nb
__global__ __launch_bounds__(256) void p3lB_kernel(
    float* __restrict__ linv, const float* __restrict__ ptmp, int s){
  __shared__ float As[64][68];
  __shared__ float Bs[64][68];
  const int t = threadIdx.x, tx = t & 15, ty = t >> 4;
  int nb = 1<<s, b = 64<<s;
  const float* pmb = ptmp + (s==2 ? 131072 : (s==3 ? 393216 : 917504));
  int idx = blockIdx.x;
  int m = idx/(nb*nb), r2 = idx%(nb*nb);
  int ti = r2/nb, tj = r2%nb;
  int rb = m*2*nb + nb + ti;
  const float* pm = pmb + (size_t)m*b*b;
  float acc[4][4]={};
  for (int k=0; k<=ti; ++k){
    __syncthreads();
    stage64(As, linv + (size_t)(rb*64)*MM + (m*2*nb+nb+k)*64, MM, t);
    stage64(Bs, pm + (size_t)(k*64)*b + tj*64, b, t);
    __syncthreads();
    tile_gemm_step(acc, As, Bs, tx, ty);
  }
  #pragma unroll
  for (int u=0;u<4;++u)
    *(float4*)&linv[(size_t)(rb*64+ty*4+u)*MM + (m*2*nb+tj)*64 + tx*4] =
        make_float4(-acc[u][0],-acc[u][1],-acc[u][2],-acc[u][3]);
}

// phase 4 merged + linv split: [0,1056) W; [1056,1312) alpha; [1312,17696)
// linv rowmajor split (reads only linv; writes lvh/lvl over dead kuu).
__global__ __launch_bounds__(256) void walpha_split_kernel(
    const float* __restrict__ linv, const float* __restrict__ qlf,
    const float* __restrict__ qlg, const float* __restrict__ qmf,
    const float* __restrict__ qmg, float* __restrict__ wf, float* __restrict__ wg,
    float* __restrict__ af, float* __restrict__ ag,
    short* __restrict__ lvh, short* __restrict__ lvl){
  __shared__ float As[64][68];
  __shared__ float Bs[64][68];
  const int t = threadIdx.x, tx = t & 15, ty = t >> 4;
  int idx = blockIdx.x;
  if (idx >= 1312){
    int p = (idx-1312)*256 + t;
    int chunk = p >> 9, wi = p & 511;
    int mo = chunk >> 6, ko = chunk & 63;
    int row = mo*16 + (wi >> 5), col = ko*32 + (wi & 31);
    float v = linv[(size_t)row*MM + col];
    short h, lo; bfsplit(v, h, lo);
    lvh[p] = h; lvl[p] = lo;
    return;
  }
  if (idx >= 1056){
    int abid = idx - 1056;
    int gw = abid*4 + (t>>6), l = t&63;
    for (int job=gw; job<4096; job+=1024){
      int gp = job>>11, r = job&2047;
      const float* qm = gp ? qmg : qmf;
      float s=0.f;
      for (int c=l; c<=r; c+=64) s += linv[(size_t)r*MM+c]*qm[c];
      #pragma unroll
      for (int off=32; off; off>>=1) s += __shfl_down(s, off, 64);
      if (l==0) (gp ? ag : af)[r] = s;
    }
    return;
  }
  int gp = idx/528, rem = idx%528;
  int bi=0; while ((bi+1)*(bi+2)/2 <= rem) ++bi;
  int bj = rem - bi*(bi+1)/2;
  const float* ql = gp ? qlg : qlf;
  float* w        = gp ? wg  : wf;
  float acc[4][4]={};
  for (int bk=bj; bk<=bi; ++bk){
    __syncthreads();
    stage64(As, linv + (size_t)(bi*64)*MM + bk*64, MM, t);
    stage64(Bs, ql   + (size_t)(bk*64)*MM + bj*64, MM, t);
    __syncthreads();
    if (bk==bj){
      for (int p=t;p<4096;p+=256){ int i=p>>6, c=p&63; if (i<c) Bs[i][c]=0.f; }
      __syncthreads();
    }
    tile_gemm_step(acc, As, Bs, tx, ty);
  }
  #pragma unroll
  for (int u=0;u<4;++u)
    *(float4*)&w[(size_t)(bi*64+ty*4+u)*MM + bj*64 + tx*4] =
        make_float4(acc[u][0],acc[u][1],acc[u][2],acc[u][3]);
}

// merged reductions: blocks [0,512) redw; block 512 red_small.
__global__ __launch_bounds__(256) void reduce_kernel(
    const float* __restrict__ lkd, const float* __restrict__ qlf,
    const float* __restrict__ qlg, const float* __restrict__ af,
    const float* __restrict__ ag, const float* __restrict__ wf,
    const float* __restrict__ wg, float* __restrict__ scal){
  __shared__ float scratch[4];
  if (blockIdx.x == 512){
    float ldk=0, ldf=0, ldg=0, a2f=0, a2g=0;
    for (int i=threadIdx.x;i<MM;i+=256){
      int kb = i>>6, r = i&63;
      ldk += __logf(lkd[kb*4096 + r*64 + r]);
      ldf += __logf(fabsf(qlf[(size_t)i*MM+i]));
      ldg += __logf(fabsf(qlg[(size_t)i*MM+i]));
      float v = af[i]; a2f += v*v;
      v = ag[i];       a2g += v*v;
    }
    float r;
    r = block_reduce(ldk, scratch); if (threadIdx.x==0) scal[0] = 2.f*r;
    r = block_reduce(ldf, scratch); if (threadIdx.x==0) scal[1] = 2.f*r;
    r = block_reduce(ldg, scratch); if (threadIdx.x==0) scal[2] = 2.f*r;
    r = block_reduce(a2f, scratch); if (threadIdx.x==0) scal[3] = r;
    r = block_reduce(a2g, scratch); if (threadIdx.x==0) scal[4] = r;
    return;
  }
  size_t start  = (size_t)blockIdx.x*256 + threadIdx.x;
  size_t stride = (size_t)512*256;
  float sf=0, sg=0;
  for (size_t p=start;p<(size_t)MM*MM;p+=stride){
    float v=wf[p]; sf += v*v;
    v=wg[p];       sg += v*v;
  }
  float r = block_reduce(sf, scratch);
  if (threadIdx.x==0) atomicAdd(&scal[5], r);
  r = block_reduce(sg, scratch);
  if (threadIdx.x==0) atomicAdd(&scal[6], r);
}

// merged: [0,8192) wf/wg transpose-split; [8192,10240) tt_mfma.
__global__ __launch_bounds__(256, 2) void split_tt_kernel(
    const float* __restrict__ wf, const float* __restrict__ wg,
    short* __restrict__ wfh, short* __restrict__ wfl,
    short* __restrict__ wgh, short* __restrict__ wgl,
    const float* __restrict__ x, const float* __restrict__ zn2,
    const short* __restrict__ zfh, const short* __restrict__ zfl,
    const short* __restrict__ lvh, const short* __restrict__ lvl,
    short* __restrict__ tth, short* __restrict__ ttl){
  __shared__ __align__(16) short lAh[8192], lAl[8192], lBh[8192], lBl[8192];
  __shared__ float tile[32][33];
  const int t = threadIdx.x;
  const int bid = blockIdx.x;
  if (bid < 8192){
    int zz = bid >> 12;
    int rem = bid & 4095;
    int mb = rem & 63, kb = rem >> 6;
    const float* src = zz ? wg : wf;
    short* dh = zz ? wgh : wfh;
    short* dl = zz ? wgl : wfl;
    #pragma unroll
    for (int k=0;k<4;++k){
      int idx = t + k*256;
      int lr = idx >> 5, lc = idx & 31;
      tile[lr][lc] = src[(size_t)(kb*32+lr)*MM + mb*32 + lc];
    }
    __syncthreads();
    #pragma unroll
    for (int e=0;e<4;++e){
      int p = t*4 + e;
      int c = p >> 9, wi = p & 511;
      int i = (wi >> 5) & 15, kk = wi & 31;
      float v = tile[kk][c*16 + i];
      short h, lo; bfsplit(v, h, lo);
      size_t gp = ((size_t)(mb*2 + c)*64 + kb)*512 + wi;
      dh[gp] = h; dl[gp] = lo;
    }
    return;
  }
  int v0 = bid - 8192;
  int istrip = v0 % 128, bj2 = v0 / 128;
  int l = t & 63, w = t >> 6;
  int li = l & 15, q = l >> 4;
  int lofs = li*32 + q*8;                              // global z layout
  int lofs_s = li*32 + ((q ^ ((li>>1)&3)))*8;          // swizzled LDS reads
  int wn4 = (w>>1)*4, wm4 = (w&1)*4;

  short8 xh[2], xl[2];
  float xn2v[8];
  {
    float xn2t[2];
    #pragma unroll
    for (int tn=0; tn<2; ++tn){
      int n = istrip*128 + w*32 + tn*16 + li;
      const float4* xp = (const float4*)(x + (size_t)n*DD);
      float4 p0 = xp[0], p1 = xp[1];
      float v[8] = {p0.x,p0.y,p0.z,p0.w,p1.x,p1.y,p1.z,p1.w};
      float s = 0.f;
      #pragma unroll
      for (int d=0; d<8; ++d) s += v[d]*v[d];
      xn2t[tn] = s;
      short8 hh, ll;
      #pragma unroll
      for (int j=0; j<8; ++j){
        short h=0, lo=0;
        if (q==0) bfsplit(v[j], h, lo);
        hh[j]=h; ll[j]=lo;
      }
      xh[tn]=hh; xl[tn]=ll;
    }
    #pragma unroll
    for (int tn=0; tn<2; ++tn)
      #pragma unroll
      for (int r=0; r<4; ++r)
        xn2v[tn*4+r] = __shfl(xn2t[tn], q*4 + r, 64);
  }

  float4v acc[4][4];
  #pragma unroll
  for (int i=0;i<4;++i)
    #pragma unroll
    for (int j=0;j<4;++j) acc[i][j] = f4zero();

  int nkt = 2*bj2 + 2;
  for (int bk=0; bk<nkt; ++bk){
    __syncthreads();
    {
      short8 zh[4], zl[4];
      float zt2[4];
      #pragma unroll
      for (int tz=0; tz<4; ++tz){
        size_t zo = (size_t)(bk*4 + tz)*512 + lofs;
        zh[tz] = *(const short8*)(zfh + zo);
        zl[tz] = *(const short8*)(zfl + zo);
        zt2[tz] = zn2[bk*64 + tz*16 + li];
      }
      #pragma unroll
      for (int tn=0; tn<2; ++tn){
        #pragma unroll
        for (int tz=0; tz<4; ++tz){
          float4v s4 = mfma3(xh[tn], xl[tn], zh[tz], zl[tz], f4zero());
          #pragma unroll
          for (int r=0; r<4; ++r){
            float e = __expf(4.f*s4[r] - 2.f*(xn2v[tn*4+r] + zt2[tz]));
            short h, lo; bfsplit(e, h, lo);
            int rowc = q*4 + r;
            int slot2 = (((tz&1)*2 + (li>>3)) ^ ((rowc>>1)&3));
            int pos = ((w*2+tn)*2 + (tz>>1))*512 + rowc*32 + slot2*8 + (li&7);
            lAh[pos] = h; lAl[pos] = lo;
          }
        }
      }
    }
    #pragma unroll
    for (int c4 = t; c4 < 1024; c4 += 256){
      int ch = c4 >> 6, wdi = c4 & 63;
      int wsw = (wdi & 60) | ((wdi ^ (wdi >> 3)) & 3);
      int dst = ch*64 + wsw;
      size_t g = ((size_t)(bj2*8 + (ch>>1))*64 + (size_t)(bk*2 + (ch&1)))*64 + wdi;
      ((uint4*)lBh)[dst] = ((const uint4*)lvh)[g];
      ((uint4*)lBl)[dst] = ((const uint4*)lvl)[g];
    }
    __syncthreads();
    #pragma unroll
    for (int s=0; s<2; ++s){
      short8 ah[4], al[4], bh[4], bl[4];
      #pragma unroll
      for (int tn=0; tn<4; ++tn){
        int off = ((wn4+tn)*2 + s)*512 + lofs_s;
        ah[tn] = *(const short8*)&lAh[off];
        al[tn] = *(const short8*)&lAl[off];
      }
      #pragma unroll
      for (int tm=0; tm<4; ++tm){
        int off = ((wm4+tm)*2 + s)*512 + lofs_s;
        bh[tm] = *(const short8*)&lBh[off];
        bl[tm] = *(const short8*)&lBl[off];
      }
      #pragma unroll
      for (int tn=0; tn<4; ++tn)
        #pragma unroll
        for (int tm=0; tm<4; ++tm)
          acc[tn][tm] = mfma3(ah[tn], al[tn], bh[tm], bl[tm], acc[tn][tm]);
    }
  }
  #pragma unroll
  for (int tn=0; tn<4; ++tn){
    int no_g = istrip*8 + wn4 + tn;
    #pragma unroll
    for (int tm=0; tm<4; ++tm){
      int mo_g = bj2*4 + (w&1)*2 + (tm>>1);
      size_t cb = ((size_t)no_g*64 + mo_g)*512;
      #pragma unroll
      for (int r=0; r<4; ++r){
        short h, lo; bfsplit(acc[tn][tm][r], h, lo);
        size_t pos = cb + (q*4+r)*32 + (tm&1)*16 + li;
        tth[pos] = h; ttl[pos] = lo;
      }
    }
  }
}

// merged: [0,4096) lin_v2; [4096,8192) quad_mfma; block 8192 kl.
__global__ __launch_bounds__(256, 2) void linquadkl_kernel(
    const short* __restrict__ tth, const short* __restrict__ ttl,
    const float* __restrict__ af, const float* __restrict__ ag,
    float* __restrict__ t2, float* __restrict__ lf, float* __restrict__ lg,
    const short* __restrict__ wfh, const short* __restrict__ wfl,
    const short* __restrict__ wgh, const short* __restrict__ wgl,
    float* __restrict__ vfq, float* __restrict__ vgq,
    const float* __restrict__ scal, float* __restrict__ out){
  __shared__ __align__(16) short lAh[8192], lAl[8192], lBh[8192], lBl[8192];
  const int t = threadIdx.x;
  const int bid = blockIdx.x;
  if (bid == 8192){
    if (t == 0){
      float klf = 0.5f*(scal[5] + scal[3] - (float)MM + scal[0] - scal[1]);
      float klg = 0.5f*(scal[6] + scal[4] - (float)MM + scal[0] - scal[2]);
      out[0] += klf + klg;
    }
    return;
  }
  if (bid < 4096){
    int w = t >> 6, l = t & 63;
    int n = bid*4 + w;
    int g = l >> 2, j = l & 3;
    float s2=0.f, sf=0.f, sg=0.f;
    #pragma unroll
    for (int it=0; it<4; ++it){
      int ck = g + it*16;
      size_t off = ((size_t)(n>>4)*64 + ck)*512 + (n&15)*32 + j*8;
      short8 h8 = *(const short8*)(tth + off);
      short8 l8 = *(const short8*)(ttl + off);
      int m0 = ck*32 + j*8;
      float4 a0 = *(const float4*)(af + m0), a1 = *(const float4*)(af + m0 + 4);
      float4 g0 = *(const float4*)(ag + m0), g1 = *(const float4*)(ag + m0 + 4);
      float av[8] = {a0.x,a0.y,a0.z,a0.w,a1.x,a1.y,a1.z,a1.w};
      float gv[8] = {g0.x,g0.y,g0.z,g0.w,g1.x,g1.y,g1.z,g1.w};
      #pragma unroll
      for (int e=0; e<8; ++e){
        float tv = bf2f(h8[e]) + bf2f(l8[e]);
        s2 += tv*tv; sf += tv*av[e]; sg += tv*gv[e];
      }
    }
    #pragma unroll
    for (int off=32; off; off>>=1){
      s2 += __shfl_down(s2, off, 64);
      sf += __shfl_down(sf, off, 64);
      sg += __shfl_down(sg, off, 64);
    }
    if (l==0){ t2[n] = s2; lf[n] = sf; lg[n] = sg; }
    return;
  }
  int v0 = bid - 4096;
  int istrip = v0 % 128, bj2 = (v0 / 128) % 16, zz = v0 / 2048;
  int l = t & 63, w = t >> 6;
  const short* gbh = zz ? wgh : wfh;
  const short* gbl = zz ? wgl : wfl;
  float* vq = zz ? vgq : vfq;
  int li = l & 15, q = l >> 4;
  int lofs_s = li*32 + ((q ^ ((li>>1)&3)))*8;
  int wn4 = (w>>1)*4, wm4 = (w&1)*4;

  float4v acc[4][4];
  #pragma unroll
  for (int i=0;i<4;++i)
    #pragma unroll
    for (int j=0;j<4;++j) acc[i][j] = f4zero();

  for (int bk=2*bj2; bk<32; ++bk){
    __syncthreads();
    #pragma unroll
    for (int c4 = t; c4 < 1024; c4 += 256){
      int ch = c4 >> 6, wdi = c4 & 63;
      int wsw = (wdi & 60) | ((wdi ^ (wdi >> 3)) & 3);
      int dst = ch*64 + wsw;
      size_t ga = ((size_t)(istrip*8 + (ch>>1))*64 + (size_t)(bk*2 + (ch&1)))*64 + wdi;
      ((uint4*)lAh)[dst] = ((const uint4*)tth)[ga];
      ((uint4*)lAl)[dst] = ((const uint4*)ttl)[ga];
      size_t gb = ((size_t)(bj2*8 + (ch>>1))*64 + (size_t)(bk*2 + (ch&1)))*64 + wdi;
      ((uint4*)lBh)[dst] = ((const uint4*)gbh)[gb];
      ((uint4*)lBl)[dst] = ((const uint4*)gbl)[gb];
    }
    __syncthreads();
    #pragma unroll
    for (int s=0; s<2; ++s){
      short8 ah[4], al[4], bh[4], bl[4];
      #pragma unroll
      for (int tn=0; tn<4; ++tn){
        int off = ((wn4+tn)*2 + s)*512 + lofs_s;
        ah[tn] = *(const short8*)&lAh[off];
        al[tn] = *(const short8*)&lAl[off];
      }
      #pragma unroll
      for (int tm=0; tm<4; ++tm){
        int off = ((wm4+tm)*2 + s)*512 + lofs_s;
        bh[tm] = *(const short8*)&lBh[off];
        bl[tm] = *(const short8*)&lBl[off];
      }
      #pragma unroll
      for (int tn=0; tn<4; ++tn)
        #pragma unroll
        for (int tm=0; tm<4; ++tm)
          acc[tn][tm] = mfma3(ah[tn], al[tn], bh[tm], bl[tm], acc[tn][tm]);
    }
  }
  float rs[16];
  #pragma unroll
  for (int tn=0; tn<4; ++tn)
    #pragma unroll
    for (int r=0; r<4; ++r){
      float s = 0.f;
      #pragma unroll
      for (int tm=0; tm<4; ++tm){ float v = acc[tn][tm][r]; s += v*v; }
      rs[tn*4+r] = s;
    }
  #pragma unroll
  for (int off=8; off; off>>=1)
    #pragma unroll
    for (int k=0; k<16; ++k) rs[k] += __shfl_down(rs[k], off, 16);
  if (li == 0){
    #pragma unroll
    for (int tn=0; tn<4; ++tn)
      #pragma unroll
      for (int r=0; r<4; ++r){
        int n = istrip*128 + (w>>1)*64 + tn*16 + q*4 + r;
        atomicAdd(&vq[n], rs[tn*4+r]);
      }
  }
}

__global__ __launch_bounds__(256) void final_kernel(const float* __restrict__ y,
    const float* __restrict__ t2, const float* __restrict__ lf, const float* __restrict__ lg,
    const float* __restrict__ vfq, const float* __restrict__ vgq, float* __restrict__ out){
  __shared__ float scratch[4];
  int i = blockIdx.x*256 + threadIdx.x;
  float mf = lf[i], mg = lg[i];
  float vf = 1.f + vfq[i] - t2[i];
  float vg = 1.f + vgq[i] - t2[i];
  float dy = y[i] - mf;
  float e = -HLOG2PI - 0.5f*mg - 0.5f*(dy*dy + vf)*__expf(-mg + 0.5f*vg);
  float r = block_reduce(e, scratch);
  if (threadIdx.x==0) atomicAdd(out, -r);
}

extern "C" void kernel_launch(void* const* d_in, const int* in_sizes, int n_in,
                              void* d_out, int out_size, void* d_ws, size_t ws_size,
                              hipStream_t stream){
  (void)in_sizes; (void)n_in; (void)out_size; (void)ws_size;
  const float* x   = (const float*)d_in[0];
  const float* y   = (const float*)d_in[1];
  const float* z   = (const float*)d_in[2];
  const float* qmf = (const float*)d_in[3];
  const float* qlf = (const float*)d_in[4];
  const float* qmg = (const float*)d_in[5];
  const float* qlg = (const float*)d_in[6];
  float* out = (float*)d_out;
  char* Bw = (char*)d_ws;

  float* kuu  = (float*)Bw;
  float* linv = (float*)(Bw + SZB);
  float* wf   = (float*)(Bw + 2*SZB);
  float* wg   = (float*)(Bw + 3*SZB);
  short* lvh  = (short*)Bw;
  short* lvl  = (short*)(Bw + SZB/2);
  short* wfh  = (short*)(Bw + SZB);
  short* wfl  = (short*)(Bw + SZB + SZB/2);
  short* wgh  = (short*)(Bw + 2*SZB);
  short* wgl  = (short*)(Bw + 2*SZB + SZB/2);
  short* tth  = (short*)(Bw + 3*SZB);
  short* ttl  = (short*)(Bw + 3*SZB + (size_t)NN*MM*2);
  float* ltri   = (float*)(Bw + 4*SZB);
  float* ptmp   = (float*)(Bw + 5*SZB);
  float* lkdiag = (float*)(Bw + 5*SZB + (size_t)8388608);
  float* sdg    = (float*)(Bw + 5*SZB + (size_t)8388608 + (size_t)524288);
  float* sm   = (float*)(Bw + 3*SZB + (size_t)NN*MM*4);
  float* af = sm;          float* ag = af + MM;
  float* t2 = ag + MM;     float* lf = t2 + NN;   float* lg = lf + NN;
  float* vfq = lg + NN;    float* vgq = vfq + NN; float* scal = vgq + NN;
  float* zn2 = scal + 64 + 2048;
  short* zfh = (short*)(zn2 + MM);
  short* zfl = zfh + MM*32;

  hipMemsetAsync(out, 0, sizeof(float), stream);
  hipMemsetAsync(vfq, 0, (size_t)(2*NN + 64 + 2048)*sizeof(float), stream);
  hipMemsetAsync(wf,  0, 2*SZB, stream);    // W upper triangles must be 0
  hipMemsetAsync(linv,0, SZB,   stream);    // Linv upper must be 0

  // ---- factorization: multi-launch, merged endpoints ----
  phase0_kernel<<<536, 256, 0, stream>>>(z, kuu, zfh, zfl, zn2, lkdiag, sdg);
  for (int kb = 0; kb < 30; ++kb){
    int T = NB - 1 - kb;
    panel_kernel<<<T*(T+1)/2, 256, 0, stream>>>(kuu, lkdiag, sdg, ltri, kb);
  }
  panel30_phase2_kernel<<<32, 256, 0, stream>>>(kuu, lkdiag, sdg, ltri, linv);
  p3l0_kernel<<<16, 256, 0, stream>>>(ltri, linv);
  p3l1_kernel<<<8, 256, 0, stream>>>(ltri, linv, ptmp);
  for (int s = 2; s < 5; ++s){
    int nb = 1<<s, mc = 16>>s;
    p3lA_kernel<<<mc*nb*nb, 256, 0, stream>>>(ltri, linv, ptmp, s);
    p3lB_kernel<<<mc*nb*nb, 256, 0, stream>>>(linv, ptmp, s);
  }
  walpha_split_kernel<<<17696, 256, 0, stream>>>(linv, qlf, qlg, qmf, qmg,
                                                 wf, wg, af, ag, lvh, lvl);
  reduce_kernel<<<513, 256, 0, stream>>>(lkdiag, qlf, qlg, af, ag, wf, wg, scal);
  split_tt_kernel<<<10240, 256, 0, stream>>>(wf, wg, wfh, wfl, wgh, wgl,
                                             x, zn2, zfh, zfl, lvh, lvl, tth, ttl);
  linquadkl_kernel<<<8193, 256, 0, stream>>>(tth, ttl, af, ag, t2, lf, lg,
                                             wfh, wfl, wgh, wgl, vfq, vgq, scal, out);
  final_kernel<<<NN/256, 256, 0, stream>>>(y, t2, lf, lg, vfq, vgq, out);
}